// Round 3
// baseline (1705.523 us; speedup 1.0000x reference)
//
#include <hip/hip_runtime.h>

#define EDIM 256
#define KNN 8
#define NB 64
#define NP 512
#define NTOT (NB * NP)
#define SLAB 8                 // cells per slab
#define NSLAB (NB / SLAB)
#define SLABPTS (SLAB * NP)    // 4096 points per slab

// ---------------------------------------------------------------------------
// Kernel 1: per-object embeddings (class/color/pos, each L2-normalized) +
// merge GEMM [768 -> 256]. 8 objects per block of 256 threads.
// ---------------------------------------------------------------------------
__global__ __launch_bounds__(256)
void k_embed(const float* __restrict__ class_table,
             const float* __restrict__ cW1, const float* __restrict__ cb1,
             const float* __restrict__ cW2, const float* __restrict__ cb2,
             const float* __restrict__ pW1, const float* __restrict__ pb1,
             const float* __restrict__ pW2, const float* __restrict__ pb2,
             const float* __restrict__ mW, const float* __restrict__ mb,
             const float* __restrict__ positions, const float* __restrict__ colors,
             const int* __restrict__ cls, const int cstride,
             float* __restrict__ emb, float* __restrict__ sqn)
{
    __shared__ float cv[8][768];
    __shared__ float hidc[64];
    __shared__ float hidp[64];
    __shared__ float red[12];

    const int t = threadIdx.x;
    const int lane = t & 63, wv = t >> 6;
    const int base = blockIdx.x * 8;

    for (int g = 0; g < 8; ++g) {
        const int obj = base + g;
        if (t < 64) {
            float a = cb1[t];
            #pragma unroll
            for (int i = 0; i < 3; ++i)
                a += colors[obj * 3 + i] * cW1[i * 64 + t];
            hidc[t] = fmaxf(a, 0.f);
        } else if (t < 128) {
            const int tt = t - 64;
            float a = pb1[tt];
            #pragma unroll
            for (int i = 0; i < 3; ++i)
                a += positions[obj * 3 + i] * pW1[i * 64 + tt];
            hidp[tt] = fmaxf(a, 0.f);
        }
        __syncthreads();

        int ci = cls[(size_t)obj * cstride];
        if ((unsigned)ci > 30u) ci = 0;           // guard OOB class ids
        float ce = class_table[ci * EDIM + t];
        float co = cb2[t];
        float pe = pb2[t];
        for (int j = 0; j < 64; j += 4) {
            #pragma unroll
            for (int jj = 0; jj < 4; ++jj) {
                co += hidc[j + jj] * cW2[(j + jj) * EDIM + t];
                pe += hidp[j + jj] * pW2[(j + jj) * EDIM + t];
            }
        }

        float s0 = ce * ce, s1 = co * co, s2 = pe * pe;
        #pragma unroll
        for (int off = 32; off > 0; off >>= 1) {
            s0 += __shfl_down(s0, off, 64);
            s1 += __shfl_down(s1, off, 64);
            s2 += __shfl_down(s2, off, 64);
        }
        if (lane == 0) { red[wv] = s0; red[4 + wv] = s1; red[8 + wv] = s2; }
        __syncthreads();
        const float n0 = red[0] + red[1] + red[2] + red[3];
        const float n1 = red[4] + red[5] + red[6] + red[7];
        const float n2 = red[8] + red[9] + red[10] + red[11];
        const float r0 = 1.f / fmaxf(sqrtf(n0), 1e-12f);
        const float r1 = 1.f / fmaxf(sqrtf(n1), 1e-12f);
        const float r2 = 1.f / fmaxf(sqrtf(n2), 1e-12f);
        cv[g][t]       = ce * r0;
        cv[g][256 + t] = co * r1;
        cv[g][512 + t] = pe * r2;
        __syncthreads();
    }

    // merge GEMM: emb[g][t] = sum_r cv[g][r] * mW[r][t] + mb[t]
    float acc[8] = {0, 0, 0, 0, 0, 0, 0, 0};
    for (int r = 0; r < 768; r += 4) {
        const float w0 = mW[(r + 0) * EDIM + t];
        const float w1 = mW[(r + 1) * EDIM + t];
        const float w2 = mW[(r + 2) * EDIM + t];
        const float w3 = mW[(r + 3) * EDIM + t];
        #pragma unroll
        for (int g = 0; g < 8; ++g) {
            const float4 x4 = *(const float4*)&cv[g][r];
            acc[g] += x4.x * w0 + x4.y * w1 + x4.z * w2 + x4.w * w3;
        }
    }
    const float mbv = mb[t];
    for (int g = 0; g < 8; ++g) {
        const float e = acc[g] + mbv;
        emb[(size_t)(base + g) * EDIM + t] = e;
        float ss = e * e;
        #pragma unroll
        for (int off = 32; off > 0; off >>= 1) ss += __shfl_down(ss, off, 64);
        if (lane == 0) red[wv] = ss;
        __syncthreads();
        if (t == 0) sqn[base + g] = red[0] + red[1] + red[2] + red[3];
        __syncthreads();
    }
}

// ---------------------------------------------------------------------------
// Kernel 2: per-cell distance matrix for one 8-cell slab.
// dist_slab[b_local][p][q] = sq[p]+sq[q]-2*dot. 64x64 tile per block.
// ---------------------------------------------------------------------------
__global__ __launch_bounds__(256)
void k_gram(const float* __restrict__ emb, const float* __restrict__ sqn,
            float* __restrict__ dist, const int s0)
{
    __shared__ float As[32][68];
    __shared__ float Bs[32][68];

    const int t = threadIdx.x;
    const int b_local = blockIdx.x >> 6;          // 0..7
    const int tile = blockIdx.x & 63;
    const int p0 = (tile >> 3) * 64, q0 = (tile & 7) * 64;
    const int tx = t & 15, ty = t >> 4;
    const size_t cb = (size_t)(s0 + b_local) * NP;  // global cell base
    const size_t lb = (size_t)b_local * NP;         // slab-local cell base

    float acc[4][4];
    #pragma unroll
    for (int i = 0; i < 4; ++i)
        #pragma unroll
        for (int j = 0; j < 4; ++j) acc[i][j] = 0.f;

    for (int kc = 0; kc < 256; kc += 32) {
        #pragma unroll
        for (int i = 0; i < 2; ++i) {
            const int fid = t + 256 * i;     // 0..511
            const int row = fid >> 3;        // 0..63
            const int k4 = fid & 7;          // 0..7
            const float4 a = *(const float4*)&emb[(cb + p0 + row) * EDIM + kc + k4 * 4];
            As[k4 * 4 + 0][row] = a.x; As[k4 * 4 + 1][row] = a.y;
            As[k4 * 4 + 2][row] = a.z; As[k4 * 4 + 3][row] = a.w;
            const float4 bq = *(const float4*)&emb[(cb + q0 + row) * EDIM + kc + k4 * 4];
            Bs[k4 * 4 + 0][row] = bq.x; Bs[k4 * 4 + 1][row] = bq.y;
            Bs[k4 * 4 + 2][row] = bq.z; Bs[k4 * 4 + 3][row] = bq.w;
        }
        __syncthreads();
        #pragma unroll 8
        for (int k = 0; k < 32; ++k) {
            const float4 av = *(const float4*)&As[k][4 * ty];
            const float4 bv = *(const float4*)&Bs[k][4 * tx];
            const float aa[4] = {av.x, av.y, av.z, av.w};
            const float bb[4] = {bv.x, bv.y, bv.z, bv.w};
            #pragma unroll
            for (int i = 0; i < 4; ++i)
                #pragma unroll
                for (int j = 0; j < 4; ++j)
                    acc[i][j] += aa[i] * bb[j];
        }
        __syncthreads();
    }

    float sp[4], sq_[4];
    #pragma unroll
    for (int i = 0; i < 4; ++i) sp[i] = sqn[cb + p0 + 4 * ty + i];
    #pragma unroll
    for (int j = 0; j < 4; ++j) sq_[j] = sqn[cb + q0 + 4 * tx + j];
    #pragma unroll
    for (int i = 0; i < 4; ++i) {
        float4 dv;
        dv.x = (sp[i] + sq_[0]) - 2.f * acc[i][0];
        dv.y = (sp[i] + sq_[1]) - 2.f * acc[i][1];
        dv.z = (sp[i] + sq_[2]) - 2.f * acc[i][2];
        dv.w = (sp[i] + sq_[3]) - 2.f * acc[i][3];
        *(float4*)&dist[(lb + p0 + 4 * ty + i) * NP + q0 + 4 * tx] = dv;
    }
}

// ---------------------------------------------------------------------------
// Kernel 3: top-8 smallest per point within the slab (ties -> lowest index,
// matching jax.lax.top_k). One wave per point, 4 points per block.
// ---------------------------------------------------------------------------
__global__ __launch_bounds__(256)
void k_select(const float* __restrict__ dist, int* __restrict__ nidx, const int s0)
{
    const int wv = threadIdx.x >> 6, lane = threadIdx.x & 63;
    const int p_sl = blockIdx.x * 4 + wv;        // slab-local point id 0..4095
    const int b = s0 + (p_sl >> 9);              // global cell
    const int p_in = p_sl & 511;
    const float* row = dist + (size_t)p_sl * NP;

    float d[8]; int q[8];
    #pragma unroll
    for (int i = 0; i < 8; ++i) { q[i] = lane + 64 * i; d[i] = row[lane + 64 * i]; }

    for (int r = 0; r < KNN; ++r) {
        float bd = d[0]; int bq = q[0];
        #pragma unroll
        for (int i = 1; i < 8; ++i)
            if (d[i] < bd || (d[i] == bd && q[i] < bq)) { bd = d[i]; bq = q[i]; }
        #pragma unroll
        for (int s = 32; s > 0; s >>= 1) {
            const float od = __shfl_down(bd, s, 64);
            const int oq = __shfl_down(bq, s, 64);
            if (od < bd || (od == bd && oq < bq)) { bd = od; bq = oq; }
        }
        const int win = __shfl(bq, 0, 64);
        if (lane == 0) nidx[((size_t)b * NP + p_in) * KNN + r] = b * NP + win;
        if ((win & 63) == lane) {
            const int wi = win >> 6;
            #pragma unroll
            for (int i = 0; i < 8; ++i) if (wi == i) d[i] = 3.4e38f;
        }
    }
}

// ---------------------------------------------------------------------------
// Kernel 4: EdgeConv factorization for one slab.
// u = x@(W1a - W1b) + gb1 written IN PLACE over emb rows (block-local safe);
// v = x@W1b written to the slab buffer. 16 points per block.
// ---------------------------------------------------------------------------
__global__ __launch_bounds__(256)
void k_uv(float* xu, const float* __restrict__ gW1,
          const float* __restrict__ gb1, float* __restrict__ v, const int s0)
{
    __shared__ float xs[16][256];
    const int t = threadIdx.x;
    const int pl0 = blockIdx.x * 16;                     // slab-local
    const size_t pg0 = (size_t)s0 * NP + pl0;            // global
    for (int i = 0; i < 16; ++i) xs[i][t] = xu[(pg0 + i) * EDIM + t];
    __syncthreads();

    const float gb = gb1[t];
    float au[16], av[16];
    #pragma unroll
    for (int g = 0; g < 16; ++g) { au[g] = gb; av[g] = 0.f; }

    for (int k = 0; k < 256; k += 4) {
        float wa[4], wb[4];
        #pragma unroll
        for (int j = 0; j < 4; ++j) {
            wb[j] = gW1[(size_t)(256 + k + j) * EDIM + t];
            wa[j] = gW1[(size_t)(k + j) * EDIM + t] - wb[j];
        }
        #pragma unroll
        for (int g = 0; g < 16; ++g) {
            const float4 x4 = *(const float4*)&xs[g][k];
            au[g] += x4.x * wa[0] + x4.y * wa[1] + x4.z * wa[2] + x4.w * wa[3];
            av[g] += x4.x * wb[0] + x4.y * wb[1] + x4.z * wb[2] + x4.w * wb[3];
        }
    }
    for (int g = 0; g < 16; ++g) {
        xu[(pg0 + g) * EDIM + t] = au[g];                // u, in place
        v[(size_t)(pl0 + g) * EDIM + t] = av[g];         // v, slab-local
    }
}

// ---------------------------------------------------------------------------
// Kernel 5: per-edge S = relu(u_p + v_j)*gamma + beta ; h = S @ gW2 ; max over
// 8 edges and over the block's 4 points (+gb2) -> per-block partial max.
// (Valid because pooling maxes over all points of the cell anyway.)
// ---------------------------------------------------------------------------
__global__ __launch_bounds__(256)
void k_edge(const float* __restrict__ u, const float* __restrict__ v,
            const int* __restrict__ nidx,
            const float* __restrict__ g_gamma, const float* __restrict__ g_beta,
            const float* __restrict__ gW2, const float* __restrict__ gb2,
            float* __restrict__ part, const int s0)
{
    __shared__ float ST[256][36];
    __shared__ float pm[8][256];
    __shared__ int nb[32];

    const int t = threadIdx.x;
    const int pl0 = blockIdx.x * 4;                      // slab-local
    const size_t pg0 = (size_t)s0 * NP + pl0;            // global
    if (t < 32) {
        int n = nidx[pg0 * KNN + t] - s0 * NP;           // slab-local neighbor
        if ((unsigned)n >= (unsigned)SLABPTS) n = 0;     // guard garbage
        nb[t] = n;
    }
    const float gm = g_gamma[t];
    const float bt = g_beta[t];
    __syncthreads();

    for (int g = 0; g < 4; ++g) {
        const float uv_ = u[(pg0 + g) * EDIM + t];
        #pragma unroll
        for (int j = 0; j < 8; ++j) {
            const int n = nb[g * 8 + j];
            const float s = fmaxf(uv_ + v[(size_t)n * EDIM + t], 0.f);
            ST[t][g * 8 + j] = s * gm + bt;
        }
    }
    __syncthreads();

    const int tx = t & 31, ty = t >> 5;
    float acc[4][8];
    #pragma unroll
    for (int i = 0; i < 4; ++i)
        #pragma unroll
        for (int c = 0; c < 8; ++c) acc[i][c] = 0.f;

    for (int k = 0; k < 256; ++k) {
        const float4 s4 = *(const float4*)&ST[k][4 * ty];
        const float ss[4] = {s4.x, s4.y, s4.z, s4.w};
        const float4 w0 = *(const float4*)(gW2 + (size_t)k * EDIM + tx * 8);
        const float4 w1 = *(const float4*)(gW2 + (size_t)k * EDIM + tx * 8 + 4);
        const float w[8] = {w0.x, w0.y, w0.z, w0.w, w1.x, w1.y, w1.z, w1.w};
        #pragma unroll
        for (int i = 0; i < 4; ++i)
            #pragma unroll
            for (int c = 0; c < 8; ++c)
                acc[i][c] += ss[i] * w[c];
    }

    #pragma unroll
    for (int c = 0; c < 8; ++c) {
        const float m = fmaxf(fmaxf(acc[0][c], acc[1][c]), fmaxf(acc[2][c], acc[3][c]));
        pm[ty][tx * 8 + c] = m;
    }
    __syncthreads();

    // thread t = channel: max over the block's 4 points, + gb2
    const float v0 = fmaxf(pm[0][t], pm[1][t]);
    const float v1 = fmaxf(pm[2][t], pm[3][t]);
    const float v2 = fmaxf(pm[4][t], pm[5][t]);
    const float v3 = fmaxf(pm[6][t], pm[7][t]);
    const float bm = fmaxf(fmaxf(v0, v1), fmaxf(v2, v3)) + gb2[t];
    const int b = s0 + (blockIdx.x >> 7);
    const int slot = blockIdx.x & 127;
    part[((size_t)b * 128 + slot) * EDIM + t] = bm;
}

// ---------------------------------------------------------------------------
// Kernel 6: reduce 128 partial maxes per cell, final MLP, L2 normalize.
// ---------------------------------------------------------------------------
__global__ __launch_bounds__(256)
void k_final(const float* __restrict__ part,
             const float* __restrict__ lW1, const float* __restrict__ lb1,
             const float* __restrict__ lW2, const float* __restrict__ lb2,
             float* __restrict__ out)
{
    __shared__ float pooled[256];
    __shared__ float hid[256];
    __shared__ float red[4];

    const int b = blockIdx.x;
    const int t = threadIdx.x;

    float m = -3.4e38f;
    for (int s = 0; s < 128; ++s)
        m = fmaxf(m, part[((size_t)b * 128 + s) * EDIM + t]);
    pooled[t] = m;
    __syncthreads();

    float h = lb1[t];
    for (int k = 0; k < 256; k += 4) {
        #pragma unroll
        for (int kk = 0; kk < 4; ++kk)
            h += pooled[k + kk] * lW1[(k + kk) * EDIM + t];
    }
    hid[t] = fmaxf(h, 0.f);
    __syncthreads();

    float o = lb2[t];
    for (int k = 0; k < 256; k += 4) {
        #pragma unroll
        for (int kk = 0; kk < 4; ++kk)
            o += hid[k + kk] * lW2[(k + kk) * EDIM + t];
    }

    float ss = o * o;
    #pragma unroll
    for (int s = 32; s > 0; s >>= 1) ss += __shfl_down(ss, s, 64);
    if ((t & 63) == 0) red[t >> 6] = ss;
    __syncthreads();
    const float tot = red[0] + red[1] + red[2] + red[3];
    const float rn = 1.f / fmaxf(sqrtf(tot), 1e-12f);
    out[b * EDIM + t] = o * rn;
}

// ---------------------------------------------------------------------------
extern "C" void kernel_launch(void* const* d_in, const int* in_sizes, int n_in,
                              void* d_out, int out_size, void* d_ws, size_t ws_size,
                              hipStream_t stream)
{
    (void)n_in; (void)out_size; (void)ws_size;

    const float* class_table = (const float*)d_in[0];
    const float* cW1 = (const float*)d_in[1];
    const float* cb1 = (const float*)d_in[2];
    const float* cW2 = (const float*)d_in[3];
    const float* cb2 = (const float*)d_in[4];
    const float* pW1 = (const float*)d_in[5];
    const float* pb1 = (const float*)d_in[6];
    const float* pW2 = (const float*)d_in[7];
    const float* pb2 = (const float*)d_in[8];
    const float* mW  = (const float*)d_in[9];
    const float* mb  = (const float*)d_in[10];
    const float* gW1 = (const float*)d_in[11];
    const float* gb1 = (const float*)d_in[12];
    const float* g_gamma = (const float*)d_in[13];
    const float* g_beta  = (const float*)d_in[14];
    const float* gW2 = (const float*)d_in[15];
    const float* gb2 = (const float*)d_in[16];
    const float* lW1 = (const float*)d_in[17];
    const float* lb1 = (const float*)d_in[18];
    const float* lW2 = (const float*)d_in[19];
    const float* lb2 = (const float*)d_in[20];
    const float* positions = (const float*)d_in[21];
    const float* colors    = (const float*)d_in[22];
    const int*  cls        = (const int*)d_in[23];

    // int64-packed class_indices guard (low word at even int32 offsets, LE)
    const int cstride = (in_sizes[23] == 2 * NTOT) ? 2 : 1;

    // workspace (f32 elems), peak ~47.3 MB:
    //   emb/u [N*256] | sqn [N] | nidx [N*8] int | v_slab [4096*256]
    //   dist_slab [8*512*512] == part [64*128*256] (disjoint in time)
    float* emb = (float*)d_ws;
    float* sqn = emb + (size_t)NTOT * EDIM;
    int* nidx = (int*)(sqn + NTOT);
    float* vbuf = (float*)(nidx + (size_t)NTOT * KNN);
    float* dist = vbuf + (size_t)SLABPTS * EDIM;
    float* part = dist;                      // reuse after all gram/select done
    float* out = (float*)d_out;

    k_embed<<<NTOT / 8, 256, 0, stream>>>(class_table, cW1, cb1, cW2, cb2,
                                          pW1, pb1, pW2, pb2, mW, mb,
                                          positions, colors, cls, cstride, emb, sqn);
    for (int s = 0; s < NSLAB; ++s) {
        k_gram<<<SLAB * 64, 256, 0, stream>>>(emb, sqn, dist, s * SLAB);
        k_select<<<SLABPTS / 4, 256, 0, stream>>>(dist, nidx, s * SLAB);
    }
    for (int s = 0; s < NSLAB; ++s) {
        k_uv<<<SLABPTS / 16, 256, 0, stream>>>(emb, gW1, gb1, vbuf, s * SLAB);
        k_edge<<<SLABPTS / 4, 256, 0, stream>>>(emb, vbuf, nidx, g_gamma, g_beta,
                                                gW2, gb2, part, s * SLAB);
    }
    k_final<<<NB, 256, 0, stream>>>(part, lW1, lb1, lW2, lb2, out);
}

// Round 5
// 1335.575 us; speedup vs baseline: 1.2770x; 1.2770x over previous
//
#include <hip/hip_runtime.h>

#define EDIM 256
#define KNN 8
#define NB 64
#define NP 512
#define NTOT (NB * NP)
#define SLAB 8
#define NSLAB (NB / SLAB)
#define SLABPTS (SLAB * NP)   // 4096

typedef short s16x8 __attribute__((ext_vector_type(8)));
typedef float f32x4 __attribute__((ext_vector_type(4)));

__device__ __forceinline__ unsigned short f2b(float f) {
    unsigned u = __float_as_uint(f);
    u = (u + 0x7fffu + ((u >> 16) & 1u)) >> 16;   // RNE
    return (unsigned short)u;
}
__device__ __forceinline__ float b2f(unsigned short h) {
    return __uint_as_float(((unsigned)h) << 16);
}
__device__ __forceinline__ void split2(float x, unsigned short& h, unsigned short& l) {
    h = f2b(x);
    l = f2b(x - b2f(h));
}

// ---------------------------------------------------------------------------
// Kernel 0: weight prep -> transposed bf16 hi/lo pairs for MFMA B-operands.
//   mW[768,256] -> mWh/mWl [n=256][k=768]
//   Wd = gW1[0:256]-gW1[256:512] -> Wdh/Wdl [256][256]
//   Wb = gW1[256:512]            -> Wbh/Wbl
//   gW2 -> g2h/g2l
// ---------------------------------------------------------------------------
__global__ __launch_bounds__(256)
void k_cvt(const float* __restrict__ mW, const float* __restrict__ gW1,
           const float* __restrict__ gW2,
           unsigned short* __restrict__ mWh, unsigned short* __restrict__ mWl,
           unsigned short* __restrict__ Wdh, unsigned short* __restrict__ Wdl,
           unsigned short* __restrict__ Wbh, unsigned short* __restrict__ Wbl,
           unsigned short* __restrict__ g2h, unsigned short* __restrict__ g2l)
{
    const int gid = blockIdx.x * 256 + threadIdx.x;
    unsigned short h, l;
    if (gid < 196608) {
        const int n = gid / 768, k = gid % 768;
        split2(mW[k * 256 + n], h, l);
        mWh[gid] = h; mWl[gid] = l;
    } else if (gid < 262144) {
        const int i = gid - 196608, n = i / 256, k = i % 256;
        split2(gW1[k * 256 + n] - gW1[(k + 256) * 256 + n], h, l);
        Wdh[i] = h; Wdl[i] = l;
    } else if (gid < 327680) {
        const int i = gid - 262144, n = i / 256, k = i % 256;
        split2(gW1[(k + 256) * 256 + n], h, l);
        Wbh[i] = h; Wbl[i] = l;
    } else if (gid < 393216) {
        const int i = gid - 327680, n = i / 256, k = i % 256;
        split2(gW2[k * 256 + n], h, l);
        g2h[i] = h; g2l[i] = l;
    }
}

// ---------------------------------------------------------------------------
// Kernel 1: per-object embeddings + merge GEMM (split-MFMA), one slab.
// 16 objects/block. Prologue f32 VALU (4 obj/wave); 3 segments (ce/co/pe)
// streamed through a CV hi/lo LDS slice; merge = 3-pass MFMA.
// Outputs emb hi/lo (bf16 pair ~ f32) + sqn (f32, from full-precision e).
// ---------------------------------------------------------------------------
__global__ __launch_bounds__(256)
void k_embed(const float* __restrict__ class_table,
             const float* __restrict__ cW1, const float* __restrict__ cb1,
             const float* __restrict__ cW2, const float* __restrict__ cb2,
             const float* __restrict__ pW1, const float* __restrict__ pb1,
             const float* __restrict__ pW2, const float* __restrict__ pb2,
             const unsigned short* __restrict__ mWh, const unsigned short* __restrict__ mWl,
             const float* __restrict__ mb,
             const float* __restrict__ positions, const float* __restrict__ colors,
             const int* __restrict__ cls, const int cstride,
             unsigned short* __restrict__ ehi, unsigned short* __restrict__ elo,
             float* __restrict__ sqn, const int slab)
{
    __shared__ unsigned short CVh[16 * 264];   // 8.4 KB
    __shared__ unsigned short CVl[16 * 264];   // 8.4 KB
    __shared__ unsigned short BT[2 * 10240];   // BTh|BTl 40 KB (aliases hid)
    __shared__ float sqpart[16][4];

    float* hidc = (float*)BT;                  // [16 obj][64]
    float* hidp = hidc + 1024;

    const int t = threadIdx.x;
    const int w = t >> 6, lane = t & 63;
    const int l15 = lane & 15, quad = lane >> 4;
    const int obase = blockIdx.x * 16;         // slab-local

    // --- step A: first layers (color/pos), 4 obj per wave, 4 units per lane
    {
        const int o = lane >> 4;               // 0..3
        const int objl = w * 4 + o;
        const int gobj = slab * SLABPTS + obase + objl;
        const float c0 = colors[gobj * 3], c1 = colors[gobj * 3 + 1], c2 = colors[gobj * 3 + 2];
        const float q0 = positions[gobj * 3], q1 = positions[gobj * 3 + 1], q2 = positions[gobj * 3 + 2];
        const int u0 = (lane & 15) * 4;
        #pragma unroll
        for (int uu = 0; uu < 4; ++uu) {
            const int u = u0 + uu;
            const float hc = cb1[u] + c0 * cW1[u] + c1 * cW1[64 + u] + c2 * cW1[128 + u];
            const float hp = pb1[u] + q0 * pW1[u] + q1 * pW1[64 + u] + q2 * pW1[128 + u];
            hidc[objl * 64 + u] = fmaxf(hc, 0.f);
            hidp[objl * 64 + u] = fmaxf(hp, 0.f);
        }
    }
    __syncthreads();

    // --- step B: second layers; lane owns channels 4*lane..+3 for wave's 4 objs
    float co[4][4], pe[4][4];
    {
        const float4 cb4 = *(const float4*)&cb2[lane * 4];
        const float4 pb4 = *(const float4*)&pb2[lane * 4];
        #pragma unroll
        for (int o = 0; o < 4; ++o) {
            co[o][0] = cb4.x; co[o][1] = cb4.y; co[o][2] = cb4.z; co[o][3] = cb4.w;
            pe[o][0] = pb4.x; pe[o][1] = pb4.y; pe[o][2] = pb4.z; pe[o][3] = pb4.w;
        }
        for (int j = 0; j < 64; ++j) {
            const float4 wc = *(const float4*)&cW2[j * 256 + lane * 4];
            const float4 wp = *(const float4*)&pW2[j * 256 + lane * 4];
            #pragma unroll
            for (int o = 0; o < 4; ++o) {
                const float hc = hidc[(w * 4 + o) * 64 + j];
                const float hp = hidp[(w * 4 + o) * 64 + j];
                co[o][0] += hc * wc.x; co[o][1] += hc * wc.y;
                co[o][2] += hc * wc.z; co[o][3] += hc * wc.w;
                pe[o][0] += hp * wp.x; pe[o][1] += hp * wp.y;
                pe[o][2] += hp * wp.z; pe[o][3] += hp * wp.w;
            }
        }
    }

    // --- step C: class embed + normalizations -> registers
    float cen[4][4], con[4][4], pen[4][4];
    #pragma unroll
    for (int o = 0; o < 4; ++o) {
        const int objl = w * 4 + o;
        const int gobj = slab * SLABPTS + obase + objl;
        int ci = cls[(size_t)gobj * cstride];
        if ((unsigned)ci > 30u) ci = 0;
        const float4 ce4 = *(const float4*)&class_table[ci * 256 + lane * 4];
        const float cev[4] = {ce4.x, ce4.y, ce4.z, ce4.w};
        float sce = 0.f, sco = 0.f, spe = 0.f;
        #pragma unroll
        for (int cc = 0; cc < 4; ++cc) {
            sce += cev[cc] * cev[cc];
            sco += co[o][cc] * co[o][cc];
            spe += pe[o][cc] * pe[o][cc];
        }
        #pragma unroll
        for (int s = 32; s > 0; s >>= 1) {
            sce += __shfl_xor(sce, s, 64);
            sco += __shfl_xor(sco, s, 64);
            spe += __shfl_xor(spe, s, 64);
        }
        const float rce = 1.f / fmaxf(sqrtf(sce), 1e-12f);
        const float rco = 1.f / fmaxf(sqrtf(sco), 1e-12f);
        const float rpe = 1.f / fmaxf(sqrtf(spe), 1e-12f);
        #pragma unroll
        for (int cc = 0; cc < 4; ++cc) {
            cen[o][cc] = cev[cc] * rce;
            con[o][cc] = co[o][cc] * rco;
            pen[o][cc] = pe[o][cc] * rpe;
        }
    }

    // --- step D: merge GEMM, 3 segments x 8 k-tiles, 3-pass split MFMA.
    // wave w owns N-tiles nt = w*4 .. w*4+3 (cols w*64 .. w*64+63).
    f32x4 acc[4];
    #pragma unroll
    for (int i = 0; i < 4; ++i) acc[i] = (f32x4){0.f, 0.f, 0.f, 0.f};

    #pragma unroll
    for (int seg = 0; seg < 3; ++seg) {
        __syncthreads();   // prior seg MFMA reads (and step-B hid reads) done
        #pragma unroll
        for (int o = 0; o < 4; ++o) {
            const int row = w * 4 + o;
            #pragma unroll
            for (int cc = 0; cc < 4; ++cc) {
                const float val = (seg == 0) ? cen[o][cc] : (seg == 1) ? con[o][cc] : pen[o][cc];
                unsigned short h, l;
                split2(val, h, l);
                CVh[row * 264 + lane * 4 + cc] = h;
                CVl[row * 264 + lane * 4 + cc] = l;
            }
        }
        for (int s = 0; s < 8; ++s) {
            __syncthreads();
            {   // stage BTh/BTl: thread t = column n
                const int k0 = seg * 256 + s * 32;
                const uint4* sh = (const uint4*)(mWh + t * 768 + k0);
                const uint4* sl = (const uint4*)(mWl + t * 768 + k0);
                uint4* dh = (uint4*)(BT + t * 40);
                uint4* dl = (uint4*)(BT + 10240 + t * 40);
                dh[0] = sh[0]; dh[1] = sh[1]; dh[2] = sh[2]; dh[3] = sh[3];
                dl[0] = sl[0]; dl[1] = sl[1]; dl[2] = sl[2]; dl[3] = sl[3];
            }
            __syncthreads();
            const s16x8 ah = *(const s16x8*)&CVh[l15 * 264 + s * 32 + quad * 8];
            const s16x8 al = *(const s16x8*)&CVl[l15 * 264 + s * 32 + quad * 8];
            #pragma unroll
            for (int i = 0; i < 4; ++i) {
                const int nt = w * 4 + i;
                const s16x8 bh = *(const s16x8*)&BT[(nt * 16 + l15) * 40 + quad * 8];
                const s16x8 bl = *(const s16x8*)&BT[10240 + (nt * 16 + l15) * 40 + quad * 8];
                acc[i] = __builtin_amdgcn_mfma_f32_16x16x32_bf16(ah, bh, acc[i], 0, 0, 0);
                acc[i] = __builtin_amdgcn_mfma_f32_16x16x32_bf16(al, bh, acc[i], 0, 0, 0);
                acc[i] = __builtin_amdgcn_mfma_f32_16x16x32_bf16(ah, bl, acc[i], 0, 0, 0);
            }
        }
    }

    // --- epilogue: +mb (f32), split-store emb, sqn from f32 e
    float rp[4] = {0.f, 0.f, 0.f, 0.f};
    #pragma unroll
    for (int i = 0; i < 4; ++i) {
        const int col = (w * 4 + i) * 16 + l15;
        const float mbv = mb[col];
        #pragma unroll
        for (int r = 0; r < 4; ++r) {
            const int row = quad * 4 + r;
            const float e = acc[i][r] + mbv;
            unsigned short h, l;
            split2(e, h, l);
            ehi[(size_t)(obase + row) * 256 + col] = h;
            elo[(size_t)(obase + row) * 256 + col] = l;
            rp[r] += e * e;
        }
    }
    #pragma unroll
    for (int s = 8; s > 0; s >>= 1) {
        #pragma unroll
        for (int r = 0; r < 4; ++r) rp[r] += __shfl_down(rp[r], s, 16);
    }
    if (l15 == 0) {
        #pragma unroll
        for (int r = 0; r < 4; ++r) sqpart[quad * 4 + r][w] = rp[r];
    }
    __syncthreads();
    if (t < 16) sqn[obase + t] = sqpart[t][0] + sqpart[t][1] + sqpart[t][2] + sqpart[t][3];
}

// ---------------------------------------------------------------------------
// Kernel 2: Gram/distance via 3-pass split MFMA (f32-faithful selection).
// 64x64 tile per block, frags direct from ehi/elo (slab-local).
// ---------------------------------------------------------------------------
__global__ __launch_bounds__(256)
void k_gram(const unsigned short* __restrict__ ehi, const unsigned short* __restrict__ elo,
            const float* __restrict__ sqn, float* __restrict__ dist)
{
    const int t = threadIdx.x, w = t >> 6, lane = t & 63;
    const int l15 = lane & 15, quad = lane >> 4;
    const int b_local = blockIdx.x >> 6;
    const int tile = blockIdx.x & 63;
    const int p0 = (tile >> 3) * 64, q0 = (tile & 7) * 64;
    const size_t cb = (size_t)b_local * NP;

    const size_t arow = (cb + p0 + 16 * w + l15) * 256 + quad * 8;
    const size_t brow = (cb + q0 + l15) * 256 + quad * 8;

    f32x4 acc[4];
    #pragma unroll
    for (int nt = 0; nt < 4; ++nt) acc[nt] = (f32x4){0.f, 0.f, 0.f, 0.f};

    for (int s = 0; s < 8; ++s) {
        const s16x8 ah = *(const s16x8*)(ehi + arow + s * 32);
        const s16x8 al = *(const s16x8*)(elo + arow + s * 32);
        #pragma unroll
        for (int nt = 0; nt < 4; ++nt) {
            const size_t bo = brow + (size_t)nt * 16 * 256 + s * 32;
            const s16x8 bh = *(const s16x8*)(ehi + bo);
            const s16x8 bl = *(const s16x8*)(elo + bo);
            acc[nt] = __builtin_amdgcn_mfma_f32_16x16x32_bf16(ah, bh, acc[nt], 0, 0, 0);
            acc[nt] = __builtin_amdgcn_mfma_f32_16x16x32_bf16(al, bh, acc[nt], 0, 0, 0);
            acc[nt] = __builtin_amdgcn_mfma_f32_16x16x32_bf16(ah, bl, acc[nt], 0, 0, 0);
        }
    }

    float sqp[4];
    #pragma unroll
    for (int r = 0; r < 4; ++r) sqp[r] = sqn[cb + p0 + 16 * w + quad * 4 + r];
    #pragma unroll
    for (int nt = 0; nt < 4; ++nt) {
        const int colq = q0 + nt * 16 + l15;
        const float sq_q = sqn[cb + colq];
        #pragma unroll
        for (int r = 0; r < 4; ++r) {
            const int rowp = p0 + 16 * w + quad * 4 + r;
            dist[(cb + rowp) * NP + colq] = (sqp[r] + sq_q) - 2.f * acc[nt][r];
        }
    }
}

// ---------------------------------------------------------------------------
// Kernel 3: top-8 smallest per point (ties -> lowest index). One wave/point.
// nidx entries are slab-local point ids.
// ---------------------------------------------------------------------------
__global__ __launch_bounds__(256)
void k_select(const float* __restrict__ dist, int* __restrict__ nidx)
{
    const int wv = threadIdx.x >> 6, lane = threadIdx.x & 63;
    const int p_sl = blockIdx.x * 4 + wv;          // 0..4095
    const float* row = dist + (size_t)p_sl * NP;

    float d[8]; int q[8];
    #pragma unroll
    for (int i = 0; i < 8; ++i) { q[i] = lane + 64 * i; d[i] = row[lane + 64 * i]; }

    for (int r = 0; r < KNN; ++r) {
        float bd = d[0]; int bq = q[0];
        #pragma unroll
        for (int i = 1; i < 8; ++i)
            if (d[i] < bd || (d[i] == bd && q[i] < bq)) { bd = d[i]; bq = q[i]; }
        #pragma unroll
        for (int s = 32; s > 0; s >>= 1) {
            const float od = __shfl_down(bd, s, 64);
            const int oq = __shfl_down(bq, s, 64);
            if (od < bd || (od == bd && oq < bq)) { bd = od; bq = oq; }
        }
        const int win = __shfl(bq, 0, 64);
        if (lane == 0) nidx[(size_t)p_sl * KNN + r] = ((p_sl >> 9) << 9) | win;
        if ((win & 63) == lane) {
            const int wi = win >> 6;
            #pragma unroll
            for (int i = 0; i < 8; ++i) if (wi == i) d[i] = 3.4e38f;
        }
    }
}

// ---------------------------------------------------------------------------
// Kernel 4: u = x@Wd+gb1, v = x@Wb via 3-pass split MFMA. 32 points/block;
// blockIdx>>7 picks u vs v. A frags direct from ehi/elo; B staged hi+lo.
// ---------------------------------------------------------------------------
__global__ __launch_bounds__(256)
void k_uv(const unsigned short* __restrict__ ehi, const unsigned short* __restrict__ elo,
          const unsigned short* __restrict__ Wdh, const unsigned short* __restrict__ Wdl,
          const unsigned short* __restrict__ Wbh, const unsigned short* __restrict__ Wbl,
          const float* __restrict__ gb1,
          float* __restrict__ u, float* __restrict__ v)
{
    __shared__ unsigned short BT[2 * 10240];   // BTh|BTl

    const int t = threadIdx.x, w = t >> 6, lane = t & 63;
    const int l15 = lane & 15, quad = lane >> 4;
    const int isV = blockIdx.x >> 7;
    const int m0 = (blockIdx.x & 127) * 32;    // slab-local
    const unsigned short* Wh = isV ? Wbh : Wdh;
    const unsigned short* Wl = isV ? Wbl : Wdl;
    float* out = isV ? v : u;
    const int mt = w & 1, ch = w >> 1;

    const size_t arow = (size_t)(m0 + mt * 16 + l15) * 256 + quad * 8;

    f32x4 acc[8];
    #pragma unroll
    for (int nt = 0; nt < 8; ++nt) acc[nt] = (f32x4){0.f, 0.f, 0.f, 0.f};

    for (int s = 0; s < 8; ++s) {
        __syncthreads();
        {
            const uint4* sh = (const uint4*)(Wh + t * 256 + s * 32);
            const uint4* sl = (const uint4*)(Wl + t * 256 + s * 32);
            uint4* dh = (uint4*)(BT + t * 40);
            uint4* dl = (uint4*)(BT + 10240 + t * 40);
            dh[0] = sh[0]; dh[1] = sh[1]; dh[2] = sh[2]; dh[3] = sh[3];
            dl[0] = sl[0]; dl[1] = sl[1]; dl[2] = sl[2]; dl[3] = sl[3];
        }
        __syncthreads();
        const s16x8 ah = *(const s16x8*)(ehi + arow + s * 32);
        const s16x8 al = *(const s16x8*)(elo + arow + s * 32);
        #pragma unroll
        for (int nt = 0; nt < 8; ++nt) {
            const int bo = ((ch * 8 + nt) * 16 + l15) * 40 + quad * 8;
            const s16x8 bh = *(const s16x8*)&BT[bo];
            const s16x8 bl = *(const s16x8*)&BT[10240 + bo];
            acc[nt] = __builtin_amdgcn_mfma_f32_16x16x32_bf16(ah, bh, acc[nt], 0, 0, 0);
            acc[nt] = __builtin_amdgcn_mfma_f32_16x16x32_bf16(al, bh, acc[nt], 0, 0, 0);
            acc[nt] = __builtin_amdgcn_mfma_f32_16x16x32_bf16(ah, bl, acc[nt], 0, 0, 0);
        }
    }

    #pragma unroll
    for (int nt = 0; nt < 8; ++nt) {
        const int col = (ch * 8 + nt) * 16 + l15;
        const float bias = isV ? 0.f : gb1[col];
        #pragma unroll
        for (int r = 0; r < 4; ++r) {
            const int row = mt * 16 + quad * 4 + r;
            out[(size_t)(m0 + row) * 256 + col] = acc[nt][r] + bias;
        }
    }
}

// ---------------------------------------------------------------------------
// Kernel 5: edge GEMM + max aggregation, 4 points (32 edges)/block.
// S = relu(u_p+v_j)*gamma+beta computed f32, split hi/lo in LDS;
// h = S@gW2 via split MFMA (Bh k-pass with Ah+Al, then Bl k-pass with Ah);
// max over 8 edges then block's 4 points (+gb2) -> part slot.
// ---------------------------------------------------------------------------
__global__ __launch_bounds__(256)
void k_edge(const float* __restrict__ u, const float* __restrict__ v,
            const int* __restrict__ nidx,
            const float* __restrict__ g_gamma, const float* __restrict__ g_beta,
            const unsigned short* __restrict__ g2h, const unsigned short* __restrict__ g2l,
            const float* __restrict__ gb2,
            float* __restrict__ part, const int slab)
{
    __shared__ unsigned short Sh[32 * 264];    // 16.9 KB
    __shared__ unsigned short Sl[32 * 264];    // 16.9 KB
    __shared__ unsigned short BT[10240];       // 20.5 KB
    __shared__ float pmax[4][256];             // 4 KB
    __shared__ int nb[32];

    const int t = threadIdx.x, w = t >> 6, lane = t & 63;
    const int l15 = lane & 15, quad = lane >> 4;
    const int pl0 = blockIdx.x * 4;            // slab-local point base

    if (t < 32) {
        int n = nidx[(size_t)(pl0 + (t >> 3)) * KNN + (t & 7)];
        if ((unsigned)n >= (unsigned)SLABPTS) n = 0;
        nb[t] = n;
    }
    const float gm = g_gamma[t], bt = g_beta[t];
    __syncthreads();

    {
        float uval[4];
        #pragma unroll
        for (int p = 0; p < 4; ++p) uval[p] = u[(size_t)(pl0 + p) * 256 + t];
        for (int r = 0; r < 32; ++r) {
            const float sv = fmaxf(uval[r >> 3] + v[(size_t)nb[r] * 256 + t], 0.f);
            const float x = sv * gm + bt;
            unsigned short h, l;
            split2(x, h, l);
            Sh[r * 264 + t] = h;
            Sl[r * 264 + t] = l;
        }
    }

    const int mt = w & 1, ch = w >> 1;
    f32x4 acc[8];
    #pragma unroll
    for (int nt = 0; nt < 8; ++nt) acc[nt] = (f32x4){0.f, 0.f, 0.f, 0.f};

    // pass 1: B = g2h, A = Sh and Sl
    for (int s = 0; s < 8; ++s) {
        __syncthreads();   // covers S writes (s==0) / prior BT reads
        {
            const uint4* src = (const uint4*)(g2h + t * 256 + s * 32);
            uint4* dst = (uint4*)(BT + t * 40);
            dst[0] = src[0]; dst[1] = src[1]; dst[2] = src[2]; dst[3] = src[3];
        }
        __syncthreads();
        const int ao = (mt * 16 + l15) * 264 + s * 32 + quad * 8;
        const s16x8 ah = *(const s16x8*)&Sh[ao];
        const s16x8 al = *(const s16x8*)&Sl[ao];
        #pragma unroll
        for (int nt = 0; nt < 8; ++nt) {
            const s16x8 b = *(const s16x8*)&BT[((ch * 8 + nt) * 16 + l15) * 40 + quad * 8];
            acc[nt] = __builtin_amdgcn_mfma_f32_16x16x32_bf16(ah, b, acc[nt], 0, 0, 0);
            acc[nt] = __builtin_amdgcn_mfma_f32_16x16x32_bf16(al, b, acc[nt], 0, 0, 0);
        }
    }
    // pass 2: B = g2l, A = Sh
    for (int s = 0; s < 8; ++s) {
        __syncthreads();
        {
            const uint4* src = (const uint4*)(g2l + t * 256 + s * 32);
            uint4* dst = (uint4*)(BT + t * 40);
            dst[0] = src[0]; dst[1] = src[1]; dst[2] = src[2]; dst[3] = src[3];
        }
        __syncthreads();
        const int ao = (mt * 16 + l15) * 264 + s * 32 + quad * 8;
        const s16x8 ah = *(const s16x8*)&Sh[ao];
        #pragma unroll
        for (int nt = 0; nt < 8; ++nt) {
            const s16x8 b = *(const s16x8*)&BT[((ch * 8 + nt) * 16 + l15) * 40 + quad * 8];
            acc[nt] = __builtin_amdgcn_mfma_f32_16x16x32_bf16(ah, b, acc[nt], 0, 0, 0);
        }
    }

    // reduce: lane's 4 regs are rows quad*4..+3 (one point); xor-16 merges quads
    #pragma unroll
    for (int nt = 0; nt < 8; ++nt) {
        float rm = fmaxf(fmaxf(acc[nt][0], acc[nt][1]), fmaxf(acc[nt][2], acc[nt][3]));
        rm = fmaxf(rm, __shfl_xor(rm, 16, 64));
        const int col = ch * 128 + nt * 16 + l15;
        if (quad == 0)      pmax[mt * 2][col] = rm;
        else if (quad == 2) pmax[mt * 2 + 1][col] = rm;
    }
    __syncthreads();

    const float bm = fmaxf(fmaxf(pmax[0][t], pmax[1][t]), fmaxf(pmax[2][t], pmax[3][t])) + gb2[t];
    const int cell = slab * SLAB + (pl0 >> 9);
    const int slot = (pl0 & 511) >> 2;         // 0..127
    part[((size_t)cell * 128 + slot) * 256 + t] = bm;
}

// ---------------------------------------------------------------------------
// Kernel 6: reduce 128 partial maxes per cell, final MLP (f32), L2 normalize.
// ---------------------------------------------------------------------------
__global__ __launch_bounds__(256)
void k_final(const float* __restrict__ part,
             const float* __restrict__ lW1, const float* __restrict__ lb1,
             const float* __restrict__ lW2, const float* __restrict__ lb2,
             float* __restrict__ out)
{
    __shared__ float pooled[256];
    __shared__ float hid[256];
    __shared__ float red[4];

    const int b = blockIdx.x;
    const int t = threadIdx.x;

    float m = -3.4e38f;
    for (int s = 0; s < 128; ++s)
        m = fmaxf(m, part[((size_t)b * 128 + s) * 256 + t]);
    pooled[t] = m;
    __syncthreads();

    float h = lb1[t];
    for (int k = 0; k < 256; k += 4) {
        #pragma unroll
        for (int kk = 0; kk < 4; ++kk)
            h += pooled[k + kk] * lW1[(k + kk) * 256 + t];
    }
    hid[t] = fmaxf(h, 0.f);
    __syncthreads();

    float o = lb2[t];
    for (int k = 0; k < 256; k += 4) {
        #pragma unroll
        for (int kk = 0; kk < 4; ++kk)
            o += hid[k + kk] * lW2[(k + kk) * 256 + t];
    }

    float ss = o * o;
    #pragma unroll
    for (int s = 32; s > 0; s >>= 1) ss += __shfl_down(ss, s, 64);
    if ((t & 63) == 0) red[t >> 6] = ss;
    __syncthreads();
    const float tot = red[0] + red[1] + red[2] + red[3];
    const float rn = 1.f / fmaxf(sqrtf(tot), 1e-12f);
    out[b * 256 + t] = o * rn;
}

// ---------------------------------------------------------------------------
extern "C" void kernel_launch(void* const* d_in, const int* in_sizes, int n_in,
                              void* d_out, int out_size, void* d_ws, size_t ws_size,
                              hipStream_t stream)
{
    (void)n_in; (void)out_size; (void)ws_size;

    const float* class_table = (const float*)d_in[0];
    const float* cW1 = (const float*)d_in[1];
    const float* cb1 = (const float*)d_in[2];
    const float* cW2 = (const float*)d_in[3];
    const float* cb2 = (const float*)d_in[4];
    const float* pW1 = (const float*)d_in[5];
    const float* pb1 = (const float*)d_in[6];
    const float* pW2 = (const float*)d_in[7];
    const float* pb2 = (const float*)d_in[8];
    const float* mW  = (const float*)d_in[9];
    const float* mb  = (const float*)d_in[10];
    const float* gW1 = (const float*)d_in[11];
    const float* gb1 = (const float*)d_in[12];
    const float* g_gamma = (const float*)d_in[13];
    const float* g_beta  = (const float*)d_in[14];
    const float* gW2 = (const float*)d_in[15];
    const float* gb2 = (const float*)d_in[16];
    const float* lW1 = (const float*)d_in[17];
    const float* lb1 = (const float*)d_in[18];
    const float* lW2 = (const float*)d_in[19];
    const float* lb2 = (const float*)d_in[20];
    const float* positions = (const float*)d_in[21];
    const float* colors    = (const float*)d_in[22];
    const int*  cls        = (const int*)d_in[23];

    const int cstride = (in_sizes[23] == 2 * NTOT) ? 2 : 1;

    // workspace layout (bytes), total ~31.1 MB (well under the proven 47.3):
    char* base = (char*)d_ws;
    float*          part = (float*)(base + 0);                 //  8,388,608
    unsigned short* mWh  = (unsigned short*)(base + 8388608);  //    393,216
    unsigned short* mWl  = (unsigned short*)(base + 8781824);  //    393,216
    unsigned short* Wdh  = (unsigned short*)(base + 9175040);  //    131,072
    unsigned short* Wdl  = (unsigned short*)(base + 9306112);
    unsigned short* Wbh  = (unsigned short*)(base + 9437184);
    unsigned short* Wbl  = (unsigned short*)(base + 9568256);
    unsigned short* g2h  = (unsigned short*)(base + 9699328);
    unsigned short* g2l  = (unsigned short*)(base + 9830400);
    int*            nidx = (int*)(base + 9961472);             //    131,072
    float*          sqn  = (float*)(base + 10092544);          //     16,384
    unsigned short* ehi  = (unsigned short*)(base + 10108928); //  2,097,152
    unsigned short* elo  = (unsigned short*)(base + 12206080); //  2,097,152
    float*          dist = (float*)(base + 14303232);          //  8,388,608
    float*          u    = (float*)(base + 22691840);          //  4,194,304
    float*          v    = (float*)(base + 26886144);          //  4,194,304
    float* out = (float*)d_out;

    k_cvt<<<1536, 256, 0, stream>>>(mW, gW1, gW2, mWh, mWl, Wdh, Wdl, Wbh, Wbl, g2h, g2l);
    for (int s = 0; s < NSLAB; ++s) {
        k_embed<<<SLABPTS / 16, 256, 0, stream>>>(class_table, cW1, cb1, cW2, cb2,
                                                  pW1, pb1, pW2, pb2, mWh, mWl, mb,
                                                  positions, colors, cls, cstride,
                                                  ehi, elo, sqn, s);
        k_gram<<<SLAB * 64, 256, 0, stream>>>(ehi, elo, sqn, dist);
        k_select<<<SLABPTS / 4, 256, 0, stream>>>(dist, nidx);
        k_uv<<<256, 256, 0, stream>>>(ehi, elo, Wdh, Wdl, Wbh, Wbl, gb1, u, v);
        k_edge<<<SLABPTS / 4, 256, 0, stream>>>(u, v, nidx, g_gamma, g_beta,
                                                g2h, g2l, gb2, part, s);
    }
    k_final<<<NB, 256, 0, stream>>>(part, lW1, lb1, lW2, lb2, out);
}

// Round 6
// 1265.139 us; speedup vs baseline: 1.3481x; 1.0557x over previous
//
#include <hip/hip_runtime.h>

#define EDIM 256
#define KNN 8
#define NB 64
#define NP 512
#define NTOT (NB * NP)
#define SLAB 16
#define NSLAB (NB / SLAB)
#define SLABPTS (SLAB * NP)   // 8192

typedef short s16x8 __attribute__((ext_vector_type(8)));
typedef float f32x4 __attribute__((ext_vector_type(4)));

__device__ __forceinline__ unsigned short f2b(float f) {
    unsigned u = __float_as_uint(f);
    u = (u + 0x7fffu + ((u >> 16) & 1u)) >> 16;   // RNE
    return (unsigned short)u;
}
__device__ __forceinline__ float b2f(unsigned short h) {
    return __uint_as_float(((unsigned)h) << 16);
}
__device__ __forceinline__ void split2(float x, unsigned short& h, unsigned short& l) {
    h = f2b(x);
    l = f2b(x - b2f(h));
}

// ---------------------------------------------------------------------------
// Kernel 0: weight prep -> transposed bf16 hi/lo pairs for MFMA B-operands.
// ---------------------------------------------------------------------------
__global__ __launch_bounds__(256)
void k_cvt(const float* __restrict__ mW, const float* __restrict__ gW1,
           const float* __restrict__ gW2,
           unsigned short* __restrict__ mWh, unsigned short* __restrict__ mWl,
           unsigned short* __restrict__ Wdh, unsigned short* __restrict__ Wdl,
           unsigned short* __restrict__ Wbh, unsigned short* __restrict__ Wbl,
           unsigned short* __restrict__ g2h, unsigned short* __restrict__ g2l)
{
    const int gid = blockIdx.x * 256 + threadIdx.x;
    unsigned short h, l;
    if (gid < 196608) {
        const int n = gid / 768, k = gid % 768;
        split2(mW[k * 256 + n], h, l);
        mWh[gid] = h; mWl[gid] = l;
    } else if (gid < 262144) {
        const int i = gid - 196608, n = i / 256, k = i % 256;
        split2(gW1[k * 256 + n] - gW1[(k + 256) * 256 + n], h, l);
        Wdh[i] = h; Wdl[i] = l;
    } else if (gid < 327680) {
        const int i = gid - 262144, n = i / 256, k = i % 256;
        split2(gW1[(k + 256) * 256 + n], h, l);
        Wbh[i] = h; Wbl[i] = l;
    } else if (gid < 393216) {
        const int i = gid - 327680, n = i / 256, k = i % 256;
        split2(gW2[k * 256 + n], h, l);
        g2h[i] = h; g2l[i] = l;
    }
}

// ---------------------------------------------------------------------------
// Kernel 1: per-object embeddings + merge GEMM (split-MFMA), 16 obj/block.
// B-fragments read DIRECTLY from global (L2-resident weights) -> only 2
// barriers per segment, no staging LDS. Outputs emb hi/lo + sqn (slab-local).
// ---------------------------------------------------------------------------
__global__ __launch_bounds__(256)
void k_embed(const float* __restrict__ class_table,
             const float* __restrict__ cW1, const float* __restrict__ cb1,
             const float* __restrict__ cW2, const float* __restrict__ cb2,
             const float* __restrict__ pW1, const float* __restrict__ pb1,
             const float* __restrict__ pW2, const float* __restrict__ pb2,
             const unsigned short* __restrict__ mWh, const unsigned short* __restrict__ mWl,
             const float* __restrict__ mb,
             const float* __restrict__ positions, const float* __restrict__ colors,
             const int* __restrict__ cls, const int cstride,
             unsigned short* __restrict__ ehi, unsigned short* __restrict__ elo,
             float* __restrict__ sqn, const int pbase)
{
    __shared__ unsigned short CVh[16 * 264];   // 8.4 KB  (one 256-k segment)
    __shared__ unsigned short CVl[16 * 264];   // 8.4 KB
    __shared__ float hid[2048];                // 8 KB: [16 obj][64] c | p
    __shared__ float sqpart[16][4];

    float* hidc = hid;
    float* hidp = hid + 1024;

    const int t = threadIdx.x;
    const int w = t >> 6, lane = t & 63;
    const int l15 = lane & 15, quad = lane >> 4;
    const int obase = blockIdx.x * 16;         // slab-local

    // --- step A: first layers (color/pos), 4 obj per wave, 4 units per lane
    {
        const int o = lane >> 4;
        const int objl = w * 4 + o;
        const int gobj = pbase + obase + objl;
        const float c0 = colors[gobj * 3], c1 = colors[gobj * 3 + 1], c2 = colors[gobj * 3 + 2];
        const float q0 = positions[gobj * 3], q1 = positions[gobj * 3 + 1], q2 = positions[gobj * 3 + 2];
        const int u0 = (lane & 15) * 4;
        #pragma unroll
        for (int uu = 0; uu < 4; ++uu) {
            const int u = u0 + uu;
            const float hc = cb1[u] + c0 * cW1[u] + c1 * cW1[64 + u] + c2 * cW1[128 + u];
            const float hp = pb1[u] + q0 * pW1[u] + q1 * pW1[64 + u] + q2 * pW1[128 + u];
            hidc[objl * 64 + u] = fmaxf(hc, 0.f);
            hidp[objl * 64 + u] = fmaxf(hp, 0.f);
        }
    }
    __syncthreads();

    // --- step B: second layers; lane owns channels 4*lane..+3 for wave's 4 objs
    float co[4][4], pe[4][4];
    {
        const float4 cb4 = *(const float4*)&cb2[lane * 4];
        const float4 pb4 = *(const float4*)&pb2[lane * 4];
        #pragma unroll
        for (int o = 0; o < 4; ++o) {
            co[o][0] = cb4.x; co[o][1] = cb4.y; co[o][2] = cb4.z; co[o][3] = cb4.w;
            pe[o][0] = pb4.x; pe[o][1] = pb4.y; pe[o][2] = pb4.z; pe[o][3] = pb4.w;
        }
        for (int j = 0; j < 64; ++j) {
            const float4 wc = *(const float4*)&cW2[j * 256 + lane * 4];
            const float4 wp = *(const float4*)&pW2[j * 256 + lane * 4];
            #pragma unroll
            for (int o = 0; o < 4; ++o) {
                const float hc = hidc[(w * 4 + o) * 64 + j];
                const float hp = hidp[(w * 4 + o) * 64 + j];
                co[o][0] += hc * wc.x; co[o][1] += hc * wc.y;
                co[o][2] += hc * wc.z; co[o][3] += hc * wc.w;
                pe[o][0] += hp * wp.x; pe[o][1] += hp * wp.y;
                pe[o][2] += hp * wp.z; pe[o][3] += hp * wp.w;
            }
        }
    }

    // --- step C: class embed + normalizations -> registers
    float cen[4][4], con[4][4], pen[4][4];
    #pragma unroll
    for (int o = 0; o < 4; ++o) {
        const int objl = w * 4 + o;
        const int gobj = pbase + obase + objl;
        int ci = cls[(size_t)gobj * cstride];
        if ((unsigned)ci > 30u) ci = 0;
        const float4 ce4 = *(const float4*)&class_table[ci * 256 + lane * 4];
        const float cev[4] = {ce4.x, ce4.y, ce4.z, ce4.w};
        float sce = 0.f, sco = 0.f, spe = 0.f;
        #pragma unroll
        for (int cc = 0; cc < 4; ++cc) {
            sce += cev[cc] * cev[cc];
            sco += co[o][cc] * co[o][cc];
            spe += pe[o][cc] * pe[o][cc];
        }
        #pragma unroll
        for (int s = 32; s > 0; s >>= 1) {
            sce += __shfl_xor(sce, s, 64);
            sco += __shfl_xor(sco, s, 64);
            spe += __shfl_xor(spe, s, 64);
        }
        const float rce = 1.f / fmaxf(sqrtf(sce), 1e-12f);
        const float rco = 1.f / fmaxf(sqrtf(sco), 1e-12f);
        const float rpe = 1.f / fmaxf(sqrtf(spe), 1e-12f);
        #pragma unroll
        for (int cc = 0; cc < 4; ++cc) {
            cen[o][cc] = cev[cc] * rce;
            con[o][cc] = co[o][cc] * rco;
            pen[o][cc] = pe[o][cc] * rpe;
        }
    }

    // --- step D: merge GEMM, 3 segments x 8 k-tiles, 3-pass split MFMA.
    // wave w owns cols w*64..w*64+63; B-frags from global mWh/mWl.
    f32x4 acc[4];
    #pragma unroll
    for (int i = 0; i < 4; ++i) acc[i] = (f32x4){0.f, 0.f, 0.f, 0.f};

    #pragma unroll
    for (int seg = 0; seg < 3; ++seg) {
        __syncthreads();   // previous segment's CV reads complete
        #pragma unroll
        for (int o = 0; o < 4; ++o) {
            const int row = w * 4 + o;
            #pragma unroll
            for (int cc = 0; cc < 4; ++cc) {
                const float val = (seg == 0) ? cen[o][cc] : (seg == 1) ? con[o][cc] : pen[o][cc];
                unsigned short h, l;
                split2(val, h, l);
                CVh[row * 264 + lane * 4 + cc] = h;
                CVl[row * 264 + lane * 4 + cc] = l;
            }
        }
        __syncthreads();
        for (int s = 0; s < 8; ++s) {
            const s16x8 ah = *(const s16x8*)&CVh[l15 * 264 + s * 32 + quad * 8];
            const s16x8 al = *(const s16x8*)&CVl[l15 * 264 + s * 32 + quad * 8];
            #pragma unroll
            for (int i = 0; i < 4; ++i) {
                const int n = (w * 4 + i) * 16 + l15;
                const size_t bo = (size_t)n * 768 + seg * 256 + s * 32 + quad * 8;
                const s16x8 bh = *(const s16x8*)(mWh + bo);
                const s16x8 bl = *(const s16x8*)(mWl + bo);
                acc[i] = __builtin_amdgcn_mfma_f32_16x16x32_bf16(ah, bh, acc[i], 0, 0, 0);
                acc[i] = __builtin_amdgcn_mfma_f32_16x16x32_bf16(al, bh, acc[i], 0, 0, 0);
                acc[i] = __builtin_amdgcn_mfma_f32_16x16x32_bf16(ah, bl, acc[i], 0, 0, 0);
            }
        }
    }

    // --- epilogue: +mb (f32), split-store emb, sqn from f32 e
    float rp[4] = {0.f, 0.f, 0.f, 0.f};
    #pragma unroll
    for (int i = 0; i < 4; ++i) {
        const int col = (w * 4 + i) * 16 + l15;
        const float mbv = mb[col];
        #pragma unroll
        for (int r = 0; r < 4; ++r) {
            const int row = quad * 4 + r;
            const float e = acc[i][r] + mbv;
            unsigned short h, l;
            split2(e, h, l);
            ehi[(size_t)(obase + row) * 256 + col] = h;
            elo[(size_t)(obase + row) * 256 + col] = l;
            rp[r] += e * e;
        }
    }
    #pragma unroll
    for (int s = 8; s > 0; s >>= 1) {
        #pragma unroll
        for (int r = 0; r < 4; ++r) rp[r] += __shfl_down(rp[r], s, 16);
    }
    if (l15 == 0) {
        #pragma unroll
        for (int r = 0; r < 4; ++r) sqpart[quad * 4 + r][w] = rp[r];
    }
    __syncthreads();
    if (t < 16) sqn[obase + t] = sqpart[t][0] + sqpart[t][1] + sqpart[t][2] + sqpart[t][3];
}

// ---------------------------------------------------------------------------
// Kernel 2: Gram/distance via 3-pass split MFMA, frags direct from ehi/elo.
// 64x64 tile per block. 16 cells per slab.
// ---------------------------------------------------------------------------
__global__ __launch_bounds__(256)
void k_gram(const unsigned short* __restrict__ ehi, const unsigned short* __restrict__ elo,
            const float* __restrict__ sqn, float* __restrict__ dist)
{
    const int t = threadIdx.x, w = t >> 6, lane = t & 63;
    const int l15 = lane & 15, quad = lane >> 4;
    const int b_local = blockIdx.x >> 6;       // 0..15
    const int tile = blockIdx.x & 63;
    const int p0 = (tile >> 3) * 64, q0 = (tile & 7) * 64;
    const size_t cb = (size_t)b_local * NP;

    const size_t arow = (cb + p0 + 16 * w + l15) * 256 + quad * 8;
    const size_t brow = (cb + q0 + l15) * 256 + quad * 8;

    f32x4 acc[4];
    #pragma unroll
    for (int nt = 0; nt < 4; ++nt) acc[nt] = (f32x4){0.f, 0.f, 0.f, 0.f};

    for (int s = 0; s < 8; ++s) {
        const s16x8 ah = *(const s16x8*)(ehi + arow + s * 32);
        const s16x8 al = *(const s16x8*)(elo + arow + s * 32);
        #pragma unroll
        for (int nt = 0; nt < 4; ++nt) {
            const size_t bo = brow + (size_t)nt * 16 * 256 + s * 32;
            const s16x8 bh = *(const s16x8*)(ehi + bo);
            const s16x8 bl = *(const s16x8*)(elo + bo);
            acc[nt] = __builtin_amdgcn_mfma_f32_16x16x32_bf16(ah, bh, acc[nt], 0, 0, 0);
            acc[nt] = __builtin_amdgcn_mfma_f32_16x16x32_bf16(al, bh, acc[nt], 0, 0, 0);
            acc[nt] = __builtin_amdgcn_mfma_f32_16x16x32_bf16(ah, bl, acc[nt], 0, 0, 0);
        }
    }

    float sqp[4];
    #pragma unroll
    for (int r = 0; r < 4; ++r) sqp[r] = sqn[cb + p0 + 16 * w + quad * 4 + r];
    #pragma unroll
    for (int nt = 0; nt < 4; ++nt) {
        const int colq = q0 + nt * 16 + l15;
        const float sq_q = sqn[cb + colq];
        #pragma unroll
        for (int r = 0; r < 4; ++r) {
            const int rowp = p0 + 16 * w + quad * 4 + r;
            dist[(cb + rowp) * NP + colq] = (sqp[r] + sq_q) - 2.f * acc[nt][r];
        }
    }
}

// ---------------------------------------------------------------------------
// Kernel 3: top-8 smallest per point (ties -> lowest index). One wave/point.
// nidx entries are slab-local point ids.
// ---------------------------------------------------------------------------
__global__ __launch_bounds__(256)
void k_select(const float* __restrict__ dist, int* __restrict__ nidx)
{
    const int wv = threadIdx.x >> 6, lane = threadIdx.x & 63;
    const int p_sl = blockIdx.x * 4 + wv;          // 0..8191
    const float* row = dist + (size_t)p_sl * NP;

    float d[8]; int q[8];
    #pragma unroll
    for (int i = 0; i < 8; ++i) { q[i] = lane + 64 * i; d[i] = row[lane + 64 * i]; }

    for (int r = 0; r < KNN; ++r) {
        float bd = d[0]; int bq = q[0];
        #pragma unroll
        for (int i = 1; i < 8; ++i)
            if (d[i] < bd || (d[i] == bd && q[i] < bq)) { bd = d[i]; bq = q[i]; }
        #pragma unroll
        for (int s = 32; s > 0; s >>= 1) {
            const float od = __shfl_down(bd, s, 64);
            const int oq = __shfl_down(bq, s, 64);
            if (od < bd || (od == bd && oq < bq)) { bd = od; bq = oq; }
        }
        const int win = __shfl(bq, 0, 64);
        if (lane == 0) nidx[(size_t)p_sl * KNN + r] = ((p_sl >> 9) << 9) | win;
        if ((win & 63) == lane) {
            const int wi = win >> 6;
            #pragma unroll
            for (int i = 0; i < 8; ++i) if (wi == i) d[i] = 3.4e38f;
        }
    }
}

// ---------------------------------------------------------------------------
// Kernel 4: u = x@Wd+gb1, v = x@Wb via 3-pass split MFMA. 32 points/block;
// block id >> 8 picks u vs v. NO LDS, NO barriers: A frags from ehi/elo,
// B frags direct from global (L2-resident 131 KB weights).
// ---------------------------------------------------------------------------
__global__ __launch_bounds__(256)
void k_uv(const unsigned short* __restrict__ ehi, const unsigned short* __restrict__ elo,
          const unsigned short* __restrict__ Wdh, const unsigned short* __restrict__ Wdl,
          const unsigned short* __restrict__ Wbh, const unsigned short* __restrict__ Wbl,
          const float* __restrict__ gb1,
          float* __restrict__ u, float* __restrict__ v)
{
    const int t = threadIdx.x, w = t >> 6, lane = t & 63;
    const int l15 = lane & 15, quad = lane >> 4;
    const int isV = blockIdx.x >> 8;
    const int m0 = (blockIdx.x & 255) * 32;    // slab-local
    const unsigned short* Wh = isV ? Wbh : Wdh;
    const unsigned short* Wl = isV ? Wbl : Wdl;
    float* out = isV ? v : u;
    const int mt = w & 1, ch = w >> 1;

    const size_t arow = (size_t)(m0 + mt * 16 + l15) * 256 + quad * 8;

    f32x4 acc[8];
    #pragma unroll
    for (int nt = 0; nt < 8; ++nt) acc[nt] = (f32x4){0.f, 0.f, 0.f, 0.f};

    for (int s = 0; s < 8; ++s) {
        const s16x8 ah = *(const s16x8*)(ehi + arow + s * 32);
        const s16x8 al = *(const s16x8*)(elo + arow + s * 32);
        #pragma unroll
        for (int nt = 0; nt < 8; ++nt) {
            const int n = (ch * 8 + nt) * 16 + l15;
            const size_t bo = (size_t)n * 256 + s * 32 + quad * 8;
            const s16x8 bh = *(const s16x8*)(Wh + bo);
            const s16x8 bl = *(const s16x8*)(Wl + bo);
            acc[nt] = __builtin_amdgcn_mfma_f32_16x16x32_bf16(ah, bh, acc[nt], 0, 0, 0);
            acc[nt] = __builtin_amdgcn_mfma_f32_16x16x32_bf16(al, bh, acc[nt], 0, 0, 0);
            acc[nt] = __builtin_amdgcn_mfma_f32_16x16x32_bf16(ah, bl, acc[nt], 0, 0, 0);
        }
    }

    #pragma unroll
    for (int nt = 0; nt < 8; ++nt) {
        const int col = (ch * 8 + nt) * 16 + l15;
        const float bias = isV ? 0.f : gb1[col];
        #pragma unroll
        for (int r = 0; r < 4; ++r) {
            const int row = mt * 16 + quad * 4 + r;
            out[(size_t)(m0 + row) * 256 + col] = acc[nt][r] + bias;
        }
    }
}

// ---------------------------------------------------------------------------
// Kernel 5: edge GEMM + max aggregation, 4 points (32 edges)/block.
// S = relu(u_p+v_j)*gamma+beta f32 -> split hi/lo in LDS; h = S@gW2 via
// split MFMA with B frags direct from global; max over 8 edges + 4 points.
// Single barrier pair, no staging.
// ---------------------------------------------------------------------------
__global__ __launch_bounds__(256)
void k_edge(const float* __restrict__ u, const float* __restrict__ v,
            const int* __restrict__ nidx,
            const float* __restrict__ g_gamma, const float* __restrict__ g_beta,
            const unsigned short* __restrict__ g2h, const unsigned short* __restrict__ g2l,
            const float* __restrict__ gb2,
            float* __restrict__ part, const int cell0)
{
    __shared__ unsigned short Sh[32 * 264];    // 16.9 KB
    __shared__ unsigned short Sl[32 * 264];    // 16.9 KB
    __shared__ float pmax[4][256];             // 4 KB
    __shared__ int nb[32];

    const int t = threadIdx.x, w = t >> 6, lane = t & 63;
    const int l15 = lane & 15, quad = lane >> 4;
    const int pl0 = blockIdx.x * 4;            // slab-local point base

    if (t < 32) {
        int n = nidx[(size_t)(pl0 + (t >> 3)) * KNN + (t & 7)];
        if ((unsigned)n >= (unsigned)SLABPTS) n = 0;
        nb[t] = n;
    }
    const float gm = g_gamma[t], bt = g_beta[t];
    __syncthreads();

    {
        float uval[4];
        #pragma unroll
        for (int p = 0; p < 4; ++p) uval[p] = u[(size_t)(pl0 + p) * 256 + t];
        for (int r = 0; r < 32; ++r) {
            const float sv = fmaxf(uval[r >> 3] + v[(size_t)nb[r] * 256 + t], 0.f);
            const float x = sv * gm + bt;
            unsigned short h, l;
            split2(x, h, l);
            Sh[r * 264 + t] = h;
            Sl[r * 264 + t] = l;
        }
    }
    __syncthreads();

    const int mt = w & 1, ch = w >> 1;
    f32x4 acc[8];
    #pragma unroll
    for (int nt = 0; nt < 8; ++nt) acc[nt] = (f32x4){0.f, 0.f, 0.f, 0.f};

    for (int s = 0; s < 8; ++s) {
        const int ao = (mt * 16 + l15) * 264 + s * 32 + quad * 8;
        const s16x8 ah = *(const s16x8*)&Sh[ao];
        const s16x8 al = *(const s16x8*)&Sl[ao];
        #pragma unroll
        for (int nt = 0; nt < 8; ++nt) {
            const int n = (ch * 8 + nt) * 16 + l15;
            const size_t bo = (size_t)n * 256 + s * 32 + quad * 8;
            const s16x8 bh = *(const s16x8*)(g2h + bo);
            const s16x8 bl = *(const s16x8*)(g2l + bo);
            acc[nt] = __builtin_amdgcn_mfma_f32_16x16x32_bf16(ah, bh, acc[nt], 0, 0, 0);
            acc[nt] = __builtin_amdgcn_mfma_f32_16x16x32_bf16(al, bh, acc[nt], 0, 0, 0);
            acc[nt] = __builtin_amdgcn_mfma_f32_16x16x32_bf16(ah, bl, acc[nt], 0, 0, 0);
        }
    }

    // reduce: lane's 4 regs are 4 rows of one point; xor-16 merges quad pairs
    #pragma unroll
    for (int nt = 0; nt < 8; ++nt) {
        float rm = fmaxf(fmaxf(acc[nt][0], acc[nt][1]), fmaxf(acc[nt][2], acc[nt][3]));
        rm = fmaxf(rm, __shfl_xor(rm, 16, 64));
        const int col = ch * 128 + nt * 16 + l15;
        if (quad == 0)      pmax[mt * 2][col] = rm;
        else if (quad == 2) pmax[mt * 2 + 1][col] = rm;
    }
    __syncthreads();

    const float bm = fmaxf(fmaxf(pmax[0][t], pmax[1][t]), fmaxf(pmax[2][t], pmax[3][t])) + gb2[t];
    const int cell = cell0 + (pl0 >> 9);
    const int slot = (pl0 & 511) >> 2;         // 0..127
    part[((size_t)cell * 128 + slot) * 256 + t] = bm;
}

// ---------------------------------------------------------------------------
// Kernel 6: reduce 128 partial maxes per cell, final MLP (f32), L2 normalize.
// ---------------------------------------------------------------------------
__global__ __launch_bounds__(256)
void k_final(const float* __restrict__ part,
             const float* __restrict__ lW1, const float* __restrict__ lb1,
             const float* __restrict__ lW2, const float* __restrict__ lb2,
             float* __restrict__ out)
{
    __shared__ float pooled[256];
    __shared__ float hid[256];
    __shared__ float red[4];

    const int b = blockIdx.x;
    const int t = threadIdx.x;

    float m = -3.4e38f;
    for (int s = 0; s < 128; ++s)
        m = fmaxf(m, part[((size_t)b * 128 + s) * 256 + t]);
    pooled[t] = m;
    __syncthreads();

    float h = lb1[t];
    for (int k = 0; k < 256; k += 4) {
        #pragma unroll
        for (int kk = 0; kk < 4; ++kk)
            h += pooled[k + kk] * lW1[(k + kk) * 256 + t];
    }
    hid[t] = fmaxf(h, 0.f);
    __syncthreads();

    float o = lb2[t];
    for (int k = 0; k < 256; k += 4) {
        #pragma unroll
        for (int kk = 0; kk < 4; ++kk)
            o += hid[k + kk] * lW2[(k + kk) * 256 + t];
    }

    float ss = o * o;
    #pragma unroll
    for (int s = 32; s > 0; s >>= 1) ss += __shfl_down(ss, s, 64);
    if ((t & 63) == 0) red[t >> 6] = ss;
    __syncthreads();
    const float tot = red[0] + red[1] + red[2] + red[3];
    const float rn = 1.f / fmaxf(sqrtf(tot), 1e-12f);
    out[b * 256 + t] = o * rn;
}

// ---------------------------------------------------------------------------
extern "C" void kernel_launch(void* const* d_in, const int* in_sizes, int n_in,
                              void* d_out, int out_size, void* d_ws, size_t ws_size,
                              hipStream_t stream)
{
    (void)n_in; (void)out_size; (void)ws_size;

    const float* class_table = (const float*)d_in[0];
    const float* cW1 = (const float*)d_in[1];
    const float* cb1 = (const float*)d_in[2];
    const float* cW2 = (const float*)d_in[3];
    const float* cb2 = (const float*)d_in[4];
    const float* pW1 = (const float*)d_in[5];
    const float* pb1 = (const float*)d_in[6];
    const float* pW2 = (const float*)d_in[7];
    const float* pb2 = (const float*)d_in[8];
    const float* mW  = (const float*)d_in[9];
    const float* mb  = (const float*)d_in[10];
    const float* gW1 = (const float*)d_in[11];
    const float* gb1 = (const float*)d_in[12];
    const float* g_gamma = (const float*)d_in[13];
    const float* g_beta  = (const float*)d_in[14];
    const float* gW2 = (const float*)d_in[15];
    const float* gb2 = (const float*)d_in[16];
    const float* lW1 = (const float*)d_in[17];
    const float* lb1 = (const float*)d_in[18];
    const float* lW2 = (const float*)d_in[19];
    const float* lb2 = (const float*)d_in[20];
    const float* positions = (const float*)d_in[21];
    const float* colors    = (const float*)d_in[22];
    const int*  cls        = (const int*)d_in[23];

    const int cstride = (in_sizes[23] == 2 * NTOT) ? 2 : 1;

    // workspace (bytes), peak ~35.4 MB (under proven-safe 47.3):
    //   part 8.4M | weights 1.6M | nidx 256K | sqn 32K | ehi/elo 8.4M |
    //   dist 16.8M == (u 8.4M | v 8.4M)   (per-slab, disjoint in time)
    char* base = (char*)d_ws;
    float*          part = (float*)(base + 0);                 //  8,388,608
    unsigned short* mWh  = (unsigned short*)(base + 8388608);
    unsigned short* mWl  = (unsigned short*)(base + 8781824);
    unsigned short* Wdh  = (unsigned short*)(base + 9175040);
    unsigned short* Wdl  = (unsigned short*)(base + 9306112);
    unsigned short* Wbh  = (unsigned short*)(base + 9437184);
    unsigned short* Wbl  = (unsigned short*)(base + 9568256);
    unsigned short* g2h  = (unsigned short*)(base + 9699328);
    unsigned short* g2l  = (unsigned short*)(base + 9830400);
    int*            nidx = (int*)(base + 9961472);             //    262,144
    float*          sqn  = (float*)(base + 10223616);          //     32,768
    unsigned short* ehi  = (unsigned short*)(base + 10256384); //  4,194,304
    unsigned short* elo  = (unsigned short*)(base + 14450688); //  4,194,304
    float*          dist = (float*)(base + 18644992);          // 16,777,216
    float*          u    = dist;                               //  8,388,608
    float*          v    = (float*)(base + 27033600);          //  8,388,608
    float* out = (float*)d_out;

    k_cvt<<<1536, 256, 0, stream>>>(mW, gW1, gW2, mWh, mWl, Wdh, Wdl, Wbh, Wbl, g2h, g2l);
    for (int s = 0; s < NSLAB; ++s) {
        k_embed<<<SLABPTS / 16, 256, 0, stream>>>(class_table, cW1, cb1, cW2, cb2,
                                                  pW1, pb1, pW2, pb2, mWh, mWl, mb,
                                                  positions, colors, cls, cstride,
                                                  ehi, elo, sqn, s * SLABPTS);
        k_gram<<<SLAB * 64, 256, 0, stream>>>(ehi, elo, sqn, dist);
        k_select<<<SLABPTS / 4, 256, 0, stream>>>(dist, nidx);
        k_uv<<<2 * SLABPTS / 32, 256, 0, stream>>>(ehi, elo, Wdh, Wdl, Wbh, Wbl, gb1, u, v);
        k_edge<<<SLABPTS / 4, 256, 0, stream>>>(u, v, nidx, g_gamma, g_beta,
                                                g2h, g2l, gb2, part, s * SLAB);
    }
    k_final<<<NB, 256, 0, stream>>>(part, lW1, lb1, lW2, lb2, out);
}

// Round 7
// 1254.541 us; speedup vs baseline: 1.3595x; 1.0084x over previous
//
#include <hip/hip_runtime.h>

#define EDIM 256
#define KNN 8
#define NB 64
#define NP 512
#define NTOT (NB * NP)
#define SLAB 16
#define NSLAB (NB / SLAB)
#define SLABPTS (SLAB * NP)   // 8192

typedef short s16x8 __attribute__((ext_vector_type(8)));
typedef float f32x4 __attribute__((ext_vector_type(4)));

__device__ __forceinline__ unsigned short f2b(float f) {
    unsigned u = __float_as_uint(f);
    u = (u + 0x7fffu + ((u >> 16) & 1u)) >> 16;   // RNE
    return (unsigned short)u;
}
__device__ __forceinline__ float b2f(unsigned short h) {
    return __uint_as_float(((unsigned)h) << 16);
}
__device__ __forceinline__ void split2(float x, unsigned short& h, unsigned short& l) {
    h = f2b(x);
    l = f2b(x - b2f(h));
}

// ---------------------------------------------------------------------------
// Kernel 0: weight prep -> transposed bf16 hi/lo pairs for MFMA B-operands.
// g2 is pre-folded with gamma: W2'[k][n] = gamma[k]*W2[k][n].
// hb[n] = beta @ W2[:,n] + gb2[n]  (f32, exact fold of the BN shift).
// ---------------------------------------------------------------------------
__global__ __launch_bounds__(256)
void k_cvt(const float* __restrict__ mW, const float* __restrict__ gW1,
           const float* __restrict__ gW2, const float* __restrict__ g_gamma,
           const float* __restrict__ g_beta, const float* __restrict__ gb2,
           unsigned short* __restrict__ mWh, unsigned short* __restrict__ mWl,
           unsigned short* __restrict__ Wdh, unsigned short* __restrict__ Wdl,
           unsigned short* __restrict__ Wbh, unsigned short* __restrict__ Wbl,
           unsigned short* __restrict__ g2h, unsigned short* __restrict__ g2l,
           float* __restrict__ hb)
{
    const int gid = blockIdx.x * 256 + threadIdx.x;
    unsigned short h, l;
    if (gid < 196608) {
        const int n = gid / 768, k = gid % 768;
        split2(mW[k * 256 + n], h, l);
        mWh[gid] = h; mWl[gid] = l;
    } else if (gid < 262144) {
        const int i = gid - 196608, n = i / 256, k = i % 256;
        split2(gW1[k * 256 + n] - gW1[(k + 256) * 256 + n], h, l);
        Wdh[i] = h; Wdl[i] = l;
    } else if (gid < 327680) {
        const int i = gid - 262144, n = i / 256, k = i % 256;
        split2(gW1[(k + 256) * 256 + n], h, l);
        Wbh[i] = h; Wbl[i] = l;
    } else if (gid < 393216) {
        const int i = gid - 327680, n = i / 256, k = i % 256;
        split2(g_gamma[k] * gW2[k * 256 + n], h, l);
        g2h[i] = h; g2l[i] = l;
    } else if (gid < 393472) {
        const int n = gid - 393216;
        float s = gb2[n];
        for (int k = 0; k < 256; ++k) s += g_beta[k] * gW2[k * 256 + n];
        hb[n] = s;
    }
}

// ---------------------------------------------------------------------------
// Kernel 1: per-object embeddings + merge GEMM (split-MFMA), 16 obj/block.
// B-fragments read DIRECTLY from global (L2-resident weights).
// ---------------------------------------------------------------------------
__global__ __launch_bounds__(256)
void k_embed(const float* __restrict__ class_table,
             const float* __restrict__ cW1, const float* __restrict__ cb1,
             const float* __restrict__ cW2, const float* __restrict__ cb2,
             const float* __restrict__ pW1, const float* __restrict__ pb1,
             const float* __restrict__ pW2, const float* __restrict__ pb2,
             const unsigned short* __restrict__ mWh, const unsigned short* __restrict__ mWl,
             const float* __restrict__ mb,
             const float* __restrict__ positions, const float* __restrict__ colors,
             const int* __restrict__ cls, const int cstride,
             unsigned short* __restrict__ ehi, unsigned short* __restrict__ elo,
             float* __restrict__ sqn, const int pbase)
{
    __shared__ unsigned short CVh[16 * 264];   // 8.4 KB  (one 256-k segment)
    __shared__ unsigned short CVl[16 * 264];   // 8.4 KB
    __shared__ float hid[2048];                // 8 KB: [16 obj][64] c | p
    __shared__ float sqpart[16][4];

    float* hidc = hid;
    float* hidp = hid + 1024;

    const int t = threadIdx.x;
    const int w = t >> 6, lane = t & 63;
    const int l15 = lane & 15, quad = lane >> 4;
    const int obase = blockIdx.x * 16;         // slab-local

    // --- step A: first layers (color/pos), 4 obj per wave, 4 units per lane
    {
        const int o = lane >> 4;
        const int objl = w * 4 + o;
        const int gobj = pbase + obase + objl;
        const float c0 = colors[gobj * 3], c1 = colors[gobj * 3 + 1], c2 = colors[gobj * 3 + 2];
        const float q0 = positions[gobj * 3], q1 = positions[gobj * 3 + 1], q2 = positions[gobj * 3 + 2];
        const int u0 = (lane & 15) * 4;
        #pragma unroll
        for (int uu = 0; uu < 4; ++uu) {
            const int u = u0 + uu;
            const float hc = cb1[u] + c0 * cW1[u] + c1 * cW1[64 + u] + c2 * cW1[128 + u];
            const float hp = pb1[u] + q0 * pW1[u] + q1 * pW1[64 + u] + q2 * pW1[128 + u];
            hidc[objl * 64 + u] = fmaxf(hc, 0.f);
            hidp[objl * 64 + u] = fmaxf(hp, 0.f);
        }
    }
    __syncthreads();

    // --- step B: second layers; lane owns channels 4*lane..+3 for wave's 4 objs
    float co[4][4], pe[4][4];
    {
        const float4 cb4 = *(const float4*)&cb2[lane * 4];
        const float4 pb4 = *(const float4*)&pb2[lane * 4];
        #pragma unroll
        for (int o = 0; o < 4; ++o) {
            co[o][0] = cb4.x; co[o][1] = cb4.y; co[o][2] = cb4.z; co[o][3] = cb4.w;
            pe[o][0] = pb4.x; pe[o][1] = pb4.y; pe[o][2] = pb4.z; pe[o][3] = pb4.w;
        }
        for (int j = 0; j < 64; ++j) {
            const float4 wc = *(const float4*)&cW2[j * 256 + lane * 4];
            const float4 wp = *(const float4*)&pW2[j * 256 + lane * 4];
            #pragma unroll
            for (int o = 0; o < 4; ++o) {
                const float hc = hidc[(w * 4 + o) * 64 + j];
                const float hp = hidp[(w * 4 + o) * 64 + j];
                co[o][0] += hc * wc.x; co[o][1] += hc * wc.y;
                co[o][2] += hc * wc.z; co[o][3] += hc * wc.w;
                pe[o][0] += hp * wp.x; pe[o][1] += hp * wp.y;
                pe[o][2] += hp * wp.z; pe[o][3] += hp * wp.w;
            }
        }
    }

    // --- step C: class embed + normalizations -> registers
    float cen[4][4], con[4][4], pen[4][4];
    #pragma unroll
    for (int o = 0; o < 4; ++o) {
        const int objl = w * 4 + o;
        const int gobj = pbase + obase + objl;
        int ci = cls[(size_t)gobj * cstride];
        if ((unsigned)ci > 30u) ci = 0;
        const float4 ce4 = *(const float4*)&class_table[ci * 256 + lane * 4];
        const float cev[4] = {ce4.x, ce4.y, ce4.z, ce4.w};
        float sce = 0.f, sco = 0.f, spe = 0.f;
        #pragma unroll
        for (int cc = 0; cc < 4; ++cc) {
            sce += cev[cc] * cev[cc];
            sco += co[o][cc] * co[o][cc];
            spe += pe[o][cc] * pe[o][cc];
        }
        #pragma unroll
        for (int s = 32; s > 0; s >>= 1) {
            sce += __shfl_xor(sce, s, 64);
            sco += __shfl_xor(sco, s, 64);
            spe += __shfl_xor(spe, s, 64);
        }
        const float rce = 1.f / fmaxf(sqrtf(sce), 1e-12f);
        const float rco = 1.f / fmaxf(sqrtf(sco), 1e-12f);
        const float rpe = 1.f / fmaxf(sqrtf(spe), 1e-12f);
        #pragma unroll
        for (int cc = 0; cc < 4; ++cc) {
            cen[o][cc] = cev[cc] * rce;
            con[o][cc] = co[o][cc] * rco;
            pen[o][cc] = pe[o][cc] * rpe;
        }
    }

    // --- step D: merge GEMM, 3 segments x 8 k-tiles, 3-pass split MFMA.
    f32x4 acc[4];
    #pragma unroll
    for (int i = 0; i < 4; ++i) acc[i] = (f32x4){0.f, 0.f, 0.f, 0.f};

    #pragma unroll
    for (int seg = 0; seg < 3; ++seg) {
        __syncthreads();   // previous segment's CV reads complete
        #pragma unroll
        for (int o = 0; o < 4; ++o) {
            const int row = w * 4 + o;
            #pragma unroll
            for (int cc = 0; cc < 4; ++cc) {
                const float val = (seg == 0) ? cen[o][cc] : (seg == 1) ? con[o][cc] : pen[o][cc];
                unsigned short h, l;
                split2(val, h, l);
                CVh[row * 264 + lane * 4 + cc] = h;
                CVl[row * 264 + lane * 4 + cc] = l;
            }
        }
        __syncthreads();
        for (int s = 0; s < 8; ++s) {
            const s16x8 ah = *(const s16x8*)&CVh[l15 * 264 + s * 32 + quad * 8];
            const s16x8 al = *(const s16x8*)&CVl[l15 * 264 + s * 32 + quad * 8];
            #pragma unroll
            for (int i = 0; i < 4; ++i) {
                const int n = (w * 4 + i) * 16 + l15;
                const size_t bo = (size_t)n * 768 + seg * 256 + s * 32 + quad * 8;
                const s16x8 bh = *(const s16x8*)(mWh + bo);
                const s16x8 bl = *(const s16x8*)(mWl + bo);
                acc[i] = __builtin_amdgcn_mfma_f32_16x16x32_bf16(ah, bh, acc[i], 0, 0, 0);
                acc[i] = __builtin_amdgcn_mfma_f32_16x16x32_bf16(al, bh, acc[i], 0, 0, 0);
                acc[i] = __builtin_amdgcn_mfma_f32_16x16x32_bf16(ah, bl, acc[i], 0, 0, 0);
            }
        }
    }

    // --- epilogue: +mb (f32), split-store emb, sqn from f32 e
    float rp[4] = {0.f, 0.f, 0.f, 0.f};
    #pragma unroll
    for (int i = 0; i < 4; ++i) {
        const int col = (w * 4 + i) * 16 + l15;
        const float mbv = mb[col];
        #pragma unroll
        for (int r = 0; r < 4; ++r) {
            const int row = quad * 4 + r;
            const float e = acc[i][r] + mbv;
            unsigned short h, l;
            split2(e, h, l);
            ehi[(size_t)(obase + row) * 256 + col] = h;
            elo[(size_t)(obase + row) * 256 + col] = l;
            rp[r] += e * e;
        }
    }
    #pragma unroll
    for (int s = 8; s > 0; s >>= 1) {
        #pragma unroll
        for (int r = 0; r < 4; ++r) rp[r] += __shfl_down(rp[r], s, 16);
    }
    if (l15 == 0) {
        #pragma unroll
        for (int r = 0; r < 4; ++r) sqpart[quad * 4 + r][w] = rp[r];
    }
    __syncthreads();
    if (t < 16) sqn[obase + t] = sqpart[t][0] + sqpart[t][1] + sqpart[t][2] + sqpart[t][3];
}

// ---------------------------------------------------------------------------
// Kernel 2: Gram/distance via 3-pass split MFMA, frags direct from ehi/elo.
// ---------------------------------------------------------------------------
__global__ __launch_bounds__(256)
void k_gram(const unsigned short* __restrict__ ehi, const unsigned short* __restrict__ elo,
            const float* __restrict__ sqn, float* __restrict__ dist)
{
    const int t = threadIdx.x, w = t >> 6, lane = t & 63;
    const int l15 = lane & 15, quad = lane >> 4;
    const int b_local = blockIdx.x >> 6;       // 0..15
    const int tile = blockIdx.x & 63;
    const int p0 = (tile >> 3) * 64, q0 = (tile & 7) * 64;
    const size_t cb = (size_t)b_local * NP;

    const size_t arow = (cb + p0 + 16 * w + l15) * 256 + quad * 8;
    const size_t brow = (cb + q0 + l15) * 256 + quad * 8;

    f32x4 acc[4];
    #pragma unroll
    for (int nt = 0; nt < 4; ++nt) acc[nt] = (f32x4){0.f, 0.f, 0.f, 0.f};

    for (int s = 0; s < 8; ++s) {
        const s16x8 ah = *(const s16x8*)(ehi + arow + s * 32);
        const s16x8 al = *(const s16x8*)(elo + arow + s * 32);
        #pragma unroll
        for (int nt = 0; nt < 4; ++nt) {
            const size_t bo = brow + (size_t)nt * 16 * 256 + s * 32;
            const s16x8 bh = *(const s16x8*)(ehi + bo);
            const s16x8 bl = *(const s16x8*)(elo + bo);
            acc[nt] = __builtin_amdgcn_mfma_f32_16x16x32_bf16(ah, bh, acc[nt], 0, 0, 0);
            acc[nt] = __builtin_amdgcn_mfma_f32_16x16x32_bf16(al, bh, acc[nt], 0, 0, 0);
            acc[nt] = __builtin_amdgcn_mfma_f32_16x16x32_bf16(ah, bl, acc[nt], 0, 0, 0);
        }
    }

    float sqp[4];
    #pragma unroll
    for (int r = 0; r < 4; ++r) sqp[r] = sqn[cb + p0 + 16 * w + quad * 4 + r];
    #pragma unroll
    for (int nt = 0; nt < 4; ++nt) {
        const int colq = q0 + nt * 16 + l15;
        const float sq_q = sqn[cb + colq];
        #pragma unroll
        for (int r = 0; r < 4; ++r) {
            const int rowp = p0 + 16 * w + quad * 4 + r;
            dist[(cb + rowp) * NP + colq] = (sqp[r] + sq_q) - 2.f * acc[nt][r];
        }
    }
}

// ---------------------------------------------------------------------------
// Kernel 3: top-8 smallest per point (ties -> lowest index). One wave/point.
// ---------------------------------------------------------------------------
__global__ __launch_bounds__(256)
void k_select(const float* __restrict__ dist, int* __restrict__ nidx)
{
    const int wv = threadIdx.x >> 6, lane = threadIdx.x & 63;
    const int p_sl = blockIdx.x * 4 + wv;          // 0..8191
    const float* row = dist + (size_t)p_sl * NP;

    float d[8]; int q[8];
    #pragma unroll
    for (int i = 0; i < 8; ++i) { q[i] = lane + 64 * i; d[i] = row[lane + 64 * i]; }

    for (int r = 0; r < KNN; ++r) {
        float bd = d[0]; int bq = q[0];
        #pragma unroll
        for (int i = 1; i < 8; ++i)
            if (d[i] < bd || (d[i] == bd && q[i] < bq)) { bd = d[i]; bq = q[i]; }
        #pragma unroll
        for (int s = 32; s > 0; s >>= 1) {
            const float od = __shfl_down(bd, s, 64);
            const int oq = __shfl_down(bq, s, 64);
            if (od < bd || (od == bd && oq < bq)) { bd = od; bq = oq; }
        }
        const int win = __shfl(bq, 0, 64);
        if (lane == 0) nidx[(size_t)p_sl * KNN + r] = ((p_sl >> 9) << 9) | win;
        if ((win & 63) == lane) {
            const int wi = win >> 6;
            #pragma unroll
            for (int i = 0; i < 8; ++i) if (wi == i) d[i] = 3.4e38f;
        }
    }
}

// ---------------------------------------------------------------------------
// Kernel 4: u = x@Wd+gb1, v = x@Wb via 3-pass split MFMA. 32 points/block;
// block id >> 8 picks u vs v. No LDS, no barriers.
// ---------------------------------------------------------------------------
__global__ __launch_bounds__(256)
void k_uv(const unsigned short* __restrict__ ehi, const unsigned short* __restrict__ elo,
          const unsigned short* __restrict__ Wdh, const unsigned short* __restrict__ Wdl,
          const unsigned short* __restrict__ Wbh, const unsigned short* __restrict__ Wbl,
          const float* __restrict__ gb1,
          float* __restrict__ u, float* __restrict__ v)
{
    const int t = threadIdx.x, w = t >> 6, lane = t & 63;
    const int l15 = lane & 15, quad = lane >> 4;
    const int isV = blockIdx.x >> 8;
    const int m0 = (blockIdx.x & 255) * 32;    // slab-local
    const unsigned short* Wh = isV ? Wbh : Wdh;
    const unsigned short* Wl = isV ? Wbl : Wdl;
    float* out = isV ? v : u;
    const int mt = w & 1, ch = w >> 1;

    const size_t arow = (size_t)(m0 + mt * 16 + l15) * 256 + quad * 8;

    f32x4 acc[8];
    #pragma unroll
    for (int nt = 0; nt < 8; ++nt) acc[nt] = (f32x4){0.f, 0.f, 0.f, 0.f};

    for (int s = 0; s < 8; ++s) {
        const s16x8 ah = *(const s16x8*)(ehi + arow + s * 32);
        const s16x8 al = *(const s16x8*)(elo + arow + s * 32);
        #pragma unroll
        for (int nt = 0; nt < 8; ++nt) {
            const int n = (ch * 8 + nt) * 16 + l15;
            const size_t bo = (size_t)n * 256 + s * 32 + quad * 8;
            const s16x8 bh = *(const s16x8*)(Wh + bo);
            const s16x8 bl = *(const s16x8*)(Wl + bo);
            acc[nt] = __builtin_amdgcn_mfma_f32_16x16x32_bf16(ah, bh, acc[nt], 0, 0, 0);
            acc[nt] = __builtin_amdgcn_mfma_f32_16x16x32_bf16(al, bh, acc[nt], 0, 0, 0);
            acc[nt] = __builtin_amdgcn_mfma_f32_16x16x32_bf16(ah, bl, acc[nt], 0, 0, 0);
        }
    }

    #pragma unroll
    for (int nt = 0; nt < 8; ++nt) {
        const int col = (ch * 8 + nt) * 16 + l15;
        const float bias = isV ? 0.f : gb1[col];
        #pragma unroll
        for (int r = 0; r < 4; ++r) {
            const int row = mt * 16 + quad * 4 + r;
            out[(size_t)(m0 + row) * 256 + col] = acc[nt][r] + bias;
        }
    }
}

// ---------------------------------------------------------------------------
// Kernel 5: edge GEMM + max aggregation. 8 points (64 edges)/block, 16 edges
// per wave, full N=256 per wave. gamma/beta pre-folded into W2'/hbias, so
// A-frags (relu(u+v), split hi/lo) are built IN REGISTERS from f32 gathers —
// no S in LDS, no K-loop barriers. XCD-swizzled so u/v stay in per-XCD L2.
// ---------------------------------------------------------------------------
__global__ __launch_bounds__(256)
void k_edge(const float* __restrict__ u, const float* __restrict__ v,
            const int* __restrict__ nidx,
            const unsigned short* __restrict__ g2h, const unsigned short* __restrict__ g2l,
            const float* __restrict__ hb,
            float* __restrict__ part, const int cell0)
{
    __shared__ float pmax[8][256];             // 8 KB
    __shared__ int nb[64];

    const int t = threadIdx.x, w = t >> 6, lane = t & 63;
    const int l15 = lane & 15, quad = lane >> 4;

    // XCD swizzle: blockIdx%8 ~ XCD; give each XCD 2 whole cells.
    const int b = blockIdx.x;
    const int xcd = b & 7, rest = b >> 3;      // rest 0..127
    const int celll = xcd * 2 + (rest >> 6);   // slab-local cell 0..15
    const int pl0 = celll * NP + (rest & 63) * 8;   // slab-local point base

    if (t < 64) {
        int n = nidx[(size_t)(pl0 + (t >> 3)) * KNN + (t & 7)];
        if ((unsigned)n >= (unsigned)SLABPTS) n = 0;
        nb[t] = n;
    }
    __syncthreads();

    const int e = w * 16 + l15;                // edge within block 0..63
    const int vrow = nb[e];
    const int urow = pl0 + (e >> 3);

    f32x4 acc[16];
    #pragma unroll
    for (int nt = 0; nt < 16; ++nt) acc[nt] = (f32x4){0.f, 0.f, 0.f, 0.f};

    for (int s = 0; s < 8; ++s) {
        const int k0 = s * 32 + quad * 8;
        const float4 va = *(const float4*)(v + (size_t)vrow * 256 + k0);
        const float4 vb = *(const float4*)(v + (size_t)vrow * 256 + k0 + 4);
        const float4 ua = *(const float4*)(u + (size_t)urow * 256 + k0);
        const float4 ub = *(const float4*)(u + (size_t)urow * 256 + k0 + 4);
        const float sv[8] = {
            fmaxf(ua.x + va.x, 0.f), fmaxf(ua.y + va.y, 0.f),
            fmaxf(ua.z + va.z, 0.f), fmaxf(ua.w + va.w, 0.f),
            fmaxf(ub.x + vb.x, 0.f), fmaxf(ub.y + vb.y, 0.f),
            fmaxf(ub.z + vb.z, 0.f), fmaxf(ub.w + vb.w, 0.f)};
        union { s16x8 vv; unsigned short us[8]; } pah, pal;
        #pragma unroll
        for (int j = 0; j < 8; ++j) {
            unsigned short h, l;
            split2(sv[j], h, l);
            pah.us[j] = h; pal.us[j] = l;
        }
        const s16x8 ah = pah.vv, al = pal.vv;
        #pragma unroll
        for (int nt = 0; nt < 16; ++nt) {
            const size_t bo = (size_t)(nt * 16 + l15) * 256 + k0;
            const s16x8 bh = *(const s16x8*)(g2h + bo);
            const s16x8 bl = *(const s16x8*)(g2l + bo);
            acc[nt] = __builtin_amdgcn_mfma_f32_16x16x32_bf16(ah, bh, acc[nt], 0, 0, 0);
            acc[nt] = __builtin_amdgcn_mfma_f32_16x16x32_bf16(al, bh, acc[nt], 0, 0, 0);
            acc[nt] = __builtin_amdgcn_mfma_f32_16x16x32_bf16(ah, bl, acc[nt], 0, 0, 0);
        }
    }

    // C rows quad*4+r: quads 0,1 -> point 2w; quads 2,3 -> point 2w+1.
    #pragma unroll
    for (int nt = 0; nt < 16; ++nt) {
        float rm = fmaxf(fmaxf(acc[nt][0], acc[nt][1]), fmaxf(acc[nt][2], acc[nt][3]));
        rm = fmaxf(rm, __shfl_xor(rm, 16, 64));
        if ((quad & 1) == 0) pmax[2 * w + (quad >> 1)][nt * 16 + l15] = rm;
    }
    __syncthreads();

    float bm = pmax[0][t];
    #pragma unroll
    for (int p = 1; p < 8; ++p) bm = fmaxf(bm, pmax[p][t]);
    bm += hb[t];
    const int cell = cell0 + celll;
    const int slot = rest & 63;                // block within cell, 0..63
    part[((size_t)cell * 64 + slot) * 256 + t] = bm;
}

// ---------------------------------------------------------------------------
// Kernel 6: reduce 64 partial maxes per cell, final MLP (f32), L2 normalize.
// ---------------------------------------------------------------------------
__global__ __launch_bounds__(256)
void k_final(const float* __restrict__ part,
             const float* __restrict__ lW1, const float* __restrict__ lb1,
             const float* __restrict__ lW2, const float* __restrict__ lb2,
             float* __restrict__ out)
{
    __shared__ float pooled[256];
    __shared__ float hid[256];
    __shared__ float red[4];

    const int b = blockIdx.x;
    const int t = threadIdx.x;

    float m = -3.4e38f;
    for (int s = 0; s < 64; ++s)
        m = fmaxf(m, part[((size_t)b * 64 + s) * 256 + t]);
    pooled[t] = m;
    __syncthreads();

    float h = lb1[t];
    for (int k = 0; k < 256; k += 4) {
        #pragma unroll
        for (int kk = 0; kk < 4; ++kk)
            h += pooled[k + kk] * lW1[(k + kk) * 256 + t];
    }
    hid[t] = fmaxf(h, 0.f);
    __syncthreads();

    float o = lb2[t];
    for (int k = 0; k < 256; k += 4) {
        #pragma unroll
        for (int kk = 0; kk < 4; ++kk)
            o += hid[k + kk] * lW2[(k + kk) * 256 + t];
    }

    float ss = o * o;
    #pragma unroll
    for (int s = 32; s > 0; s >>= 1) ss += __shfl_down(ss, s, 64);
    if ((t & 63) == 0) red[t >> 6] = ss;
    __syncthreads();
    const float tot = red[0] + red[1] + red[2] + red[3];
    const float rn = 1.f / fmaxf(sqrtf(tot), 1e-12f);
    out[b * 256 + t] = o * rn;
}

// ---------------------------------------------------------------------------
extern "C" void kernel_launch(void* const* d_in, const int* in_sizes, int n_in,
                              void* d_out, int out_size, void* d_ws, size_t ws_size,
                              hipStream_t stream)
{
    (void)n_in; (void)out_size; (void)ws_size;

    const float* class_table = (const float*)d_in[0];
    const float* cW1 = (const float*)d_in[1];
    const float* cb1 = (const float*)d_in[2];
    const float* cW2 = (const float*)d_in[3];
    const float* cb2 = (const float*)d_in[4];
    const float* pW1 = (const float*)d_in[5];
    const float* pb1 = (const float*)d_in[6];
    const float* pW2 = (const float*)d_in[7];
    const float* pb2 = (const float*)d_in[8];
    const float* mW  = (const float*)d_in[9];
    const float* mb  = (const float*)d_in[10];
    const float* gW1 = (const float*)d_in[11];
    const float* gb1 = (const float*)d_in[12];
    const float* g_gamma = (const float*)d_in[13];
    const float* g_beta  = (const float*)d_in[14];
    const float* gW2 = (const float*)d_in[15];
    const float* gb2 = (const float*)d_in[16];
    const float* lW1 = (const float*)d_in[17];
    const float* lb1 = (const float*)d_in[18];
    const float* lW2 = (const float*)d_in[19];
    const float* lb2 = (const float*)d_in[20];
    const float* positions = (const float*)d_in[21];
    const float* colors    = (const float*)d_in[22];
    const int*  cls        = (const int*)d_in[23];

    const int cstride = (in_sizes[23] == 2 * NTOT) ? 2 : 1;

    // workspace (bytes), peak ~35.4 MB (under proven-safe 47.3):
    char* base = (char*)d_ws;
    float*          part = (float*)(base + 0);                 //  4 MB used
    unsigned short* mWh  = (unsigned short*)(base + 8388608);
    unsigned short* mWl  = (unsigned short*)(base + 8781824);
    unsigned short* Wdh  = (unsigned short*)(base + 9175040);
    unsigned short* Wdl  = (unsigned short*)(base + 9306112);
    unsigned short* Wbh  = (unsigned short*)(base + 9437184);
    unsigned short* Wbl  = (unsigned short*)(base + 9568256);
    unsigned short* g2h  = (unsigned short*)(base + 9699328);
    unsigned short* g2l  = (unsigned short*)(base + 9830400);
    int*            nidx = (int*)(base + 9961472);             //    262,144
    float*          sqn  = (float*)(base + 10223616);          //     32,768
    unsigned short* ehi  = (unsigned short*)(base + 10256384); //  4,194,304
    unsigned short* elo  = (unsigned short*)(base + 14450688); //  4,194,304
    float*          dist = (float*)(base + 18644992);          // 16,777,216
    float*          u    = dist;                               //  8,388,608
    float*          v    = (float*)(base + 27033600);          //  8,388,608
    float*          hb   = (float*)(base + 35422208);          //      1,024
    float* out = (float*)d_out;

    k_cvt<<<1537, 256, 0, stream>>>(mW, gW1, gW2, g_gamma, g_beta, gb2,
                                    mWh, mWl, Wdh, Wdl, Wbh, Wbl, g2h, g2l, hb);
    for (int s = 0; s < NSLAB; ++s) {
        k_embed<<<SLABPTS / 16, 256, 0, stream>>>(class_table, cW1, cb1, cW2, cb2,
                                                  pW1, pb1, pW2, pb2, mWh, mWl, mb,
                                                  positions, colors, cls, cstride,
                                                  ehi, elo, sqn, s * SLABPTS);
        k_gram<<<SLAB * 64, 256, 0, stream>>>(ehi, elo, sqn, dist);
        k_select<<<SLABPTS / 4, 256, 0, stream>>>(dist, nidx);
        k_uv<<<2 * SLABPTS / 32, 256, 0, stream>>>(ehi, elo, Wdh, Wdl, Wbh, Wbl, gb1, u, v);
        k_edge<<<SLABPTS / 8, 256, 0, stream>>>(u, v, nidx, g2h, g2l, hb,
                                                part, s * SLAB);
    }
    k_final<<<NB, 256, 0, stream>>>(part, lW1, lb1, lW2, lb2, out);
}

// Round 8
// 1097.275 us; speedup vs baseline: 1.5543x; 1.1433x over previous
//
#include <hip/hip_runtime.h>

#define EDIM 256
#define KNN 8
#define NB 64
#define NP 512
#define NTOT (NB * NP)
#define SLAB 16
#define NSLAB (NB / SLAB)
#define SLABPTS (SLAB * NP)   // 8192

typedef short s16x8 __attribute__((ext_vector_type(8)));
typedef float f32x4 __attribute__((ext_vector_type(4)));

__device__ __forceinline__ unsigned short f2b(float f) {
    unsigned u = __float_as_uint(f);
    u = (u + 0x7fffu + ((u >> 16) & 1u)) >> 16;   // RNE
    return (unsigned short)u;
}
__device__ __forceinline__ float b2f(unsigned short h) {
    return __uint_as_float(((unsigned)h) << 16);
}
__device__ __forceinline__ void split2(float x, unsigned short& h, unsigned short& l) {
    h = f2b(x);
    l = f2b(x - b2f(h));
}

// ---------------------------------------------------------------------------
// Kernel 0: weight prep -> transposed bf16 hi/lo pairs for MFMA B-operands.
// g2 pre-folded with gamma; hb = beta @ W2 + gb2 (exact BN-shift fold).
// ---------------------------------------------------------------------------
__global__ __launch_bounds__(256)
void k_cvt(const float* __restrict__ mW, const float* __restrict__ gW1,
           const float* __restrict__ gW2, const float* __restrict__ g_gamma,
           const float* __restrict__ g_beta, const float* __restrict__ gb2,
           unsigned short* __restrict__ mWh, unsigned short* __restrict__ mWl,
           unsigned short* __restrict__ Wdh, unsigned short* __restrict__ Wdl,
           unsigned short* __restrict__ Wbh, unsigned short* __restrict__ Wbl,
           unsigned short* __restrict__ g2h, unsigned short* __restrict__ g2l,
           float* __restrict__ hb)
{
    const int gid = blockIdx.x * 256 + threadIdx.x;
    unsigned short h, l;
    if (gid < 196608) {
        const int n = gid / 768, k = gid % 768;
        split2(mW[k * 256 + n], h, l);
        mWh[gid] = h; mWl[gid] = l;
    } else if (gid < 262144) {
        const int i = gid - 196608, n = i / 256, k = i % 256;
        split2(gW1[k * 256 + n] - gW1[(k + 256) * 256 + n], h, l);
        Wdh[i] = h; Wdl[i] = l;
    } else if (gid < 327680) {
        const int i = gid - 262144, n = i / 256, k = i % 256;
        split2(gW1[(k + 256) * 256 + n], h, l);
        Wbh[i] = h; Wbl[i] = l;
    } else if (gid < 393216) {
        const int i = gid - 327680, n = i / 256, k = i % 256;
        split2(g_gamma[k] * gW2[k * 256 + n], h, l);
        g2h[i] = h; g2l[i] = l;
    } else if (gid < 393472) {
        const int n = gid - 393216;
        float s = gb2[n];
        for (int k = 0; k < 256; ++k) s += g_beta[k] * gW2[k * 256 + n];
        hb[n] = s;
    }
}

// ---------------------------------------------------------------------------
// Kernel 1: per-object embeddings + merge GEMM (split-MFMA), 16 obj/block.
// ---------------------------------------------------------------------------
__global__ __launch_bounds__(256)
void k_embed(const float* __restrict__ class_table,
             const float* __restrict__ cW1, const float* __restrict__ cb1,
             const float* __restrict__ cW2, const float* __restrict__ cb2,
             const float* __restrict__ pW1, const float* __restrict__ pb1,
             const float* __restrict__ pW2, const float* __restrict__ pb2,
             const unsigned short* __restrict__ mWh, const unsigned short* __restrict__ mWl,
             const float* __restrict__ mb,
             const float* __restrict__ positions, const float* __restrict__ colors,
             const int* __restrict__ cls, const int cstride,
             unsigned short* __restrict__ ehi, unsigned short* __restrict__ elo,
             float* __restrict__ sqn, const int pbase)
{
    __shared__ unsigned short CVh[16 * 264];
    __shared__ unsigned short CVl[16 * 264];
    __shared__ float hid[2048];
    __shared__ float sqpart[16][4];

    float* hidc = hid;
    float* hidp = hid + 1024;

    const int t = threadIdx.x;
    const int w = t >> 6, lane = t & 63;
    const int l15 = lane & 15, quad = lane >> 4;
    const int obase = blockIdx.x * 16;

    {
        const int o = lane >> 4;
        const int objl = w * 4 + o;
        const int gobj = pbase + obase + objl;
        const float c0 = colors[gobj * 3], c1 = colors[gobj * 3 + 1], c2 = colors[gobj * 3 + 2];
        const float q0 = positions[gobj * 3], q1 = positions[gobj * 3 + 1], q2 = positions[gobj * 3 + 2];
        const int u0 = (lane & 15) * 4;
        #pragma unroll
        for (int uu = 0; uu < 4; ++uu) {
            const int u = u0 + uu;
            const float hc = cb1[u] + c0 * cW1[u] + c1 * cW1[64 + u] + c2 * cW1[128 + u];
            const float hp = pb1[u] + q0 * pW1[u] + q1 * pW1[64 + u] + q2 * pW1[128 + u];
            hidc[objl * 64 + u] = fmaxf(hc, 0.f);
            hidp[objl * 64 + u] = fmaxf(hp, 0.f);
        }
    }
    __syncthreads();

    float co[4][4], pe[4][4];
    {
        const float4 cb4 = *(const float4*)&cb2[lane * 4];
        const float4 pb4 = *(const float4*)&pb2[lane * 4];
        #pragma unroll
        for (int o = 0; o < 4; ++o) {
            co[o][0] = cb4.x; co[o][1] = cb4.y; co[o][2] = cb4.z; co[o][3] = cb4.w;
            pe[o][0] = pb4.x; pe[o][1] = pb4.y; pe[o][2] = pb4.z; pe[o][3] = pb4.w;
        }
        for (int j = 0; j < 64; ++j) {
            const float4 wc = *(const float4*)&cW2[j * 256 + lane * 4];
            const float4 wp = *(const float4*)&pW2[j * 256 + lane * 4];
            #pragma unroll
            for (int o = 0; o < 4; ++o) {
                const float hc = hidc[(w * 4 + o) * 64 + j];
                const float hp = hidp[(w * 4 + o) * 64 + j];
                co[o][0] += hc * wc.x; co[o][1] += hc * wc.y;
                co[o][2] += hc * wc.z; co[o][3] += hc * wc.w;
                pe[o][0] += hp * wp.x; pe[o][1] += hp * wp.y;
                pe[o][2] += hp * wp.z; pe[o][3] += hp * wp.w;
            }
        }
    }

    float cen[4][4], con[4][4], pen[4][4];
    #pragma unroll
    for (int o = 0; o < 4; ++o) {
        const int objl = w * 4 + o;
        const int gobj = pbase + obase + objl;
        int ci = cls[(size_t)gobj * cstride];
        if ((unsigned)ci > 30u) ci = 0;
        const float4 ce4 = *(const float4*)&class_table[ci * 256 + lane * 4];
        const float cev[4] = {ce4.x, ce4.y, ce4.z, ce4.w};
        float sce = 0.f, sco = 0.f, spe = 0.f;
        #pragma unroll
        for (int cc = 0; cc < 4; ++cc) {
            sce += cev[cc] * cev[cc];
            sco += co[o][cc] * co[o][cc];
            spe += pe[o][cc] * pe[o][cc];
        }
        #pragma unroll
        for (int s = 32; s > 0; s >>= 1) {
            sce += __shfl_xor(sce, s, 64);
            sco += __shfl_xor(sco, s, 64);
            spe += __shfl_xor(spe, s, 64);
        }
        const float rce = 1.f / fmaxf(sqrtf(sce), 1e-12f);
        const float rco = 1.f / fmaxf(sqrtf(sco), 1e-12f);
        const float rpe = 1.f / fmaxf(sqrtf(spe), 1e-12f);
        #pragma unroll
        for (int cc = 0; cc < 4; ++cc) {
            cen[o][cc] = cev[cc] * rce;
            con[o][cc] = co[o][cc] * rco;
            pen[o][cc] = pe[o][cc] * rpe;
        }
    }

    f32x4 acc[4];
    #pragma unroll
    for (int i = 0; i < 4; ++i) acc[i] = (f32x4){0.f, 0.f, 0.f, 0.f};

    #pragma unroll
    for (int seg = 0; seg < 3; ++seg) {
        __syncthreads();
        #pragma unroll
        for (int o = 0; o < 4; ++o) {
            const int row = w * 4 + o;
            #pragma unroll
            for (int cc = 0; cc < 4; ++cc) {
                const float val = (seg == 0) ? cen[o][cc] : (seg == 1) ? con[o][cc] : pen[o][cc];
                unsigned short h, l;
                split2(val, h, l);
                CVh[row * 264 + lane * 4 + cc] = h;
                CVl[row * 264 + lane * 4 + cc] = l;
            }
        }
        __syncthreads();
        for (int s = 0; s < 8; ++s) {
            const s16x8 ah = *(const s16x8*)&CVh[l15 * 264 + s * 32 + quad * 8];
            const s16x8 al = *(const s16x8*)&CVl[l15 * 264 + s * 32 + quad * 8];
            #pragma unroll
            for (int i = 0; i < 4; ++i) {
                const int n = (w * 4 + i) * 16 + l15;
                const size_t bo = (size_t)n * 768 + seg * 256 + s * 32 + quad * 8;
                const s16x8 bh = *(const s16x8*)(mWh + bo);
                const s16x8 bl = *(const s16x8*)(mWl + bo);
                acc[i] = __builtin_amdgcn_mfma_f32_16x16x32_bf16(ah, bh, acc[i], 0, 0, 0);
                acc[i] = __builtin_amdgcn_mfma_f32_16x16x32_bf16(al, bh, acc[i], 0, 0, 0);
                acc[i] = __builtin_amdgcn_mfma_f32_16x16x32_bf16(ah, bl, acc[i], 0, 0, 0);
            }
        }
    }

    float rp[4] = {0.f, 0.f, 0.f, 0.f};
    #pragma unroll
    for (int i = 0; i < 4; ++i) {
        const int col = (w * 4 + i) * 16 + l15;
        const float mbv = mb[col];
        #pragma unroll
        for (int r = 0; r < 4; ++r) {
            const int row = quad * 4 + r;
            const float e = acc[i][r] + mbv;
            unsigned short h, l;
            split2(e, h, l);
            ehi[(size_t)(obase + row) * 256 + col] = h;
            elo[(size_t)(obase + row) * 256 + col] = l;
            rp[r] += e * e;
        }
    }
    #pragma unroll
    for (int s = 8; s > 0; s >>= 1) {
        #pragma unroll
        for (int r = 0; r < 4; ++r) rp[r] += __shfl_down(rp[r], s, 16);
    }
    if (l15 == 0) {
        #pragma unroll
        for (int r = 0; r < 4; ++r) sqpart[quad * 4 + r][w] = rp[r];
    }
    __syncthreads();
    if (t < 16) sqn[obase + t] = sqpart[t][0] + sqpart[t][1] + sqpart[t][2] + sqpart[t][3];
}

// ---------------------------------------------------------------------------
// Kernel 2: Gram/distance via 3-pass split MFMA, frags direct from ehi/elo.
// ---------------------------------------------------------------------------
__global__ __launch_bounds__(256)
void k_gram(const unsigned short* __restrict__ ehi, const unsigned short* __restrict__ elo,
            const float* __restrict__ sqn, float* __restrict__ dist)
{
    const int t = threadIdx.x, w = t >> 6, lane = t & 63;
    const int l15 = lane & 15, quad = lane >> 4;
    const int b_local = blockIdx.x >> 6;       // 0..15
    const int tile = blockIdx.x & 63;
    const int p0 = (tile >> 3) * 64, q0 = (tile & 7) * 64;
    const size_t cb = (size_t)b_local * NP;

    const size_t arow = (cb + p0 + 16 * w + l15) * 256 + quad * 8;
    const size_t brow = (cb + q0 + l15) * 256 + quad * 8;

    f32x4 acc[4];
    #pragma unroll
    for (int nt = 0; nt < 4; ++nt) acc[nt] = (f32x4){0.f, 0.f, 0.f, 0.f};

    for (int s = 0; s < 8; ++s) {
        const s16x8 ah = *(const s16x8*)(ehi + arow + s * 32);
        const s16x8 al = *(const s16x8*)(elo + arow + s * 32);
        #pragma unroll
        for (int nt = 0; nt < 4; ++nt) {
            const size_t bo = brow + (size_t)nt * 16 * 256 + s * 32;
            const s16x8 bh = *(const s16x8*)(ehi + bo);
            const s16x8 bl = *(const s16x8*)(elo + bo);
            acc[nt] = __builtin_amdgcn_mfma_f32_16x16x32_bf16(ah, bh, acc[nt], 0, 0, 0);
            acc[nt] = __builtin_amdgcn_mfma_f32_16x16x32_bf16(al, bh, acc[nt], 0, 0, 0);
            acc[nt] = __builtin_amdgcn_mfma_f32_16x16x32_bf16(ah, bl, acc[nt], 0, 0, 0);
        }
    }

    float sqp[4];
    #pragma unroll
    for (int r = 0; r < 4; ++r) sqp[r] = sqn[cb + p0 + 16 * w + quad * 4 + r];
    #pragma unroll
    for (int nt = 0; nt < 4; ++nt) {
        const int colq = q0 + nt * 16 + l15;
        const float sq_q = sqn[cb + colq];
        #pragma unroll
        for (int r = 0; r < 4; ++r) {
            const int rowp = p0 + 16 * w + quad * 4 + r;
            dist[(cb + rowp) * NP + colq] = (sqp[r] + sq_q) - 2.f * acc[nt][r];
        }
    }
}

// ---------------------------------------------------------------------------
// Kernel 3: top-8 smallest per point (ties -> lowest index). One wave/point.
// ---------------------------------------------------------------------------
__global__ __launch_bounds__(256)
void k_select(const float* __restrict__ dist, int* __restrict__ nidx)
{
    const int wv = threadIdx.x >> 6, lane = threadIdx.x & 63;
    const int p_sl = blockIdx.x * 4 + wv;          // 0..8191
    const float* row = dist + (size_t)p_sl * NP;

    float d[8]; int q[8];
    #pragma unroll
    for (int i = 0; i < 8; ++i) { q[i] = lane + 64 * i; d[i] = row[lane + 64 * i]; }

    for (int r = 0; r < KNN; ++r) {
        float bd = d[0]; int bq = q[0];
        #pragma unroll
        for (int i = 1; i < 8; ++i)
            if (d[i] < bd || (d[i] == bd && q[i] < bq)) { bd = d[i]; bq = q[i]; }
        #pragma unroll
        for (int s = 32; s > 0; s >>= 1) {
            const float od = __shfl_down(bd, s, 64);
            const int oq = __shfl_down(bq, s, 64);
            if (od < bd || (od == bd && oq < bq)) { bd = od; bq = oq; }
        }
        const int win = __shfl(bq, 0, 64);
        if (lane == 0) nidx[(size_t)p_sl * KNN + r] = ((p_sl >> 9) << 9) | win;
        if ((win & 63) == lane) {
            const int wi = win >> 6;
            #pragma unroll
            for (int i = 0; i < 8; ++i) if (wi == i) d[i] = 3.4e38f;
        }
    }
}

// ---------------------------------------------------------------------------
// Kernel 4: u = x@Wd+gb1, v = x@Wb via 3-pass split MFMA. 32 points/block.
// ---------------------------------------------------------------------------
__global__ __launch_bounds__(256)
void k_uv(const unsigned short* __restrict__ ehi, const unsigned short* __restrict__ elo,
          const unsigned short* __restrict__ Wdh, const unsigned short* __restrict__ Wdl,
          const unsigned short* __restrict__ Wbh, const unsigned short* __restrict__ Wbl,
          const float* __restrict__ gb1,
          float* __restrict__ u, float* __restrict__ v)
{
    const int t = threadIdx.x, w = t >> 6, lane = t & 63;
    const int l15 = lane & 15, quad = lane >> 4;
    const int isV = blockIdx.x >> 8;
    const int m0 = (blockIdx.x & 255) * 32;    // slab-local
    const unsigned short* Wh = isV ? Wbh : Wdh;
    const unsigned short* Wl = isV ? Wbl : Wdl;
    float* out = isV ? v : u;
    const int mt = w & 1, ch = w >> 1;

    const size_t arow = (size_t)(m0 + mt * 16 + l15) * 256 + quad * 8;

    f32x4 acc[8];
    #pragma unroll
    for (int nt = 0; nt < 8; ++nt) acc[nt] = (f32x4){0.f, 0.f, 0.f, 0.f};

    for (int s = 0; s < 8; ++s) {
        const s16x8 ah = *(const s16x8*)(ehi + arow + s * 32);
        const s16x8 al = *(const s16x8*)(elo + arow + s * 32);
        #pragma unroll
        for (int nt = 0; nt < 8; ++nt) {
            const int n = (ch * 8 + nt) * 16 + l15;
            const size_t bo = (size_t)n * 256 + s * 32 + quad * 8;
            const s16x8 bh = *(const s16x8*)(Wh + bo);
            const s16x8 bl = *(const s16x8*)(Wl + bo);
            acc[nt] = __builtin_amdgcn_mfma_f32_16x16x32_bf16(ah, bh, acc[nt], 0, 0, 0);
            acc[nt] = __builtin_amdgcn_mfma_f32_16x16x32_bf16(al, bh, acc[nt], 0, 0, 0);
            acc[nt] = __builtin_amdgcn_mfma_f32_16x16x32_bf16(ah, bl, acc[nt], 0, 0, 0);
        }
    }

    #pragma unroll
    for (int nt = 0; nt < 8; ++nt) {
        const int col = (ch * 8 + nt) * 16 + l15;
        const float bias = isV ? 0.f : gb1[col];
        #pragma unroll
        for (int r = 0; r < 4; ++r) {
            const int row = mt * 16 + quad * 4 + r;
            out[(size_t)(m0 + row) * 256 + col] = acc[nt][r] + bias;
        }
    }
}

// ---------------------------------------------------------------------------
// Kernel 5: edge GEMM + max aggregation. 8 points (64 edges)/block.
// A (relu(u+v) hi/lo) and B (gamma-folded W2 hi/lo) are staged in LDS once
// per block per k-step; waves split the N dim (64 cols each) so LDS traffic
// equals staged bytes. Global loads for step s+1 prefetched into registers
// during step-s MFMAs. 2 blocks/CU (59.6 KB LDS).
// ---------------------------------------------------------------------------
__global__ __launch_bounds__(256)
void k_edge(const float* __restrict__ u, const float* __restrict__ v,
            const int* __restrict__ nidx,
            const unsigned short* __restrict__ g2h, const unsigned short* __restrict__ g2l,
            const float* __restrict__ hb,
            float* __restrict__ part, const int cell0)
{
    // LDS map (ushort indices): BH 0..10239 (row n, stride 40),
    // BL 10240.., AH 20480.. (row e, stride 40), AL 23040..25599.
    __shared__ unsigned short sm[25600];       // 51.2 KB
    __shared__ float pmax[8][256];             // 8 KB
    __shared__ int nb[64];

    const int t = threadIdx.x, w = t >> 6, lane = t & 63;
    const int l15 = lane & 15, quad = lane >> 4;

    // XCD swizzle: blockIdx%8 ~ XCD; 2 whole cells per XCD.
    const int b = blockIdx.x;
    const int xcd = b & 7, rest = b >> 3;      // rest 0..127
    const int celll = xcd * 2 + (rest >> 6);   // slab-local cell 0..15
    const int pl0 = celll * NP + (rest & 63) * 8;

    if (t < 64) {
        int n = nidx[(size_t)(pl0 + (t >> 3)) * KNN + (t & 7)];
        if ((unsigned)n >= (unsigned)SLABPTS) n = 0;
        nb[t] = n;
    }
    __syncthreads();

    // staging roles: thread t stages B row n=t; and A for edge e=t>>2, k-chunk kq=t&3
    const int e = t >> 2, kq = t & 3;
    const int urow = pl0 + (e >> 3);
    const int vrow = nb[e];

    uint4 pbh[4], pbl[4], pah, pal;
    #define PREFETCH(S)                                                          \
    {                                                                            \
        const int k0 = (S) * 32;                                                 \
        _Pragma("unroll")                                                        \
        for (int i = 0; i < 4; ++i) {                                            \
            pbh[i] = *(const uint4*)(g2h + (size_t)t * 256 + k0 + i * 8);        \
            pbl[i] = *(const uint4*)(g2l + (size_t)t * 256 + k0 + i * 8);        \
        }                                                                        \
        const int ka = k0 + kq * 8;                                              \
        const float4 ua = *(const float4*)(u + (size_t)urow * 256 + ka);         \
        const float4 ub = *(const float4*)(u + (size_t)urow * 256 + ka + 4);     \
        const float4 va = *(const float4*)(v + (size_t)vrow * 256 + ka);         \
        const float4 vb = *(const float4*)(v + (size_t)vrow * 256 + ka + 4);     \
        const float sv[8] = {                                                    \
            fmaxf(ua.x + va.x, 0.f), fmaxf(ua.y + va.y, 0.f),                    \
            fmaxf(ua.z + va.z, 0.f), fmaxf(ua.w + va.w, 0.f),                    \
            fmaxf(ub.x + vb.x, 0.f), fmaxf(ub.y + vb.y, 0.f),                    \
            fmaxf(ub.z + vb.z, 0.f), fmaxf(ub.w + vb.w, 0.f)};                   \
        union { uint4 v4; unsigned short us[8]; } th, tl;                        \
        _Pragma("unroll")                                                        \
        for (int j = 0; j < 8; ++j) { split2(sv[j], th.us[j], tl.us[j]); }       \
        pah = th.v4; pal = tl.v4;                                                \
    }

    f32x4 acc[4][4];
    #pragma unroll
    for (int f = 0; f < 4; ++f)
        #pragma unroll
        for (int nt = 0; nt < 4; ++nt) acc[f][nt] = (f32x4){0.f, 0.f, 0.f, 0.f};

    PREFETCH(0);
    for (int s = 0; s < 8; ++s) {
        __syncthreads();   // previous compute's LDS reads complete
        #pragma unroll
        for (int i = 0; i < 4; ++i) {
            *(uint4*)(sm + t * 40 + i * 8) = pbh[i];
            *(uint4*)(sm + 10240 + t * 40 + i * 8) = pbl[i];
        }
        *(uint4*)(sm + 20480 + e * 40 + kq * 8) = pah;
        *(uint4*)(sm + 23040 + e * 40 + kq * 8) = pal;
        __syncthreads();
        if (s < 7) PREFETCH(s + 1);

        s16x8 ah[4], al[4];
        #pragma unroll
        for (int f = 0; f < 4; ++f) {
            ah[f] = *(const s16x8*)(sm + 20480 + (f * 16 + l15) * 40 + quad * 8);
            al[f] = *(const s16x8*)(sm + 23040 + (f * 16 + l15) * 40 + quad * 8);
        }
        #pragma unroll
        for (int nt = 0; nt < 4; ++nt) {
            const int n = w * 64 + nt * 16 + l15;
            const s16x8 bh = *(const s16x8*)(sm + n * 40 + quad * 8);
            const s16x8 bl = *(const s16x8*)(sm + 10240 + n * 40 + quad * 8);
            #pragma unroll
            for (int f = 0; f < 4; ++f) {
                acc[f][nt] = __builtin_amdgcn_mfma_f32_16x16x32_bf16(ah[f], bh, acc[f][nt], 0, 0, 0);
                acc[f][nt] = __builtin_amdgcn_mfma_f32_16x16x32_bf16(al[f], bh, acc[f][nt], 0, 0, 0);
                acc[f][nt] = __builtin_amdgcn_mfma_f32_16x16x32_bf16(ah[f], bl, acc[f][nt], 0, 0, 0);
            }
        }
    }
    #undef PREFETCH

    // reduce: frag f rows quad*4+r -> edge f*16+quad*4+r -> point f*2+(quad>>1)
    #pragma unroll
    for (int f = 0; f < 4; ++f) {
        #pragma unroll
        for (int nt = 0; nt < 4; ++nt) {
            float rm = fmaxf(fmaxf(acc[f][nt][0], acc[f][nt][1]),
                             fmaxf(acc[f][nt][2], acc[f][nt][3]));
            rm = fmaxf(rm, __shfl_xor(rm, 16, 64));
            const int col = w * 64 + nt * 16 + l15;
            if ((quad & 1) == 0) pmax[f * 2 + (quad >> 1)][col] = rm;
        }
    }
    __syncthreads();

    float bm = pmax[0][t];
    #pragma unroll
    for (int p = 1; p < 8; ++p) bm = fmaxf(bm, pmax[p][t]);
    bm += hb[t];
    const int cell = cell0 + celll;
    const int slot = rest & 63;
    part[((size_t)cell * 64 + slot) * 256 + t] = bm;
}

// ---------------------------------------------------------------------------
// Kernel 6: reduce 64 partial maxes per cell, final MLP (f32), L2 normalize.
// ---------------------------------------------------------------------------
__global__ __launch_bounds__(256)
void k_final(const float* __restrict__ part,
             const float* __restrict__ lW1, const float* __restrict__ lb1,
             const float* __restrict__ lW2, const float* __restrict__ lb2,
             float* __restrict__ out)
{
    __shared__ float pooled[256];
    __shared__ float hid[256];
    __shared__ float red[4];

    const int b = blockIdx.x;
    const int t = threadIdx.x;

    float m = -3.4e38f;
    for (int s = 0; s < 64; ++s)
        m = fmaxf(m, part[((size_t)b * 64 + s) * 256 + t]);
    pooled[t] = m;
    __syncthreads();

    float h = lb1[t];
    for (int k = 0; k < 256; k += 4) {
        #pragma unroll
        for (int kk = 0; kk < 4; ++kk)
            h += pooled[k + kk] * lW1[(k + kk) * 256 + t];
    }
    hid[t] = fmaxf(h, 0.f);
    __syncthreads();

    float o = lb2[t];
    for (int k = 0; k < 256; k += 4) {
        #pragma unroll
        for (int kk = 0; kk < 4; ++kk)
            o += hid[k + kk] * lW2[(k + kk) * 256 + t];
    }

    float ss = o * o;
    #pragma unroll
    for (int s = 32; s > 0; s >>= 1) ss += __shfl_down(ss, s, 64);
    if ((t & 63) == 0) red[t >> 6] = ss;
    __syncthreads();
    const float tot = red[0] + red[1] + red[2] + red[3];
    const float rn = 1.f / fmaxf(sqrtf(tot), 1e-12f);
    out[b * 256 + t] = o * rn;
}

// ---------------------------------------------------------------------------
extern "C" void kernel_launch(void* const* d_in, const int* in_sizes, int n_in,
                              void* d_out, int out_size, void* d_ws, size_t ws_size,
                              hipStream_t stream)
{
    (void)n_in; (void)out_size; (void)ws_size;

    const float* class_table = (const float*)d_in[0];
    const float* cW1 = (const float*)d_in[1];
    const float* cb1 = (const float*)d_in[2];
    const float* cW2 = (const float*)d_in[3];
    const float* cb2 = (const float*)d_in[4];
    const float* pW1 = (const float*)d_in[5];
    const float* pb1 = (const float*)d_in[6];
    const float* pW2 = (const float*)d_in[7];
    const float* pb2 = (const float*)d_in[8];
    const float* mW  = (const float*)d_in[9];
    const float* mb  = (const float*)d_in[10];
    const float* gW1 = (const float*)d_in[11];
    const float* gb1 = (const float*)d_in[12];
    const float* g_gamma = (const float*)d_in[13];
    const float* g_beta  = (const float*)d_in[14];
    const float* gW2 = (const float*)d_in[15];
    const float* gb2 = (const float*)d_in[16];
    const float* lW1 = (const float*)d_in[17];
    const float* lb1 = (const float*)d_in[18];
    const float* lW2 = (const float*)d_in[19];
    const float* lb2 = (const float*)d_in[20];
    const float* positions = (const float*)d_in[21];
    const float* colors    = (const float*)d_in[22];
    const int*  cls        = (const int*)d_in[23];

    const int cstride = (in_sizes[23] == 2 * NTOT) ? 2 : 1;

    // workspace (bytes), peak ~35.4 MB (under proven-safe 47.3):
    char* base = (char*)d_ws;
    float*          part = (float*)(base + 0);
    unsigned short* mWh  = (unsigned short*)(base + 8388608);
    unsigned short* mWl  = (unsigned short*)(base + 8781824);
    unsigned short* Wdh  = (unsigned short*)(base + 9175040);
    unsigned short* Wdl  = (unsigned short*)(base + 9306112);
    unsigned short* Wbh  = (unsigned short*)(base + 9437184);
    unsigned short* Wbl  = (unsigned short*)(base + 9568256);
    unsigned short* g2h  = (unsigned short*)(base + 9699328);
    unsigned short* g2l  = (unsigned short*)(base + 9830400);
    int*            nidx = (int*)(base + 9961472);
    float*          sqn  = (float*)(base + 10223616);
    unsigned short* ehi  = (unsigned short*)(base + 10256384);
    unsigned short* elo  = (unsigned short*)(base + 14450688);
    float*          dist = (float*)(base + 18644992);
    float*          u    = dist;
    float*          v    = (float*)(base + 27033600);
    float*          hb   = (float*)(base + 35422208);
    float* out = (float*)d_out;

    k_cvt<<<1537, 256, 0, stream>>>(mW, gW1, gW2, g_gamma, g_beta, gb2,
                                    mWh, mWl, Wdh, Wdl, Wbh, Wbl, g2h, g2l, hb);
    for (int s = 0; s < NSLAB; ++s) {
        k_embed<<<SLABPTS / 16, 256, 0, stream>>>(class_table, cW1, cb1, cW2, cb2,
                                                  pW1, pb1, pW2, pb2, mWh, mWl, mb,
                                                  positions, colors, cls, cstride,
                                                  ehi, elo, sqn, s * SLABPTS);
        k_gram<<<SLAB * 64, 256, 0, stream>>>(ehi, elo, sqn, dist);
        k_select<<<SLABPTS / 4, 256, 0, stream>>>(dist, nidx);
        k_uv<<<2 * SLABPTS / 32, 256, 0, stream>>>(ehi, elo, Wdh, Wdl, Wbh, Wbl, gb1, u, v);
        k_edge<<<SLABPTS / 8, 256, 0, stream>>>(u, v, nidx, g2h, g2l, hb,
                                                part, s * SLAB);
    }
    k_final<<<NB, 256, 0, stream>>>(part, lW1, lb1, lW2, lb2, out);
}

// Round 9
// 937.012 us; speedup vs baseline: 1.8202x; 1.1710x over previous
//
#include <hip/hip_runtime.h>

#define EDIM 256
#define KNN 8
#define NB 64
#define NP 512
#define NTOT (NB * NP)
#define SLAB 16
#define NSLAB (NB / SLAB)
#define SLABPTS (SLAB * NP)   // 8192

typedef short s16x8 __attribute__((ext_vector_type(8)));
typedef float f32x4 __attribute__((ext_vector_type(4)));

__device__ __forceinline__ unsigned short f2b(float f) {
    unsigned u = __float_as_uint(f);
    u = (u + 0x7fffu + ((u >> 16) & 1u)) >> 16;   // RNE
    return (unsigned short)u;
}
__device__ __forceinline__ float b2f(unsigned short h) {
    return __uint_as_float(((unsigned)h) << 16);
}
__device__ __forceinline__ void split2(float x, unsigned short& h, unsigned short& l) {
    h = f2b(x);
    l = f2b(x - b2f(h));
}

// ---------------------------------------------------------------------------
// Kernel 0: weight prep -> transposed bf16 hi/lo pairs for MFMA B-operands.
// g2 pre-folded with gamma; hb = beta @ W2 + gb2 (exact BN-shift fold).
// ---------------------------------------------------------------------------
__global__ __launch_bounds__(256)
void k_cvt(const float* __restrict__ mW, const float* __restrict__ gW1,
           const float* __restrict__ gW2, const float* __restrict__ g_gamma,
           const float* __restrict__ g_beta, const float* __restrict__ gb2,
           unsigned short* __restrict__ mWh, unsigned short* __restrict__ mWl,
           unsigned short* __restrict__ Wdh, unsigned short* __restrict__ Wdl,
           unsigned short* __restrict__ Wbh, unsigned short* __restrict__ Wbl,
           unsigned short* __restrict__ g2h, unsigned short* __restrict__ g2l,
           float* __restrict__ hb)
{
    const int gid = blockIdx.x * 256 + threadIdx.x;
    unsigned short h, l;
    if (gid < 196608) {
        const int n = gid / 768, k = gid % 768;
        split2(mW[k * 256 + n], h, l);
        mWh[gid] = h; mWl[gid] = l;
    } else if (gid < 262144) {
        const int i = gid - 196608, n = i / 256, k = i % 256;
        split2(gW1[k * 256 + n] - gW1[(k + 256) * 256 + n], h, l);
        Wdh[i] = h; Wdl[i] = l;
    } else if (gid < 327680) {
        const int i = gid - 262144, n = i / 256, k = i % 256;
        split2(gW1[(k + 256) * 256 + n], h, l);
        Wbh[i] = h; Wbl[i] = l;
    } else if (gid < 393216) {
        const int i = gid - 327680, n = i / 256, k = i % 256;
        split2(g_gamma[k] * gW2[k * 256 + n], h, l);
        g2h[i] = h; g2l[i] = l;
    } else if (gid < 393472) {
        const int n = gid - 393216;
        float s = gb2[n];
        for (int k = 0; k < 256; ++k) s += g_beta[k] * gW2[k * 256 + n];
        hb[n] = s;
    }
}

// ---------------------------------------------------------------------------
// Kernel 1: per-object embeddings + merge GEMM (split-MFMA), 16 obj/block.
// ---------------------------------------------------------------------------
__global__ __launch_bounds__(256)
void k_embed(const float* __restrict__ class_table,
             const float* __restrict__ cW1, const float* __restrict__ cb1,
             const float* __restrict__ cW2, const float* __restrict__ cb2,
             const float* __restrict__ pW1, const float* __restrict__ pb1,
             const float* __restrict__ pW2, const float* __restrict__ pb2,
             const unsigned short* __restrict__ mWh, const unsigned short* __restrict__ mWl,
             const float* __restrict__ mb,
             const float* __restrict__ positions, const float* __restrict__ colors,
             const int* __restrict__ cls, const int cstride,
             unsigned short* __restrict__ ehi, unsigned short* __restrict__ elo,
             float* __restrict__ sqn, const int pbase)
{
    __shared__ unsigned short CVh[16 * 264];
    __shared__ unsigned short CVl[16 * 264];
    __shared__ float hid[2048];
    __shared__ float sqpart[16][4];

    float* hidc = hid;
    float* hidp = hid + 1024;

    const int t = threadIdx.x;
    const int w = t >> 6, lane = t & 63;
    const int l15 = lane & 15, quad = lane >> 4;
    const int obase = blockIdx.x * 16;

    {
        const int o = lane >> 4;
        const int objl = w * 4 + o;
        const int gobj = pbase + obase + objl;
        const float c0 = colors[gobj * 3], c1 = colors[gobj * 3 + 1], c2 = colors[gobj * 3 + 2];
        const float q0 = positions[gobj * 3], q1 = positions[gobj * 3 + 1], q2 = positions[gobj * 3 + 2];
        const int u0 = (lane & 15) * 4;
        #pragma unroll
        for (int uu = 0; uu < 4; ++uu) {
            const int u = u0 + uu;
            const float hc = cb1[u] + c0 * cW1[u] + c1 * cW1[64 + u] + c2 * cW1[128 + u];
            const float hp = pb1[u] + q0 * pW1[u] + q1 * pW1[64 + u] + q2 * pW1[128 + u];
            hidc[objl * 64 + u] = fmaxf(hc, 0.f);
            hidp[objl * 64 + u] = fmaxf(hp, 0.f);
        }
    }
    __syncthreads();

    float co[4][4], pe[4][4];
    {
        const float4 cb4 = *(const float4*)&cb2[lane * 4];
        const float4 pb4 = *(const float4*)&pb2[lane * 4];
        #pragma unroll
        for (int o = 0; o < 4; ++o) {
            co[o][0] = cb4.x; co[o][1] = cb4.y; co[o][2] = cb4.z; co[o][3] = cb4.w;
            pe[o][0] = pb4.x; pe[o][1] = pb4.y; pe[o][2] = pb4.z; pe[o][3] = pb4.w;
        }
        for (int j = 0; j < 64; ++j) {
            const float4 wc = *(const float4*)&cW2[j * 256 + lane * 4];
            const float4 wp = *(const float4*)&pW2[j * 256 + lane * 4];
            #pragma unroll
            for (int o = 0; o < 4; ++o) {
                const float hc = hidc[(w * 4 + o) * 64 + j];
                const float hp = hidp[(w * 4 + o) * 64 + j];
                co[o][0] += hc * wc.x; co[o][1] += hc * wc.y;
                co[o][2] += hc * wc.z; co[o][3] += hc * wc.w;
                pe[o][0] += hp * wp.x; pe[o][1] += hp * wp.y;
                pe[o][2] += hp * wp.z; pe[o][3] += hp * wp.w;
            }
        }
    }

    float cen[4][4], con[4][4], pen[4][4];
    #pragma unroll
    for (int o = 0; o < 4; ++o) {
        const int objl = w * 4 + o;
        const int gobj = pbase + obase + objl;
        int ci = cls[(size_t)gobj * cstride];
        if ((unsigned)ci > 30u) ci = 0;
        const float4 ce4 = *(const float4*)&class_table[ci * 256 + lane * 4];
        const float cev[4] = {ce4.x, ce4.y, ce4.z, ce4.w};
        float sce = 0.f, sco = 0.f, spe = 0.f;
        #pragma unroll
        for (int cc = 0; cc < 4; ++cc) {
            sce += cev[cc] * cev[cc];
            sco += co[o][cc] * co[o][cc];
            spe += pe[o][cc] * pe[o][cc];
        }
        #pragma unroll
        for (int s = 32; s > 0; s >>= 1) {
            sce += __shfl_xor(sce, s, 64);
            sco += __shfl_xor(sco, s, 64);
            spe += __shfl_xor(spe, s, 64);
        }
        const float rce = 1.f / fmaxf(sqrtf(sce), 1e-12f);
        const float rco = 1.f / fmaxf(sqrtf(sco), 1e-12f);
        const float rpe = 1.f / fmaxf(sqrtf(spe), 1e-12f);
        #pragma unroll
        for (int cc = 0; cc < 4; ++cc) {
            cen[o][cc] = cev[cc] * rce;
            con[o][cc] = co[o][cc] * rco;
            pen[o][cc] = pe[o][cc] * rpe;
        }
    }

    f32x4 acc[4];
    #pragma unroll
    for (int i = 0; i < 4; ++i) acc[i] = (f32x4){0.f, 0.f, 0.f, 0.f};

    #pragma unroll
    for (int seg = 0; seg < 3; ++seg) {
        __syncthreads();
        #pragma unroll
        for (int o = 0; o < 4; ++o) {
            const int row = w * 4 + o;
            #pragma unroll
            for (int cc = 0; cc < 4; ++cc) {
                const float val = (seg == 0) ? cen[o][cc] : (seg == 1) ? con[o][cc] : pen[o][cc];
                unsigned short h, l;
                split2(val, h, l);
                CVh[row * 264 + lane * 4 + cc] = h;
                CVl[row * 264 + lane * 4 + cc] = l;
            }
        }
        __syncthreads();
        for (int s = 0; s < 8; ++s) {
            const s16x8 ah = *(const s16x8*)&CVh[l15 * 264 + s * 32 + quad * 8];
            const s16x8 al = *(const s16x8*)&CVl[l15 * 264 + s * 32 + quad * 8];
            #pragma unroll
            for (int i = 0; i < 4; ++i) {
                const int n = (w * 4 + i) * 16 + l15;
                const size_t bo = (size_t)n * 768 + seg * 256 + s * 32 + quad * 8;
                const s16x8 bh = *(const s16x8*)(mWh + bo);
                const s16x8 bl = *(const s16x8*)(mWl + bo);
                acc[i] = __builtin_amdgcn_mfma_f32_16x16x32_bf16(ah, bh, acc[i], 0, 0, 0);
                acc[i] = __builtin_amdgcn_mfma_f32_16x16x32_bf16(al, bh, acc[i], 0, 0, 0);
                acc[i] = __builtin_amdgcn_mfma_f32_16x16x32_bf16(ah, bl, acc[i], 0, 0, 0);
            }
        }
    }

    float rp[4] = {0.f, 0.f, 0.f, 0.f};
    #pragma unroll
    for (int i = 0; i < 4; ++i) {
        const int col = (w * 4 + i) * 16 + l15;
        const float mbv = mb[col];
        #pragma unroll
        for (int r = 0; r < 4; ++r) {
            const int row = quad * 4 + r;
            const float e = acc[i][r] + mbv;
            unsigned short h, l;
            split2(e, h, l);
            ehi[(size_t)(obase + row) * 256 + col] = h;
            elo[(size_t)(obase + row) * 256 + col] = l;
            rp[r] += e * e;
        }
    }
    #pragma unroll
    for (int s = 8; s > 0; s >>= 1) {
        #pragma unroll
        for (int r = 0; r < 4; ++r) rp[r] += __shfl_down(rp[r], s, 16);
    }
    if (l15 == 0) {
        #pragma unroll
        for (int r = 0; r < 4; ++r) sqpart[quad * 4 + r][w] = rp[r];
    }
    __syncthreads();
    if (t < 16) sqn[obase + t] = sqpart[t][0] + sqpart[t][1] + sqpart[t][2] + sqpart[t][3];
}

// ---------------------------------------------------------------------------
// Kernel 2: Gram/distance via 3-pass split MFMA, 128x64 tile per block
// (2 m-frags per wave -> 192 MFMAs/wave for better latency hiding).
// ---------------------------------------------------------------------------
__global__ __launch_bounds__(256)
void k_gram(const unsigned short* __restrict__ ehi, const unsigned short* __restrict__ elo,
            const float* __restrict__ sqn, float* __restrict__ dist)
{
    const int t = threadIdx.x, w = t >> 6, lane = t & 63;
    const int l15 = lane & 15, quad = lane >> 4;
    const int b_local = blockIdx.x >> 5;       // 0..15 (32 blocks/cell)
    const int tile = blockIdx.x & 31;
    const int p0 = (tile >> 3) * 128, q0 = (tile & 7) * 64;
    const size_t cb = (size_t)b_local * NP;

    f32x4 acc[2][4];
    #pragma unroll
    for (int sub = 0; sub < 2; ++sub)
        #pragma unroll
        for (int nt = 0; nt < 4; ++nt) acc[sub][nt] = (f32x4){0.f, 0.f, 0.f, 0.f};

    for (int s = 0; s < 8; ++s) {
        s16x8 ah[2], al[2];
        #pragma unroll
        for (int sub = 0; sub < 2; ++sub) {
            const size_t ao = (cb + p0 + sub * 64 + 16 * w + l15) * 256 + s * 32 + quad * 8;
            ah[sub] = *(const s16x8*)(ehi + ao);
            al[sub] = *(const s16x8*)(elo + ao);
        }
        #pragma unroll
        for (int nt = 0; nt < 4; ++nt) {
            const size_t bo = (cb + q0 + nt * 16 + l15) * 256 + s * 32 + quad * 8;
            const s16x8 bh = *(const s16x8*)(ehi + bo);
            const s16x8 bl = *(const s16x8*)(elo + bo);
            #pragma unroll
            for (int sub = 0; sub < 2; ++sub) {
                acc[sub][nt] = __builtin_amdgcn_mfma_f32_16x16x32_bf16(ah[sub], bh, acc[sub][nt], 0, 0, 0);
                acc[sub][nt] = __builtin_amdgcn_mfma_f32_16x16x32_bf16(al[sub], bh, acc[sub][nt], 0, 0, 0);
                acc[sub][nt] = __builtin_amdgcn_mfma_f32_16x16x32_bf16(ah[sub], bl, acc[sub][nt], 0, 0, 0);
            }
        }
    }

    #pragma unroll
    for (int sub = 0; sub < 2; ++sub) {
        float sqp[4];
        #pragma unroll
        for (int r = 0; r < 4; ++r)
            sqp[r] = sqn[cb + p0 + sub * 64 + 16 * w + quad * 4 + r];
        #pragma unroll
        for (int nt = 0; nt < 4; ++nt) {
            const int colq = q0 + nt * 16 + l15;
            const float sq_q = sqn[cb + colq];
            #pragma unroll
            for (int r = 0; r < 4; ++r) {
                const int rowp = p0 + sub * 64 + 16 * w + quad * 4 + r;
                dist[(cb + rowp) * NP + colq] = (sqp[r] + sq_q) - 2.f * acc[sub][nt][r];
            }
        }
    }
}

// ---------------------------------------------------------------------------
// Kernel 3: top-8 smallest per point (ties -> lowest index). One wave/point.
// ---------------------------------------------------------------------------
__global__ __launch_bounds__(256)
void k_select(const float* __restrict__ dist, int* __restrict__ nidx)
{
    const int wv = threadIdx.x >> 6, lane = threadIdx.x & 63;
    const int p_sl = blockIdx.x * 4 + wv;          // 0..8191
    const float* row = dist + (size_t)p_sl * NP;

    float d[8]; int q[8];
    #pragma unroll
    for (int i = 0; i < 8; ++i) { q[i] = lane + 64 * i; d[i] = row[lane + 64 * i]; }

    for (int r = 0; r < KNN; ++r) {
        float bd = d[0]; int bq = q[0];
        #pragma unroll
        for (int i = 1; i < 8; ++i)
            if (d[i] < bd || (d[i] == bd && q[i] < bq)) { bd = d[i]; bq = q[i]; }
        #pragma unroll
        for (int s = 32; s > 0; s >>= 1) {
            const float od = __shfl_down(bd, s, 64);
            const int oq = __shfl_down(bq, s, 64);
            if (od < bd || (od == bd && oq < bq)) { bd = od; bq = oq; }
        }
        const int win = __shfl(bq, 0, 64);
        if (lane == 0) nidx[(size_t)p_sl * KNN + r] = ((p_sl >> 9) << 9) | win;
        if ((win & 63) == lane) {
            const int wi = win >> 6;
            #pragma unroll
            for (int i = 0; i < 8; ++i) if (wi == i) d[i] = 3.4e38f;
        }
    }
}

// ---------------------------------------------------------------------------
// Kernel 4: u = x@Wd+gb1, v = x@Wb via 3-pass split MFMA. 32 points/block.
// ---------------------------------------------------------------------------
__global__ __launch_bounds__(256)
void k_uv(const unsigned short* __restrict__ ehi, const unsigned short* __restrict__ elo,
          const unsigned short* __restrict__ Wdh, const unsigned short* __restrict__ Wdl,
          const unsigned short* __restrict__ Wbh, const unsigned short* __restrict__ Wbl,
          const float* __restrict__ gb1,
          float* __restrict__ u, float* __restrict__ v)
{
    const int t = threadIdx.x, w = t >> 6, lane = t & 63;
    const int l15 = lane & 15, quad = lane >> 4;
    const int isV = blockIdx.x >> 8;
    const int m0 = (blockIdx.x & 255) * 32;    // slab-local
    const unsigned short* Wh = isV ? Wbh : Wdh;
    const unsigned short* Wl = isV ? Wbl : Wdl;
    float* out = isV ? v : u;
    const int mt = w & 1, ch = w >> 1;

    const size_t arow = (size_t)(m0 + mt * 16 + l15) * 256 + quad * 8;

    f32x4 acc[8];
    #pragma unroll
    for (int nt = 0; nt < 8; ++nt) acc[nt] = (f32x4){0.f, 0.f, 0.f, 0.f};

    for (int s = 0; s < 8; ++s) {
        const s16x8 ah = *(const s16x8*)(ehi + arow + s * 32);
        const s16x8 al = *(const s16x8*)(elo + arow + s * 32);
        #pragma unroll
        for (int nt = 0; nt < 8; ++nt) {
            const int n = (ch * 8 + nt) * 16 + l15;
            const size_t bo = (size_t)n * 256 + s * 32 + quad * 8;
            const s16x8 bh = *(const s16x8*)(Wh + bo);
            const s16x8 bl = *(const s16x8*)(Wl + bo);
            acc[nt] = __builtin_amdgcn_mfma_f32_16x16x32_bf16(ah, bh, acc[nt], 0, 0, 0);
            acc[nt] = __builtin_amdgcn_mfma_f32_16x16x32_bf16(al, bh, acc[nt], 0, 0, 0);
            acc[nt] = __builtin_amdgcn_mfma_f32_16x16x32_bf16(ah, bl, acc[nt], 0, 0, 0);
        }
    }

    #pragma unroll
    for (int nt = 0; nt < 8; ++nt) {
        const int col = (ch * 8 + nt) * 16 + l15;
        const float bias = isV ? 0.f : gb1[col];
        #pragma unroll
        for (int r = 0; r < 4; ++r) {
            const int row = mt * 16 + quad * 4 + r;
            out[(size_t)(m0 + row) * 256 + col] = acc[nt][r] + bias;
        }
    }
}

// ---------------------------------------------------------------------------
// Kernel 5: edge GEMM + max aggregation — LDS-free, barrier-free K-loop.
// Block = 16 points (128 edges). Wave (wm,wn) owns 64 edges x 128 cols:
// acc 4x8 frags. A = relu(u_p+v_j) split hi/lo built IN REGISTERS;
// B (gamma-folded W2 hi/lo) read direct from L2. Per-wave edge max reduced
// in-register (+2 shuffles); tiny pmax LDS merges the two wm halves.
// ---------------------------------------------------------------------------
__global__ __launch_bounds__(256, 2)
void k_edge(const float* __restrict__ u, const float* __restrict__ v,
            const int* __restrict__ nidx,
            const unsigned short* __restrict__ g2h, const unsigned short* __restrict__ g2l,
            const float* __restrict__ hb,
            float* __restrict__ part, const int cell0)
{
    __shared__ float pmax[2][256];             // 2 KB

    const int t = threadIdx.x, w = t >> 6, lane = t & 63;
    const int l15 = lane & 15, quad = lane >> 4;
    const int wm = w & 1, wn = w >> 1;

    // XCD swizzle: blockIdx%8 ~ XCD; 2 whole cells per XCD.
    const int b = blockIdx.x;
    const int xcd = b & 7, rest = b >> 3;      // rest 0..63
    const int celll = xcd * 2 + (rest >> 5);   // slab-local cell 0..15
    const int pl0 = celll * NP + (rest & 31) * 16;

    // per-lane u/v rows for the wave's 4 m-tiles (edges wm*64+mt*16+l15)
    int ur[4], vr[4];
    #pragma unroll
    for (int mt = 0; mt < 4; ++mt) {
        const int e = wm * 64 + mt * 16 + l15;
        const int pt = e >> 3;
        ur[mt] = pl0 + pt;
        int n = nidx[(size_t)(pl0 + pt) * KNN + (e & 7)];
        if ((unsigned)n >= (unsigned)SLABPTS) n = 0;
        vr[mt] = n;
    }

    f32x4 acc[4][8];
    #pragma unroll
    for (int mt = 0; mt < 4; ++mt)
        #pragma unroll
        for (int nt = 0; nt < 8; ++nt) acc[mt][nt] = (f32x4){0.f, 0.f, 0.f, 0.f};

    for (int s = 0; s < 8; ++s) {
        const int k0 = s * 32 + quad * 8;
        s16x8 ah[4], al[4];
        #pragma unroll
        for (int mt = 0; mt < 4; ++mt) {
            const float4 ua = *(const float4*)(u + (size_t)ur[mt] * 256 + k0);
            const float4 ub = *(const float4*)(u + (size_t)ur[mt] * 256 + k0 + 4);
            const float4 va = *(const float4*)(v + (size_t)vr[mt] * 256 + k0);
            const float4 vb = *(const float4*)(v + (size_t)vr[mt] * 256 + k0 + 4);
            const float sv[8] = {
                fmaxf(ua.x + va.x, 0.f), fmaxf(ua.y + va.y, 0.f),
                fmaxf(ua.z + va.z, 0.f), fmaxf(ua.w + va.w, 0.f),
                fmaxf(ub.x + vb.x, 0.f), fmaxf(ub.y + vb.y, 0.f),
                fmaxf(ub.z + vb.z, 0.f), fmaxf(ub.w + vb.w, 0.f)};
            union { s16x8 v8; unsigned short us[8]; } th, tl;
            #pragma unroll
            for (int j = 0; j < 8; ++j) split2(sv[j], th.us[j], tl.us[j]);
            ah[mt] = th.v8; al[mt] = tl.v8;
        }
        #pragma unroll
        for (int nt = 0; nt < 8; ++nt) {
            const int n = wn * 128 + nt * 16 + l15;
            const s16x8 bh = *(const s16x8*)(g2h + (size_t)n * 256 + k0);
            const s16x8 bl = *(const s16x8*)(g2l + (size_t)n * 256 + k0);
            #pragma unroll
            for (int mt = 0; mt < 4; ++mt) {
                acc[mt][nt] = __builtin_amdgcn_mfma_f32_16x16x32_bf16(ah[mt], bh, acc[mt][nt], 0, 0, 0);
                acc[mt][nt] = __builtin_amdgcn_mfma_f32_16x16x32_bf16(al[mt], bh, acc[mt][nt], 0, 0, 0);
                acc[mt][nt] = __builtin_amdgcn_mfma_f32_16x16x32_bf16(ah[mt], bl, acc[mt][nt], 0, 0, 0);
            }
        }
    }

    // in-register max over the wave's 64 edges, per column
    #pragma unroll
    for (int nt = 0; nt < 8; ++nt) {
        float rm = -3.4e38f;
        #pragma unroll
        for (int mt = 0; mt < 4; ++mt)
            rm = fmaxf(rm, fmaxf(fmaxf(acc[mt][nt][0], acc[mt][nt][1]),
                                 fmaxf(acc[mt][nt][2], acc[mt][nt][3])));
        rm = fmaxf(rm, __shfl_xor(rm, 16, 64));
        rm = fmaxf(rm, __shfl_xor(rm, 32, 64));
        if (quad == 0) pmax[wm][wn * 128 + nt * 16 + l15] = rm;
    }
    __syncthreads();

    const float bm = fmaxf(pmax[0][t], pmax[1][t]) + hb[t];
    const int cell = cell0 + celll;
    const int slot = rest & 31;                // 32 blocks/cell
    part[((size_t)cell * 32 + slot) * 256 + t] = bm;
}

// ---------------------------------------------------------------------------
// Kernel 6: reduce 32 partial maxes per cell, final MLP (f32), L2 normalize.
// ---------------------------------------------------------------------------
__global__ __launch_bounds__(256)
void k_final(const float* __restrict__ part,
             const float* __restrict__ lW1, const float* __restrict__ lb1,
             const float* __restrict__ lW2, const float* __restrict__ lb2,
             float* __restrict__ out)
{
    __shared__ float pooled[256];
    __shared__ float hid[256];
    __shared__ float red[4];

    const int b = blockIdx.x;
    const int t = threadIdx.x;

    float m = -3.4e38f;
    for (int s = 0; s < 32; ++s)
        m = fmaxf(m, part[((size_t)b * 32 + s) * 256 + t]);
    pooled[t] = m;
    __syncthreads();

    float h = lb1[t];
    for (int k = 0; k < 256; k += 4) {
        #pragma unroll
        for (int kk = 0; kk < 4; ++kk)
            h += pooled[k + kk] * lW1[(k + kk) * 256 + t];
    }
    hid[t] = fmaxf(h, 0.f);
    __syncthreads();

    float o = lb2[t];
    for (int k = 0; k < 256; k += 4) {
        #pragma unroll
        for (int kk = 0; kk < 4; ++kk)
            o += hid[k + kk] * lW2[(k + kk) * 256 + t];
    }

    float ss = o * o;
    #pragma unroll
    for (int s = 32; s > 0; s >>= 1) ss += __shfl_down(ss, s, 64);
    if ((t & 63) == 0) red[t >> 6] = ss;
    __syncthreads();
    const float tot = red[0] + red[1] + red[2] + red[3];
    const float rn = 1.f / fmaxf(sqrtf(tot), 1e-12f);
    out[b * 256 + t] = o * rn;
}

// ---------------------------------------------------------------------------
extern "C" void kernel_launch(void* const* d_in, const int* in_sizes, int n_in,
                              void* d_out, int out_size, void* d_ws, size_t ws_size,
                              hipStream_t stream)
{
    (void)n_in; (void)out_size; (void)ws_size;

    const float* class_table = (const float*)d_in[0];
    const float* cW1 = (const float*)d_in[1];
    const float* cb1 = (const float*)d_in[2];
    const float* cW2 = (const float*)d_in[3];
    const float* cb2 = (const float*)d_in[4];
    const float* pW1 = (const float*)d_in[5];
    const float* pb1 = (const float*)d_in[6];
    const float* pW2 = (const float*)d_in[7];
    const float* pb2 = (const float*)d_in[8];
    const float* mW  = (const float*)d_in[9];
    const float* mb  = (const float*)d_in[10];
    const float* gW1 = (const float*)d_in[11];
    const float* gb1 = (const float*)d_in[12];
    const float* g_gamma = (const float*)d_in[13];
    const float* g_beta  = (const float*)d_in[14];
    const float* gW2 = (const float*)d_in[15];
    const float* gb2 = (const float*)d_in[16];
    const float* lW1 = (const float*)d_in[17];
    const float* lb1 = (const float*)d_in[18];
    const float* lW2 = (const float*)d_in[19];
    const float* lb2 = (const float*)d_in[20];
    const float* positions = (const float*)d_in[21];
    const float* colors    = (const float*)d_in[22];
    const int*  cls        = (const int*)d_in[23];

    const int cstride = (in_sizes[23] == 2 * NTOT) ? 2 : 1;

    // workspace (bytes), peak ~35.4 MB (under proven-safe 47.3):
    char* base = (char*)d_ws;
    float*          part = (float*)(base + 0);                 // 2 MB used
    unsigned short* mWh  = (unsigned short*)(base + 8388608);
    unsigned short* mWl  = (unsigned short*)(base + 8781824);
    unsigned short* Wdh  = (unsigned short*)(base + 9175040);
    unsigned short* Wdl  = (unsigned short*)(base + 9306112);
    unsigned short* Wbh  = (unsigned short*)(base + 9437184);
    unsigned short* Wbl  = (unsigned short*)(base + 9568256);
    unsigned short* g2h  = (unsigned short*)(base + 9699328);
    unsigned short* g2l  = (unsigned short*)(base + 9830400);
    int*            nidx = (int*)(base + 9961472);
    float*          sqn  = (float*)(base + 10223616);
    unsigned short* ehi  = (unsigned short*)(base + 10256384);
    unsigned short* elo  = (unsigned short*)(base + 14450688);
    float*          dist = (float*)(base + 18644992);
    float*          u    = dist;
    float*          v    = (float*)(base + 27033600);
    float*          hb   = (float*)(base + 35422208);
    float* out = (float*)d_out;

    k_cvt<<<1537, 256, 0, stream>>>(mW, gW1, gW2, g_gamma, g_beta, gb2,
                                    mWh, mWl, Wdh, Wdl, Wbh, Wbl, g2h, g2l, hb);
    for (int s = 0; s < NSLAB; ++s) {
        k_embed<<<SLABPTS / 16, 256, 0, stream>>>(class_table, cW1, cb1, cW2, cb2,
                                                  pW1, pb1, pW2, pb2, mWh, mWl, mb,
                                                  positions, colors, cls, cstride,
                                                  ehi, elo, sqn, s * SLABPTS);
        k_gram<<<SLAB * 32, 256, 0, stream>>>(ehi, elo, sqn, dist);
        k_select<<<SLABPTS / 4, 256, 0, stream>>>(dist, nidx);
        k_uv<<<2 * SLABPTS / 32, 256, 0, stream>>>(ehi, elo, Wdh, Wdl, Wbh, Wbl, gb1, u, v);
        k_edge<<<SLABPTS / 16, 256, 0, stream>>>(u, v, nidx, g2h, g2l, hb,
                                                 part, s * SLAB);
    }
    k_final<<<NB, 256, 0, stream>>>(part, lW1, lb1, lW2, lb2, out);
}

// Round 10
// 780.492 us; speedup vs baseline: 2.1852x; 1.2005x over previous
//
#include <hip/hip_runtime.h>

#define EDIM 256
#define KNN 8
#define NB 64
#define NP 512
#define NTOT (NB * NP)
#define SLAB 16
#define NSLAB (NB / SLAB)
#define SLABPTS (SLAB * NP)   // 8192

typedef short s16x8 __attribute__((ext_vector_type(8)));
typedef float f32x4 __attribute__((ext_vector_type(4)));

__device__ __forceinline__ unsigned short f2b(float f) {
    unsigned u = __float_as_uint(f);
    u = (u + 0x7fffu + ((u >> 16) & 1u)) >> 16;   // RNE
    return (unsigned short)u;
}
__device__ __forceinline__ float b2f(unsigned short h) {
    return __uint_as_float(((unsigned)h) << 16);
}
__device__ __forceinline__ void split2(float x, unsigned short& h, unsigned short& l) {
    h = f2b(x);
    l = f2b(x - b2f(h));
}

// ---------------------------------------------------------------------------
// Kernel 0a: weight prep -> transposed bf16 hi/lo pairs.
//   Wd = gW1[0:256]-gW1[256:512], Wb = gW1[256:512] (both [n=256][k=256])
//   g2 = gamma-folded W2 [n=256][k=256]; hb = beta@W2 + gb2
//   cW2T/pW2T: second-layer MLP weights [n=256][k=64] for the norm GEMM.
// ---------------------------------------------------------------------------
__global__ __launch_bounds__(256)
void k_cvt(const float* __restrict__ gW1, const float* __restrict__ gW2,
           const float* __restrict__ g_gamma, const float* __restrict__ g_beta,
           const float* __restrict__ gb2,
           const float* __restrict__ cW2, const float* __restrict__ pW2,
           unsigned short* __restrict__ Wdh, unsigned short* __restrict__ Wdl,
           unsigned short* __restrict__ Wbh, unsigned short* __restrict__ Wbl,
           unsigned short* __restrict__ g2h, unsigned short* __restrict__ g2l,
           float* __restrict__ hb,
           unsigned short* __restrict__ cW2Th, unsigned short* __restrict__ cW2Tl,
           unsigned short* __restrict__ pW2Th, unsigned short* __restrict__ pW2Tl)
{
    const int gid = blockIdx.x * 256 + threadIdx.x;
    unsigned short h, l;
    if (gid < 65536) {
        const int n = gid >> 8, k = gid & 255;
        split2(gW1[k * 256 + n] - gW1[(k + 256) * 256 + n], h, l);
        Wdh[gid] = h; Wdl[gid] = l;
    } else if (gid < 131072) {
        const int i = gid - 65536, n = i >> 8, k = i & 255;
        split2(gW1[(k + 256) * 256 + n], h, l);
        Wbh[i] = h; Wbl[i] = l;
    } else if (gid < 196608) {
        const int i = gid - 131072, n = i >> 8, k = i & 255;
        split2(g_gamma[k] * gW2[k * 256 + n], h, l);
        g2h[i] = h; g2l[i] = l;
    } else if (gid < 196864) {
        const int n = gid - 196608;
        float s = gb2[n];
        for (int k = 0; k < 256; ++k) s += g_beta[k] * gW2[k * 256 + n];
        hb[n] = s;
    } else if (gid < 213248) {
        const int i = gid - 196864, n = i >> 6, k = i & 63;
        split2(cW2[k * 256 + n], h, l);
        cW2Th[i] = h; cW2Tl[i] = l;
    } else if (gid < 229632) {
        const int i = gid - 213248, n = i >> 6, k = i & 63;
        split2(pW2[k * 256 + n], h, l);
        pW2Th[i] = h; pW2Tl[i] = l;
    }
}

// ---------------------------------------------------------------------------
// Kernel 0b: fold merge GEMM into the MLP weights (linearity):
//   Wc' = cW2 @ M1, Wp' = pW2 @ M2  (M1 = mW[256:512], M2 = mW[512:768])
//   cbM = cb2 @ M1, pbM = pb2 @ M2.
// ---------------------------------------------------------------------------
__global__ __launch_bounds__(256)
void k_fold(const float* __restrict__ cW2, const float* __restrict__ pW2,
            const float* __restrict__ cb2, const float* __restrict__ pb2,
            const float* __restrict__ mW,
            unsigned short* __restrict__ WcTh, unsigned short* __restrict__ WcTl,
            unsigned short* __restrict__ WpTh, unsigned short* __restrict__ WpTl,
            float* __restrict__ cbM, float* __restrict__ pbM)
{
    const int gid = blockIdx.x * 256 + threadIdx.x;
    unsigned short h, l;
    if (gid < 16384) {
        const int j = gid >> 8, n = gid & 255;
        float s = 0.f;
        for (int k = 0; k < 256; ++k) s += cW2[j * 256 + k] * mW[(256 + k) * 256 + n];
        split2(s, h, l);
        WcTh[n * 64 + j] = h; WcTl[n * 64 + j] = l;
    } else if (gid < 32768) {
        const int i = gid - 16384, j = i >> 8, n = i & 255;
        float s = 0.f;
        for (int k = 0; k < 256; ++k) s += pW2[j * 256 + k] * mW[(512 + k) * 256 + n];
        split2(s, h, l);
        WpTh[n * 64 + j] = h; WpTl[n * 64 + j] = l;
    } else if (gid < 33024) {
        const int n = gid - 32768;
        float s = 0.f;
        for (int k = 0; k < 256; ++k) s += cb2[k] * mW[(256 + k) * 256 + n];
        cbM[n] = s;
    } else if (gid < 33280) {
        const int n = gid - 33024;
        float s = 0.f;
        for (int k = 0; k < 256; ++k) s += pb2[k] * mW[(512 + k) * 256 + n];
        pbM[n] = s;
    }
}

// ---------------------------------------------------------------------------
// Kernel 0c: classMn[c] = (class_table[c] / ||class_table[c]||) @ M0. Exact
// per-class fold of the ce path (padding class 0 -> zero row).
// ---------------------------------------------------------------------------
__global__ __launch_bounds__(256)
void k_cls(const float* __restrict__ ct, const float* __restrict__ mW,
           float* __restrict__ classMn)
{
    __shared__ float ctn[256];
    __shared__ float red[4];
    const int c = blockIdx.x, t = threadIdx.x;
    const float v = ct[c * 256 + t];
    float ss = v * v;
    #pragma unroll
    for (int s = 32; s > 0; s >>= 1) ss += __shfl_down(ss, s, 64);
    if ((t & 63) == 0) red[t >> 6] = ss;
    __syncthreads();
    const float tot = red[0] + red[1] + red[2] + red[3];
    const float r = 1.f / fmaxf(sqrtf(tot), 1e-12f);
    ctn[t] = v * r;
    __syncthreads();
    float s = 0.f;
    for (int k = 0; k < 256; ++k) s += ctn[k] * mW[k * 256 + t];
    classMn[c * 256 + t] = s;
}

// ---------------------------------------------------------------------------
// Kernel 1: embeddings via folded GEMMs. 16 obj/block.
// Step A: K=3 first layers (VALU) -> hidc/hidp split hi/lo in LDS (A-operand).
// Step B: co/pe norm GEMMs (K=64, split MFMA) -> rco/rpe only.
// Step C: emb = classMn[cls] + rco*(hidc@Wc'+cbM) + rpe*(hidp@Wp'+pbM) + mb.
// Outputs ehi/elo + sqn (slab-local).
// ---------------------------------------------------------------------------
__global__ __launch_bounds__(256)
void k_embed(const float* __restrict__ classMn,
             const float* __restrict__ cW1, const float* __restrict__ cb1,
             const float* __restrict__ cb2,
             const float* __restrict__ pW1, const float* __restrict__ pb1,
             const float* __restrict__ pb2,
             const float* __restrict__ mb,
             const unsigned short* __restrict__ cW2Th, const unsigned short* __restrict__ cW2Tl,
             const unsigned short* __restrict__ pW2Th, const unsigned short* __restrict__ pW2Tl,
             const unsigned short* __restrict__ WcTh, const unsigned short* __restrict__ WcTl,
             const unsigned short* __restrict__ WpTh, const unsigned short* __restrict__ WpTl,
             const float* __restrict__ cbM, const float* __restrict__ pbM,
             const float* __restrict__ positions, const float* __restrict__ colors,
             const int* __restrict__ cls, const int cstride,
             unsigned short* __restrict__ ehi, unsigned short* __restrict__ elo,
             float* __restrict__ sqn, const int pbase)
{
    __shared__ __align__(16) unsigned short Ahc[16 * 72];
    __shared__ __align__(16) unsigned short Alc[16 * 72];
    __shared__ __align__(16) unsigned short Ahp[16 * 72];
    __shared__ __align__(16) unsigned short Alp[16 * 72];
    __shared__ float sqc[16][4], sqp_[16][4], sqe[16][4];

    const int t = threadIdx.x, w = t >> 6, lane = t & 63;
    const int l15 = lane & 15, quad = lane >> 4;
    const int obase = blockIdx.x * 16;         // slab-local

    // --- step A: first layers, split hi/lo straight into A-layout LDS
    {
        const int o = lane >> 4;               // 0..3
        const int objl = w * 4 + o;
        const int gobj = pbase + obase + objl;
        const float c0 = colors[gobj * 3], c1 = colors[gobj * 3 + 1], c2 = colors[gobj * 3 + 2];
        const float q0 = positions[gobj * 3], q1 = positions[gobj * 3 + 1], q2 = positions[gobj * 3 + 2];
        const int u0 = (lane & 15) * 4;
        #pragma unroll
        for (int uu = 0; uu < 4; ++uu) {
            const int u = u0 + uu;
            const float hc = fmaxf(cb1[u] + c0 * cW1[u] + c1 * cW1[64 + u] + c2 * cW1[128 + u], 0.f);
            const float hp = fmaxf(pb1[u] + q0 * pW1[u] + q1 * pW1[64 + u] + q2 * pW1[128 + u], 0.f);
            unsigned short h, l;
            split2(hc, h, l); Ahc[objl * 72 + u] = h; Alc[objl * 72 + u] = l;
            split2(hp, h, l); Ahp[objl * 72 + u] = h; Alp[objl * 72 + u] = l;
        }
    }
    __syncthreads();

    // --- step B: co/pe norm GEMMs (values discarded, only sumsq kept)
    f32x4 aco[4], ape[4];
    #pragma unroll
    for (int nt = 0; nt < 4; ++nt) { aco[nt] = (f32x4){0.f,0.f,0.f,0.f}; ape[nt] = (f32x4){0.f,0.f,0.f,0.f}; }

    #pragma unroll
    for (int kt = 0; kt < 2; ++kt) {
        const int ao = l15 * 72 + kt * 32 + quad * 8;
        const s16x8 ahc = *(const s16x8*)&Ahc[ao];
        const s16x8 alc = *(const s16x8*)&Alc[ao];
        const s16x8 ahp = *(const s16x8*)&Ahp[ao];
        const s16x8 alp = *(const s16x8*)&Alp[ao];
        #pragma unroll
        for (int nt = 0; nt < 4; ++nt) {
            const int n = w * 64 + nt * 16 + l15;
            const size_t bo = (size_t)n * 64 + kt * 32 + quad * 8;
            const s16x8 cbh = *(const s16x8*)(cW2Th + bo);
            const s16x8 cbl = *(const s16x8*)(cW2Tl + bo);
            const s16x8 pbh = *(const s16x8*)(pW2Th + bo);
            const s16x8 pbl = *(const s16x8*)(pW2Tl + bo);
            aco[nt] = __builtin_amdgcn_mfma_f32_16x16x32_bf16(ahc, cbh, aco[nt], 0, 0, 0);
            ape[nt] = __builtin_amdgcn_mfma_f32_16x16x32_bf16(ahp, pbh, ape[nt], 0, 0, 0);
            aco[nt] = __builtin_amdgcn_mfma_f32_16x16x32_bf16(alc, cbh, aco[nt], 0, 0, 0);
            ape[nt] = __builtin_amdgcn_mfma_f32_16x16x32_bf16(alp, pbh, ape[nt], 0, 0, 0);
            aco[nt] = __builtin_amdgcn_mfma_f32_16x16x32_bf16(ahc, cbl, aco[nt], 0, 0, 0);
            ape[nt] = __builtin_amdgcn_mfma_f32_16x16x32_bf16(ahp, pbl, ape[nt], 0, 0, 0);
        }
    }

    float sc[4] = {0.f,0.f,0.f,0.f}, sp[4] = {0.f,0.f,0.f,0.f};
    #pragma unroll
    for (int nt = 0; nt < 4; ++nt) {
        const int col = w * 64 + nt * 16 + l15;
        const float cbv = cb2[col], pbv = pb2[col];
        #pragma unroll
        for (int r = 0; r < 4; ++r) {
            const float co = aco[nt][r] + cbv;
            const float pe = ape[nt][r] + pbv;
            sc[r] += co * co;
            sp[r] += pe * pe;
        }
    }
    #pragma unroll
    for (int s = 8; s > 0; s >>= 1) {
        #pragma unroll
        for (int r = 0; r < 4; ++r) {
            sc[r] += __shfl_xor(sc[r], s, 64);
            sp[r] += __shfl_xor(sp[r], s, 64);
        }
    }
    if (l15 == 0) {
        #pragma unroll
        for (int r = 0; r < 4; ++r) { sqc[quad * 4 + r][w] = sc[r]; sqp_[quad * 4 + r][w] = sp[r]; }
    }
    __syncthreads();

    float rco[4], rpe[4];
    #pragma unroll
    for (int r = 0; r < 4; ++r) {
        const int row = quad * 4 + r;
        rco[r] = 1.f / fmaxf(sqrtf(sqc[row][0] + sqc[row][1] + sqc[row][2] + sqc[row][3]), 1e-12f);
        rpe[r] = 1.f / fmaxf(sqrtf(sqp_[row][0] + sqp_[row][1] + sqp_[row][2] + sqp_[row][3]), 1e-12f);
    }

    // --- step C: emb GEMMs with folded weights
    f32x4 ac[4], ap[4];
    #pragma unroll
    for (int nt = 0; nt < 4; ++nt) { ac[nt] = (f32x4){0.f,0.f,0.f,0.f}; ap[nt] = (f32x4){0.f,0.f,0.f,0.f}; }

    #pragma unroll
    for (int kt = 0; kt < 2; ++kt) {
        const int ao = l15 * 72 + kt * 32 + quad * 8;
        const s16x8 ahc = *(const s16x8*)&Ahc[ao];
        const s16x8 alc = *(const s16x8*)&Alc[ao];
        const s16x8 ahp = *(const s16x8*)&Ahp[ao];
        const s16x8 alp = *(const s16x8*)&Alp[ao];
        #pragma unroll
        for (int nt = 0; nt < 4; ++nt) {
            const int n = w * 64 + nt * 16 + l15;
            const size_t bo = (size_t)n * 64 + kt * 32 + quad * 8;
            const s16x8 cbh = *(const s16x8*)(WcTh + bo);
            const s16x8 cbl = *(const s16x8*)(WcTl + bo);
            const s16x8 pbh = *(const s16x8*)(WpTh + bo);
            const s16x8 pbl = *(const s16x8*)(WpTl + bo);
            ac[nt] = __builtin_amdgcn_mfma_f32_16x16x32_bf16(ahc, cbh, ac[nt], 0, 0, 0);
            ap[nt] = __builtin_amdgcn_mfma_f32_16x16x32_bf16(ahp, pbh, ap[nt], 0, 0, 0);
            ac[nt] = __builtin_amdgcn_mfma_f32_16x16x32_bf16(alc, cbh, ac[nt], 0, 0, 0);
            ap[nt] = __builtin_amdgcn_mfma_f32_16x16x32_bf16(alp, pbh, ap[nt], 0, 0, 0);
            ac[nt] = __builtin_amdgcn_mfma_f32_16x16x32_bf16(ahc, cbl, ac[nt], 0, 0, 0);
            ap[nt] = __builtin_amdgcn_mfma_f32_16x16x32_bf16(ahp, pbl, ap[nt], 0, 0, 0);
        }
    }

    int ci[4];
    #pragma unroll
    for (int r = 0; r < 4; ++r) {
        const int gobj = pbase + obase + quad * 4 + r;
        int c = cls[(size_t)gobj * cstride];
        if ((unsigned)c > 30u) c = 0;
        ci[r] = c;
    }

    float rp[4] = {0.f,0.f,0.f,0.f};
    #pragma unroll
    for (int nt = 0; nt < 4; ++nt) {
        const int col = w * 64 + nt * 16 + l15;
        const float mbv = mb[col], cbMv = cbM[col], pbMv = pbM[col];
        #pragma unroll
        for (int r = 0; r < 4; ++r) {
            const int row = quad * 4 + r;
            const float e = classMn[ci[r] * 256 + col]
                          + rco[r] * (ac[nt][r] + cbMv)
                          + rpe[r] * (ap[nt][r] + pbMv) + mbv;
            unsigned short h, l;
            split2(e, h, l);
            ehi[(size_t)(obase + row) * 256 + col] = h;
            elo[(size_t)(obase + row) * 256 + col] = l;
            rp[r] += e * e;
        }
    }
    #pragma unroll
    for (int s = 8; s > 0; s >>= 1) {
        #pragma unroll
        for (int r = 0; r < 4; ++r) rp[r] += __shfl_xor(rp[r], s, 64);
    }
    if (l15 == 0) {
        #pragma unroll
        for (int r = 0; r < 4; ++r) sqe[quad * 4 + r][w] = rp[r];
    }
    __syncthreads();
    if (t < 16) sqn[obase + t] = sqe[t][0] + sqe[t][1] + sqe[t][2] + sqe[t][3];
}

// ---------------------------------------------------------------------------
// Kernel 2: Gram/distance via 3-pass split MFMA, 128x64 tile per block.
// ---------------------------------------------------------------------------
__global__ __launch_bounds__(256)
void k_gram(const unsigned short* __restrict__ ehi, const unsigned short* __restrict__ elo,
            const float* __restrict__ sqn, float* __restrict__ dist)
{
    const int t = threadIdx.x, w = t >> 6, lane = t & 63;
    const int l15 = lane & 15, quad = lane >> 4;
    const int b_local = blockIdx.x >> 5;       // 0..15 (32 blocks/cell)
    const int tile = blockIdx.x & 31;
    const int p0 = (tile >> 3) * 128, q0 = (tile & 7) * 64;
    const size_t cb = (size_t)b_local * NP;

    f32x4 acc[2][4];
    #pragma unroll
    for (int sub = 0; sub < 2; ++sub)
        #pragma unroll
        for (int nt = 0; nt < 4; ++nt) acc[sub][nt] = (f32x4){0.f, 0.f, 0.f, 0.f};

    for (int s = 0; s < 8; ++s) {
        s16x8 ah[2], al[2];
        #pragma unroll
        for (int sub = 0; sub < 2; ++sub) {
            const size_t ao = (cb + p0 + sub * 64 + 16 * w + l15) * 256 + s * 32 + quad * 8;
            ah[sub] = *(const s16x8*)(ehi + ao);
            al[sub] = *(const s16x8*)(elo + ao);
        }
        #pragma unroll
        for (int nt = 0; nt < 4; ++nt) {
            const size_t bo = (cb + q0 + nt * 16 + l15) * 256 + s * 32 + quad * 8;
            const s16x8 bh = *(const s16x8*)(ehi + bo);
            const s16x8 bl = *(const s16x8*)(elo + bo);
            #pragma unroll
            for (int sub = 0; sub < 2; ++sub) {
                acc[sub][nt] = __builtin_amdgcn_mfma_f32_16x16x32_bf16(ah[sub], bh, acc[sub][nt], 0, 0, 0);
                acc[sub][nt] = __builtin_amdgcn_mfma_f32_16x16x32_bf16(al[sub], bh, acc[sub][nt], 0, 0, 0);
                acc[sub][nt] = __builtin_amdgcn_mfma_f32_16x16x32_bf16(ah[sub], bl, acc[sub][nt], 0, 0, 0);
            }
        }
    }

    #pragma unroll
    for (int sub = 0; sub < 2; ++sub) {
        float sqp[4];
        #pragma unroll
        for (int r = 0; r < 4; ++r)
            sqp[r] = sqn[cb + p0 + sub * 64 + 16 * w + quad * 4 + r];
        #pragma unroll
        for (int nt = 0; nt < 4; ++nt) {
            const int colq = q0 + nt * 16 + l15;
            const float sq_q = sqn[cb + colq];
            #pragma unroll
            for (int r = 0; r < 4; ++r) {
                const int rowp = p0 + sub * 64 + 16 * w + quad * 4 + r;
                dist[(cb + rowp) * NP + colq] = (sqp[r] + sq_q) - 2.f * acc[sub][nt][r];
            }
        }
    }
}

// ---------------------------------------------------------------------------
// Kernel 3: top-8 smallest per point (ties -> lowest index). One wave/point.
// ---------------------------------------------------------------------------
__global__ __launch_bounds__(256)
void k_select(const float* __restrict__ dist, int* __restrict__ nidx)
{
    const int wv = threadIdx.x >> 6, lane = threadIdx.x & 63;
    const int p_sl = blockIdx.x * 4 + wv;          // 0..8191
    const float* row = dist + (size_t)p_sl * NP;

    float d[8]; int q[8];
    #pragma unroll
    for (int i = 0; i < 8; ++i) { q[i] = lane + 64 * i; d[i] = row[lane + 64 * i]; }

    for (int r = 0; r < KNN; ++r) {
        float bd = d[0]; int bq = q[0];
        #pragma unroll
        for (int i = 1; i < 8; ++i)
            if (d[i] < bd || (d[i] == bd && q[i] < bq)) { bd = d[i]; bq = q[i]; }
        #pragma unroll
        for (int s = 32; s > 0; s >>= 1) {
            const float od = __shfl_down(bd, s, 64);
            const int oq = __shfl_down(bq, s, 64);
            if (od < bd || (od == bd && oq < bq)) { bd = od; bq = oq; }
        }
        const int win = __shfl(bq, 0, 64);
        if (lane == 0) nidx[(size_t)p_sl * KNN + r] = ((p_sl >> 9) << 9) | win;
        if ((win & 63) == lane) {
            const int wi = win >> 6;
            #pragma unroll
            for (int i = 0; i < 8; ++i) if (wi == i) d[i] = 3.4e38f;
        }
    }
}

// ---------------------------------------------------------------------------
// Kernel 4: u = x@Wd+gb1, v = x@Wb via 3-pass split MFMA. 32 points/block.
// ---------------------------------------------------------------------------
__global__ __launch_bounds__(256)
void k_uv(const unsigned short* __restrict__ ehi, const unsigned short* __restrict__ elo,
          const unsigned short* __restrict__ Wdh, const unsigned short* __restrict__ Wdl,
          const unsigned short* __restrict__ Wbh, const unsigned short* __restrict__ Wbl,
          const float* __restrict__ gb1,
          float* __restrict__ u, float* __restrict__ v)
{
    const int t = threadIdx.x, w = t >> 6, lane = t & 63;
    const int l15 = lane & 15, quad = lane >> 4;
    const int isV = blockIdx.x >> 8;
    const int m0 = (blockIdx.x & 255) * 32;    // slab-local
    const unsigned short* Wh = isV ? Wbh : Wdh;
    const unsigned short* Wl = isV ? Wbl : Wdl;
    float* out = isV ? v : u;
    const int mt = w & 1, ch = w >> 1;

    const size_t arow = (size_t)(m0 + mt * 16 + l15) * 256 + quad * 8;

    f32x4 acc[8];
    #pragma unroll
    for (int nt = 0; nt < 8; ++nt) acc[nt] = (f32x4){0.f, 0.f, 0.f, 0.f};

    for (int s = 0; s < 8; ++s) {
        const s16x8 ah = *(const s16x8*)(ehi + arow + s * 32);
        const s16x8 al = *(const s16x8*)(elo + arow + s * 32);
        #pragma unroll
        for (int nt = 0; nt < 8; ++nt) {
            const int n = (ch * 8 + nt) * 16 + l15;
            const size_t bo = (size_t)n * 256 + s * 32 + quad * 8;
            const s16x8 bh = *(const s16x8*)(Wh + bo);
            const s16x8 bl = *(const s16x8*)(Wl + bo);
            acc[nt] = __builtin_amdgcn_mfma_f32_16x16x32_bf16(ah, bh, acc[nt], 0, 0, 0);
            acc[nt] = __builtin_amdgcn_mfma_f32_16x16x32_bf16(al, bh, acc[nt], 0, 0, 0);
            acc[nt] = __builtin_amdgcn_mfma_f32_16x16x32_bf16(ah, bl, acc[nt], 0, 0, 0);
        }
    }

    #pragma unroll
    for (int nt = 0; nt < 8; ++nt) {
        const int col = (ch * 8 + nt) * 16 + l15;
        const float bias = isV ? 0.f : gb1[col];
        #pragma unroll
        for (int r = 0; r < 4; ++r) {
            const int row = mt * 16 + quad * 4 + r;
            out[(size_t)(m0 + row) * 256 + col] = acc[nt][r] + bias;
        }
    }
}

// ---------------------------------------------------------------------------
// Kernel 5: edge GEMM + max aggregation — LDS-free, barrier-free K-loop.
// Block = 16 points (128 edges). Wave (wm,wn) owns 64 edges x 128 cols.
// ---------------------------------------------------------------------------
__global__ __launch_bounds__(256, 2)
void k_edge(const float* __restrict__ u, const float* __restrict__ v,
            const int* __restrict__ nidx,
            const unsigned short* __restrict__ g2h, const unsigned short* __restrict__ g2l,
            const float* __restrict__ hb,
            float* __restrict__ part, const int cell0)
{
    __shared__ float pmax[2][256];             // 2 KB

    const int t = threadIdx.x, w = t >> 6, lane = t & 63;
    const int l15 = lane & 15, quad = lane >> 4;
    const int wm = w & 1, wn = w >> 1;

    const int b = blockIdx.x;
    const int xcd = b & 7, rest = b >> 3;      // rest 0..63
    const int celll = xcd * 2 + (rest >> 5);   // slab-local cell 0..15
    const int pl0 = celll * NP + (rest & 31) * 16;

    int ur[4], vr[4];
    #pragma unroll
    for (int mt = 0; mt < 4; ++mt) {
        const int e = wm * 64 + mt * 16 + l15;
        const int pt = e >> 3;
        ur[mt] = pl0 + pt;
        int n = nidx[(size_t)(pl0 + pt) * KNN + (e & 7)];
        if ((unsigned)n >= (unsigned)SLABPTS) n = 0;
        vr[mt] = n;
    }

    f32x4 acc[4][8];
    #pragma unroll
    for (int mt = 0; mt < 4; ++mt)
        #pragma unroll
        for (int nt = 0; nt < 8; ++nt) acc[mt][nt] = (f32x4){0.f, 0.f, 0.f, 0.f};

    for (int s = 0; s < 8; ++s) {
        const int k0 = s * 32 + quad * 8;
        s16x8 ah[4], al[4];
        #pragma unroll
        for (int mt = 0; mt < 4; ++mt) {
            const float4 ua = *(const float4*)(u + (size_t)ur[mt] * 256 + k0);
            const float4 ub = *(const float4*)(u + (size_t)ur[mt] * 256 + k0 + 4);
            const float4 va = *(const float4*)(v + (size_t)vr[mt] * 256 + k0);
            const float4 vb = *(const float4*)(v + (size_t)vr[mt] * 256 + k0 + 4);
            const float sv[8] = {
                fmaxf(ua.x + va.x, 0.f), fmaxf(ua.y + va.y, 0.f),
                fmaxf(ua.z + va.z, 0.f), fmaxf(ua.w + va.w, 0.f),
                fmaxf(ub.x + vb.x, 0.f), fmaxf(ub.y + vb.y, 0.f),
                fmaxf(ub.z + vb.z, 0.f), fmaxf(ub.w + vb.w, 0.f)};
            union { s16x8 v8; unsigned short us[8]; } th, tl;
            #pragma unroll
            for (int j = 0; j < 8; ++j) split2(sv[j], th.us[j], tl.us[j]);
            ah[mt] = th.v8; al[mt] = tl.v8;
        }
        #pragma unroll
        for (int nt = 0; nt < 8; ++nt) {
            const int n = wn * 128 + nt * 16 + l15;
            const s16x8 bh = *(const s16x8*)(g2h + (size_t)n * 256 + k0);
            const s16x8 bl = *(const s16x8*)(g2l + (size_t)n * 256 + k0);
            #pragma unroll
            for (int mt = 0; mt < 4; ++mt) {
                acc[mt][nt] = __builtin_amdgcn_mfma_f32_16x16x32_bf16(ah[mt], bh, acc[mt][nt], 0, 0, 0);
                acc[mt][nt] = __builtin_amdgcn_mfma_f32_16x16x32_bf16(al[mt], bh, acc[mt][nt], 0, 0, 0);
                acc[mt][nt] = __builtin_amdgcn_mfma_f32_16x16x32_bf16(ah[mt], bl, acc[mt][nt], 0, 0, 0);
            }
        }
    }

    #pragma unroll
    for (int nt = 0; nt < 8; ++nt) {
        float rm = -3.4e38f;
        #pragma unroll
        for (int mt = 0; mt < 4; ++mt)
            rm = fmaxf(rm, fmaxf(fmaxf(acc[mt][nt][0], acc[mt][nt][1]),
                                 fmaxf(acc[mt][nt][2], acc[mt][nt][3])));
        rm = fmaxf(rm, __shfl_xor(rm, 16, 64));
        rm = fmaxf(rm, __shfl_xor(rm, 32, 64));
        if (quad == 0) pmax[wm][wn * 128 + nt * 16 + l15] = rm;
    }
    __syncthreads();

    const float bm = fmaxf(pmax[0][t], pmax[1][t]) + hb[t];
    const int cell = cell0 + celll;
    const int slot = rest & 31;                // 32 blocks/cell
    part[((size_t)cell * 32 + slot) * 256 + t] = bm;
}

// ---------------------------------------------------------------------------
// Kernel 6: reduce 32 partial maxes per cell, final MLP (f32), L2 normalize.
// ---------------------------------------------------------------------------
__global__ __launch_bounds__(256)
void k_final(const float* __restrict__ part,
             const float* __restrict__ lW1, const float* __restrict__ lb1,
             const float* __restrict__ lW2, const float* __restrict__ lb2,
             float* __restrict__ out)
{
    __shared__ float pooled[256];
    __shared__ float hid[256];
    __shared__ float red[4];

    const int b = blockIdx.x;
    const int t = threadIdx.x;

    float m = -3.4e38f;
    for (int s = 0; s < 32; ++s)
        m = fmaxf(m, part[((size_t)b * 32 + s) * 256 + t]);
    pooled[t] = m;
    __syncthreads();

    float h = lb1[t];
    for (int k = 0; k < 256; k += 4) {
        #pragma unroll
        for (int kk = 0; kk < 4; ++kk)
            h += pooled[k + kk] * lW1[(k + kk) * 256 + t];
    }
    hid[t] = fmaxf(h, 0.f);
    __syncthreads();

    float o = lb2[t];
    for (int k = 0; k < 256; k += 4) {
        #pragma unroll
        for (int kk = 0; kk < 4; ++kk)
            o += hid[k + kk] * lW2[(k + kk) * 256 + t];
    }

    float ss = o * o;
    #pragma unroll
    for (int s = 32; s > 0; s >>= 1) ss += __shfl_down(ss, s, 64);
    if ((t & 63) == 0) red[t >> 6] = ss;
    __syncthreads();
    const float tot = red[0] + red[1] + red[2] + red[3];
    const float rn = 1.f / fmaxf(sqrtf(tot), 1e-12f);
    out[b * 256 + t] = o * rn;
}

// ---------------------------------------------------------------------------
extern "C" void kernel_launch(void* const* d_in, const int* in_sizes, int n_in,
                              void* d_out, int out_size, void* d_ws, size_t ws_size,
                              hipStream_t stream)
{
    (void)n_in; (void)out_size; (void)ws_size;

    const float* class_table = (const float*)d_in[0];
    const float* cW1 = (const float*)d_in[1];
    const float* cb1 = (const float*)d_in[2];
    const float* cW2 = (const float*)d_in[3];
    const float* cb2 = (const float*)d_in[4];
    const float* pW1 = (const float*)d_in[5];
    const float* pb1 = (const float*)d_in[6];
    const float* pW2 = (const float*)d_in[7];
    const float* pb2 = (const float*)d_in[8];
    const float* mW  = (const float*)d_in[9];
    const float* mb  = (const float*)d_in[10];
    const float* gW1 = (const float*)d_in[11];
    const float* gb1 = (const float*)d_in[12];
    const float* g_gamma = (const float*)d_in[13];
    const float* g_beta  = (const float*)d_in[14];
    const float* gW2 = (const float*)d_in[15];
    const float* gb2 = (const float*)d_in[16];
    const float* lW1 = (const float*)d_in[17];
    const float* lb1 = (const float*)d_in[18];
    const float* lW2 = (const float*)d_in[19];
    const float* lb2 = (const float*)d_in[20];
    const float* positions = (const float*)d_in[21];
    const float* colors    = (const float*)d_in[22];
    const int*  cls        = (const int*)d_in[23];

    const int cstride = (in_sizes[23] == 2 * NTOT) ? 2 : 1;

    // workspace layout (bytes), peak ~37 MB (under proven-safe 47.3):
    char* base = (char*)d_ws;
    float*          part   = (float*)(base + 0);               // 2,097,152
    unsigned short* Wdh    = (unsigned short*)(base + 2097152);
    unsigned short* Wdl    = (unsigned short*)(base + 2228224);
    unsigned short* Wbh    = (unsigned short*)(base + 2359296);
    unsigned short* Wbl    = (unsigned short*)(base + 2490368);
    unsigned short* g2h    = (unsigned short*)(base + 2621440);
    unsigned short* g2l    = (unsigned short*)(base + 2752512);
    float*          hb     = (float*)(base + 2883584);
    unsigned short* cW2Th  = (unsigned short*)(base + 2884608);
    unsigned short* cW2Tl  = (unsigned short*)(base + 2917376);
    unsigned short* pW2Th  = (unsigned short*)(base + 2950144);
    unsigned short* pW2Tl  = (unsigned short*)(base + 2982912);
    unsigned short* WcTh   = (unsigned short*)(base + 3015680);
    unsigned short* WcTl   = (unsigned short*)(base + 3048448);
    unsigned short* WpTh   = (unsigned short*)(base + 3081216);
    unsigned short* WpTl   = (unsigned short*)(base + 3113984);
    float*          classMn= (float*)(base + 3146752);         // 31,744
    float*          cbM    = (float*)(base + 3178496);
    float*          pbM    = (float*)(base + 3179520);
    int*            nidx   = (int*)(base + 3180544);           // 262,144
    float*          sqn    = (float*)(base + 3442688);         // 32,768
    unsigned short* ehi    = (unsigned short*)(base + 3475456);// 4,194,304
    unsigned short* elo    = (unsigned short*)(base + 7669760);// 4,194,304
    float*          dist   = (float*)(base + 11864064);        // 16,777,216
    float*          u      = dist;                             // 8,388,608 (aliased)
    float*          v      = (float*)(base + 28641280);        // 8,388,608
    float* out = (float*)d_out;

    k_cvt<<<897, 256, 0, stream>>>(gW1, gW2, g_gamma, g_beta, gb2, cW2, pW2,
                                   Wdh, Wdl, Wbh, Wbl, g2h, g2l, hb,
                                   cW2Th, cW2Tl, pW2Th, pW2Tl);
    k_fold<<<130, 256, 0, stream>>>(cW2, pW2, cb2, pb2, mW,
                                    WcTh, WcTl, WpTh, WpTl, cbM, pbM);
    k_cls<<<31, 256, 0, stream>>>(class_table, mW, classMn);

    for (int s = 0; s < NSLAB; ++s) {
        k_embed<<<SLABPTS / 16, 256, 0, stream>>>(classMn, cW1, cb1, cb2,
                                                  pW1, pb1, pb2, mb,
                                                  cW2Th, cW2Tl, pW2Th, pW2Tl,
                                                  WcTh, WcTl, WpTh, WpTl,
                                                  cbM, pbM,
                                                  positions, colors, cls, cstride,
                                                  ehi, elo, sqn, s * SLABPTS);
        k_gram<<<SLAB * 32, 256, 0, stream>>>(ehi, elo, sqn, dist);
        k_select<<<SLABPTS / 4, 256, 0, stream>>>(dist, nidx);
        k_uv<<<2 * SLABPTS / 32, 256, 0, stream>>>(ehi, elo, Wdh, Wdl, Wbh, Wbl, gb1, u, v);
        k_edge<<<SLABPTS / 16, 256, 0, stream>>>(u, v, nidx, g2h, g2l, hb,
                                                 part, s * SLAB);
    }
    k_final<<<NB, 256, 0, stream>>>(part, lW1, lb1, lW2, lb2, out);
}

// Round 11
// 720.845 us; speedup vs baseline: 2.3660x; 1.0827x over previous
//
#include <hip/hip_runtime.h>

#define EDIM 256
#define KNN 8
#define NB 64
#define NP 512
#define NTOT (NB * NP)
#define SLAB 16
#define NSLAB (NB / SLAB)
#define SLABPTS (SLAB * NP)   // 8192

typedef short s16x8 __attribute__((ext_vector_type(8)));
typedef float f32x4 __attribute__((ext_vector_type(4)));

__device__ __forceinline__ unsigned short f2b(float f) {
    unsigned u = __float_as_uint(f);
    u = (u + 0x7fffu + ((u >> 16) & 1u)) >> 16;   // RNE
    return (unsigned short)u;
}
__device__ __forceinline__ float b2f(unsigned short h) {
    return __uint_as_float(((unsigned)h) << 16);
}
__device__ __forceinline__ void split2(float x, unsigned short& h, unsigned short& l) {
    h = f2b(x);
    l = f2b(x - b2f(h));
}

// ---------------------------------------------------------------------------
// Kernel 0a: weight prep -> transposed bf16 hi/lo pairs.
// ---------------------------------------------------------------------------
__global__ __launch_bounds__(256)
void k_cvt(const float* __restrict__ gW1, const float* __restrict__ gW2,
           const float* __restrict__ g_gamma, const float* __restrict__ g_beta,
           const float* __restrict__ gb2,
           const float* __restrict__ cW2, const float* __restrict__ pW2,
           unsigned short* __restrict__ Wdh, unsigned short* __restrict__ Wdl,
           unsigned short* __restrict__ Wbh, unsigned short* __restrict__ Wbl,
           unsigned short* __restrict__ g2h, unsigned short* __restrict__ g2l,
           float* __restrict__ hb,
           unsigned short* __restrict__ cW2Th, unsigned short* __restrict__ cW2Tl,
           unsigned short* __restrict__ pW2Th, unsigned short* __restrict__ pW2Tl)
{
    const int gid = blockIdx.x * 256 + threadIdx.x;
    unsigned short h, l;
    if (gid < 65536) {
        const int n = gid >> 8, k = gid & 255;
        split2(gW1[k * 256 + n] - gW1[(k + 256) * 256 + n], h, l);
        Wdh[gid] = h; Wdl[gid] = l;
    } else if (gid < 131072) {
        const int i = gid - 65536, n = i >> 8, k = i & 255;
        split2(gW1[(k + 256) * 256 + n], h, l);
        Wbh[i] = h; Wbl[i] = l;
    } else if (gid < 196608) {
        const int i = gid - 131072, n = i >> 8, k = i & 255;
        split2(g_gamma[k] * gW2[k * 256 + n], h, l);
        g2h[i] = h; g2l[i] = l;
    } else if (gid < 196864) {
        const int n = gid - 196608;
        float s = gb2[n];
        for (int k = 0; k < 256; ++k) s += g_beta[k] * gW2[k * 256 + n];
        hb[n] = s;
    } else if (gid < 213248) {
        const int i = gid - 196864, n = i >> 6, k = i & 63;
        split2(cW2[k * 256 + n], h, l);
        cW2Th[i] = h; cW2Tl[i] = l;
    } else if (gid < 229632) {
        const int i = gid - 213248, n = i >> 6, k = i & 63;
        split2(pW2[k * 256 + n], h, l);
        pW2Th[i] = h; pW2Tl[i] = l;
    }
}

// ---------------------------------------------------------------------------
// Kernel 0b: fold merge GEMM into the MLP weights (linearity).
// ---------------------------------------------------------------------------
__global__ __launch_bounds__(256)
void k_fold(const float* __restrict__ cW2, const float* __restrict__ pW2,
            const float* __restrict__ cb2, const float* __restrict__ pb2,
            const float* __restrict__ mW,
            unsigned short* __restrict__ WcTh, unsigned short* __restrict__ WcTl,
            unsigned short* __restrict__ WpTh, unsigned short* __restrict__ WpTl,
            float* __restrict__ cbM, float* __restrict__ pbM)
{
    const int gid = blockIdx.x * 256 + threadIdx.x;
    unsigned short h, l;
    if (gid < 16384) {
        const int j = gid >> 8, n = gid & 255;
        float s = 0.f;
        for (int k = 0; k < 256; ++k) s += cW2[j * 256 + k] * mW[(256 + k) * 256 + n];
        split2(s, h, l);
        WcTh[n * 64 + j] = h; WcTl[n * 64 + j] = l;
    } else if (gid < 32768) {
        const int i = gid - 16384, j = i >> 8, n = i & 255;
        float s = 0.f;
        for (int k = 0; k < 256; ++k) s += pW2[j * 256 + k] * mW[(512 + k) * 256 + n];
        split2(s, h, l);
        WpTh[n * 64 + j] = h; WpTl[n * 64 + j] = l;
    } else if (gid < 33024) {
        const int n = gid - 32768;
        float s = 0.f;
        for (int k = 0; k < 256; ++k) s += cb2[k] * mW[(256 + k) * 256 + n];
        cbM[n] = s;
    } else if (gid < 33280) {
        const int n = gid - 33024;
        float s = 0.f;
        for (int k = 0; k < 256; ++k) s += pb2[k] * mW[(512 + k) * 256 + n];
        pbM[n] = s;
    }
}

// ---------------------------------------------------------------------------
// Kernel 0c: classMn[c] = (class_table[c] / ||class_table[c]||) @ M0.
// ---------------------------------------------------------------------------
__global__ __launch_bounds__(256)
void k_cls(const float* __restrict__ ct, const float* __restrict__ mW,
           float* __restrict__ classMn)
{
    __shared__ float ctn[256];
    __shared__ float red[4];
    const int c = blockIdx.x, t = threadIdx.x;
    const float v = ct[c * 256 + t];
    float ss = v * v;
    #pragma unroll
    for (int s = 32; s > 0; s >>= 1) ss += __shfl_down(ss, s, 64);
    if ((t & 63) == 0) red[t >> 6] = ss;
    __syncthreads();
    const float tot = red[0] + red[1] + red[2] + red[3];
    const float r = 1.f / fmaxf(sqrtf(tot), 1e-12f);
    ctn[t] = v * r;
    __syncthreads();
    float s = 0.f;
    for (int k = 0; k < 256; ++k) s += ctn[k] * mW[k * 256 + t];
    classMn[c * 256 + t] = s;
}

// ---------------------------------------------------------------------------
// Kernel 1: embeddings via folded GEMMs. 16 obj/block.
// ---------------------------------------------------------------------------
__global__ __launch_bounds__(256)
void k_embed(const float* __restrict__ classMn,
             const float* __restrict__ cW1, const float* __restrict__ cb1,
             const float* __restrict__ cb2,
             const float* __restrict__ pW1, const float* __restrict__ pb1,
             const float* __restrict__ pb2,
             const float* __restrict__ mb,
             const unsigned short* __restrict__ cW2Th, const unsigned short* __restrict__ cW2Tl,
             const unsigned short* __restrict__ pW2Th, const unsigned short* __restrict__ pW2Tl,
             const unsigned short* __restrict__ WcTh, const unsigned short* __restrict__ WcTl,
             const unsigned short* __restrict__ WpTh, const unsigned short* __restrict__ WpTl,
             const float* __restrict__ cbM, const float* __restrict__ pbM,
             const float* __restrict__ positions, const float* __restrict__ colors,
             const int* __restrict__ cls, const int cstride,
             unsigned short* __restrict__ ehi, unsigned short* __restrict__ elo,
             float* __restrict__ sqn, const int pbase)
{
    __shared__ __align__(16) unsigned short Ahc[16 * 72];
    __shared__ __align__(16) unsigned short Alc[16 * 72];
    __shared__ __align__(16) unsigned short Ahp[16 * 72];
    __shared__ __align__(16) unsigned short Alp[16 * 72];
    __shared__ float sqc[16][4], sqp_[16][4], sqe[16][4];

    const int t = threadIdx.x, w = t >> 6, lane = t & 63;
    const int l15 = lane & 15, quad = lane >> 4;
    const int obase = blockIdx.x * 16;         // slab-local

    {
        const int o = lane >> 4;               // 0..3
        const int objl = w * 4 + o;
        const int gobj = pbase + obase + objl;
        const float c0 = colors[gobj * 3], c1 = colors[gobj * 3 + 1], c2 = colors[gobj * 3 + 2];
        const float q0 = positions[gobj * 3], q1 = positions[gobj * 3 + 1], q2 = positions[gobj * 3 + 2];
        const int u0 = (lane & 15) * 4;
        #pragma unroll
        for (int uu = 0; uu < 4; ++uu) {
            const int u = u0 + uu;
            const float hc = fmaxf(cb1[u] + c0 * cW1[u] + c1 * cW1[64 + u] + c2 * cW1[128 + u], 0.f);
            const float hp = fmaxf(pb1[u] + q0 * pW1[u] + q1 * pW1[64 + u] + q2 * pW1[128 + u], 0.f);
            unsigned short h, l;
            split2(hc, h, l); Ahc[objl * 72 + u] = h; Alc[objl * 72 + u] = l;
            split2(hp, h, l); Ahp[objl * 72 + u] = h; Alp[objl * 72 + u] = l;
        }
    }
    __syncthreads();

    f32x4 aco[4], ape[4];
    #pragma unroll
    for (int nt = 0; nt < 4; ++nt) { aco[nt] = (f32x4){0.f,0.f,0.f,0.f}; ape[nt] = (f32x4){0.f,0.f,0.f,0.f}; }

    #pragma unroll
    for (int kt = 0; kt < 2; ++kt) {
        const int ao = l15 * 72 + kt * 32 + quad * 8;
        const s16x8 ahc = *(const s16x8*)&Ahc[ao];
        const s16x8 alc = *(const s16x8*)&Alc[ao];
        const s16x8 ahp = *(const s16x8*)&Ahp[ao];
        const s16x8 alp = *(const s16x8*)&Alp[ao];
        #pragma unroll
        for (int nt = 0; nt < 4; ++nt) {
            const int n = w * 64 + nt * 16 + l15;
            const size_t bo = (size_t)n * 64 + kt * 32 + quad * 8;
            const s16x8 cbh = *(const s16x8*)(cW2Th + bo);
            const s16x8 cbl = *(const s16x8*)(cW2Tl + bo);
            const s16x8 pbh = *(const s16x8*)(pW2Th + bo);
            const s16x8 pbl = *(const s16x8*)(pW2Tl + bo);
            aco[nt] = __builtin_amdgcn_mfma_f32_16x16x32_bf16(ahc, cbh, aco[nt], 0, 0, 0);
            ape[nt] = __builtin_amdgcn_mfma_f32_16x16x32_bf16(ahp, pbh, ape[nt], 0, 0, 0);
            aco[nt] = __builtin_amdgcn_mfma_f32_16x16x32_bf16(alc, cbh, aco[nt], 0, 0, 0);
            ape[nt] = __builtin_amdgcn_mfma_f32_16x16x32_bf16(alp, pbh, ape[nt], 0, 0, 0);
            aco[nt] = __builtin_amdgcn_mfma_f32_16x16x32_bf16(ahc, cbl, aco[nt], 0, 0, 0);
            ape[nt] = __builtin_amdgcn_mfma_f32_16x16x32_bf16(ahp, pbl, ape[nt], 0, 0, 0);
        }
    }

    float sc[4] = {0.f,0.f,0.f,0.f}, sp[4] = {0.f,0.f,0.f,0.f};
    #pragma unroll
    for (int nt = 0; nt < 4; ++nt) {
        const int col = w * 64 + nt * 16 + l15;
        const float cbv = cb2[col], pbv = pb2[col];
        #pragma unroll
        for (int r = 0; r < 4; ++r) {
            const float co = aco[nt][r] + cbv;
            const float pe = ape[nt][r] + pbv;
            sc[r] += co * co;
            sp[r] += pe * pe;
        }
    }
    #pragma unroll
    for (int s = 8; s > 0; s >>= 1) {
        #pragma unroll
        for (int r = 0; r < 4; ++r) {
            sc[r] += __shfl_xor(sc[r], s, 64);
            sp[r] += __shfl_xor(sp[r], s, 64);
        }
    }
    if (l15 == 0) {
        #pragma unroll
        for (int r = 0; r < 4; ++r) { sqc[quad * 4 + r][w] = sc[r]; sqp_[quad * 4 + r][w] = sp[r]; }
    }
    __syncthreads();

    float rco[4], rpe[4];
    #pragma unroll
    for (int r = 0; r < 4; ++r) {
        const int row = quad * 4 + r;
        rco[r] = 1.f / fmaxf(sqrtf(sqc[row][0] + sqc[row][1] + sqc[row][2] + sqc[row][3]), 1e-12f);
        rpe[r] = 1.f / fmaxf(sqrtf(sqp_[row][0] + sqp_[row][1] + sqp_[row][2] + sqp_[row][3]), 1e-12f);
    }

    f32x4 ac[4], ap[4];
    #pragma unroll
    for (int nt = 0; nt < 4; ++nt) { ac[nt] = (f32x4){0.f,0.f,0.f,0.f}; ap[nt] = (f32x4){0.f,0.f,0.f,0.f}; }

    #pragma unroll
    for (int kt = 0; kt < 2; ++kt) {
        const int ao = l15 * 72 + kt * 32 + quad * 8;
        const s16x8 ahc = *(const s16x8*)&Ahc[ao];
        const s16x8 alc = *(const s16x8*)&Alc[ao];
        const s16x8 ahp = *(const s16x8*)&Ahp[ao];
        const s16x8 alp = *(const s16x8*)&Alp[ao];
        #pragma unroll
        for (int nt = 0; nt < 4; ++nt) {
            const int n = w * 64 + nt * 16 + l15;
            const size_t bo = (size_t)n * 64 + kt * 32 + quad * 8;
            const s16x8 cbh = *(const s16x8*)(WcTh + bo);
            const s16x8 cbl = *(const s16x8*)(WcTl + bo);
            const s16x8 pbh = *(const s16x8*)(WpTh + bo);
            const s16x8 pbl = *(const s16x8*)(WpTl + bo);
            ac[nt] = __builtin_amdgcn_mfma_f32_16x16x32_bf16(ahc, cbh, ac[nt], 0, 0, 0);
            ap[nt] = __builtin_amdgcn_mfma_f32_16x16x32_bf16(ahp, pbh, ap[nt], 0, 0, 0);
            ac[nt] = __builtin_amdgcn_mfma_f32_16x16x32_bf16(alc, cbh, ac[nt], 0, 0, 0);
            ap[nt] = __builtin_amdgcn_mfma_f32_16x16x32_bf16(alp, pbh, ap[nt], 0, 0, 0);
            ac[nt] = __builtin_amdgcn_mfma_f32_16x16x32_bf16(ahc, cbl, ac[nt], 0, 0, 0);
            ap[nt] = __builtin_amdgcn_mfma_f32_16x16x32_bf16(ahp, pbl, ap[nt], 0, 0, 0);
        }
    }

    int ci[4];
    #pragma unroll
    for (int r = 0; r < 4; ++r) {
        const int gobj = pbase + obase + quad * 4 + r;
        int c = cls[(size_t)gobj * cstride];
        if ((unsigned)c > 30u) c = 0;
        ci[r] = c;
    }

    float rp[4] = {0.f,0.f,0.f,0.f};
    #pragma unroll
    for (int nt = 0; nt < 4; ++nt) {
        const int col = w * 64 + nt * 16 + l15;
        const float mbv = mb[col], cbMv = cbM[col], pbMv = pbM[col];
        #pragma unroll
        for (int r = 0; r < 4; ++r) {
            const int row = quad * 4 + r;
            const float e = classMn[ci[r] * 256 + col]
                          + rco[r] * (ac[nt][r] + cbMv)
                          + rpe[r] * (ap[nt][r] + pbMv) + mbv;
            unsigned short h, l;
            split2(e, h, l);
            ehi[(size_t)(obase + row) * 256 + col] = h;
            elo[(size_t)(obase + row) * 256 + col] = l;
            rp[r] += e * e;
        }
    }
    #pragma unroll
    for (int s = 8; s > 0; s >>= 1) {
        #pragma unroll
        for (int r = 0; r < 4; ++r) rp[r] += __shfl_xor(rp[r], s, 64);
    }
    if (l15 == 0) {
        #pragma unroll
        for (int r = 0; r < 4; ++r) sqe[quad * 4 + r][w] = rp[r];
    }
    __syncthreads();
    if (t < 16) sqn[obase + t] = sqe[t][0] + sqe[t][1] + sqe[t][2] + sqe[t][3];
}

// ---------------------------------------------------------------------------
// Kernel 2: Gram/distance via 3-pass split MFMA, 128x64 tile per block.
// ---------------------------------------------------------------------------
__global__ __launch_bounds__(256)
void k_gram(const unsigned short* __restrict__ ehi, const unsigned short* __restrict__ elo,
            const float* __restrict__ sqn, float* __restrict__ dist)
{
    const int t = threadIdx.x, w = t >> 6, lane = t & 63;
    const int l15 = lane & 15, quad = lane >> 4;
    const int b_local = blockIdx.x >> 5;       // 0..15 (32 blocks/cell)
    const int tile = blockIdx.x & 31;
    const int p0 = (tile >> 3) * 128, q0 = (tile & 7) * 64;
    const size_t cb = (size_t)b_local * NP;

    f32x4 acc[2][4];
    #pragma unroll
    for (int sub = 0; sub < 2; ++sub)
        #pragma unroll
        for (int nt = 0; nt < 4; ++nt) acc[sub][nt] = (f32x4){0.f, 0.f, 0.f, 0.f};

    for (int s = 0; s < 8; ++s) {
        s16x8 ah[2], al[2];
        #pragma unroll
        for (int sub = 0; sub < 2; ++sub) {
            const size_t ao = (cb + p0 + sub * 64 + 16 * w + l15) * 256 + s * 32 + quad * 8;
            ah[sub] = *(const s16x8*)(ehi + ao);
            al[sub] = *(const s16x8*)(elo + ao);
        }
        #pragma unroll
        for (int nt = 0; nt < 4; ++nt) {
            const size_t bo = (cb + q0 + nt * 16 + l15) * 256 + s * 32 + quad * 8;
            const s16x8 bh = *(const s16x8*)(ehi + bo);
            const s16x8 bl = *(const s16x8*)(elo + bo);
            #pragma unroll
            for (int sub = 0; sub < 2; ++sub) {
                acc[sub][nt] = __builtin_amdgcn_mfma_f32_16x16x32_bf16(ah[sub], bh, acc[sub][nt], 0, 0, 0);
                acc[sub][nt] = __builtin_amdgcn_mfma_f32_16x16x32_bf16(al[sub], bh, acc[sub][nt], 0, 0, 0);
                acc[sub][nt] = __builtin_amdgcn_mfma_f32_16x16x32_bf16(ah[sub], bl, acc[sub][nt], 0, 0, 0);
            }
        }
    }

    #pragma unroll
    for (int sub = 0; sub < 2; ++sub) {
        float sqp[4];
        #pragma unroll
        for (int r = 0; r < 4; ++r)
            sqp[r] = sqn[cb + p0 + sub * 64 + 16 * w + quad * 4 + r];
        #pragma unroll
        for (int nt = 0; nt < 4; ++nt) {
            const int colq = q0 + nt * 16 + l15;
            const float sq_q = sqn[cb + colq];
            #pragma unroll
            for (int r = 0; r < 4; ++r) {
                const int rowp = p0 + sub * 64 + 16 * w + quad * 4 + r;
                dist[(cb + rowp) * NP + colq] = (sqp[r] + sq_q) - 2.f * acc[sub][nt][r];
            }
        }
    }
}

// ---------------------------------------------------------------------------
// Kernel 3: top-8 smallest per point (ties -> lowest index). One wave/point.
// ---------------------------------------------------------------------------
__global__ __launch_bounds__(256)
void k_select(const float* __restrict__ dist, int* __restrict__ nidx)
{
    const int wv = threadIdx.x >> 6, lane = threadIdx.x & 63;
    const int p_sl = blockIdx.x * 4 + wv;          // 0..8191
    const float* row = dist + (size_t)p_sl * NP;

    float d[8]; int q[8];
    #pragma unroll
    for (int i = 0; i < 8; ++i) { q[i] = lane + 64 * i; d[i] = row[lane + 64 * i]; }

    for (int r = 0; r < KNN; ++r) {
        float bd = d[0]; int bq = q[0];
        #pragma unroll
        for (int i = 1; i < 8; ++i)
            if (d[i] < bd || (d[i] == bd && q[i] < bq)) { bd = d[i]; bq = q[i]; }
        #pragma unroll
        for (int s = 32; s > 0; s >>= 1) {
            const float od = __shfl_down(bd, s, 64);
            const int oq = __shfl_down(bq, s, 64);
            if (od < bd || (od == bd && oq < bq)) { bd = od; bq = oq; }
        }
        const int win = __shfl(bq, 0, 64);
        if (lane == 0) nidx[(size_t)p_sl * KNN + r] = ((p_sl >> 9) << 9) | win;
        if ((win & 63) == lane) {
            const int wi = win >> 6;
            #pragma unroll
            for (int i = 0; i < 8; ++i) if (wi == i) d[i] = 3.4e38f;
        }
    }
}

// ---------------------------------------------------------------------------
// Kernel 4: u = x@Wd+gb1, v = x@Wb via 3-pass split MFMA. 32 points/block.
// ---------------------------------------------------------------------------
__global__ __launch_bounds__(256)
void k_uv(const unsigned short* __restrict__ ehi, const unsigned short* __restrict__ elo,
          const unsigned short* __restrict__ Wdh, const unsigned short* __restrict__ Wdl,
          const unsigned short* __restrict__ Wbh, const unsigned short* __restrict__ Wbl,
          const float* __restrict__ gb1,
          float* __restrict__ u, float* __restrict__ v)
{
    const int t = threadIdx.x, w = t >> 6, lane = t & 63;
    const int l15 = lane & 15, quad = lane >> 4;
    const int isV = blockIdx.x >> 8;
    const int m0 = (blockIdx.x & 255) * 32;    // slab-local
    const unsigned short* Wh = isV ? Wbh : Wdh;
    const unsigned short* Wl = isV ? Wbl : Wdl;
    float* out = isV ? v : u;
    const int mt = w & 1, ch = w >> 1;

    const size_t arow = (size_t)(m0 + mt * 16 + l15) * 256 + quad * 8;

    f32x4 acc[8];
    #pragma unroll
    for (int nt = 0; nt < 8; ++nt) acc[nt] = (f32x4){0.f, 0.f, 0.f, 0.f};

    for (int s = 0; s < 8; ++s) {
        const s16x8 ah = *(const s16x8*)(ehi + arow + s * 32);
        const s16x8 al = *(const s16x8*)(elo + arow + s * 32);
        #pragma unroll
        for (int nt = 0; nt < 8; ++nt) {
            const int n = (ch * 8 + nt) * 16 + l15;
            const size_t bo = (size_t)n * 256 + s * 32 + quad * 8;
            const s16x8 bh = *(const s16x8*)(Wh + bo);
            const s16x8 bl = *(const s16x8*)(Wl + bo);
            acc[nt] = __builtin_amdgcn_mfma_f32_16x16x32_bf16(ah, bh, acc[nt], 0, 0, 0);
            acc[nt] = __builtin_amdgcn_mfma_f32_16x16x32_bf16(al, bh, acc[nt], 0, 0, 0);
            acc[nt] = __builtin_amdgcn_mfma_f32_16x16x32_bf16(ah, bl, acc[nt], 0, 0, 0);
        }
    }

    #pragma unroll
    for (int nt = 0; nt < 8; ++nt) {
        const int col = (ch * 8 + nt) * 16 + l15;
        const float bias = isV ? 0.f : gb1[col];
        #pragma unroll
        for (int r = 0; r < 4; ++r) {
            const int row = mt * 16 + quad * 4 + r;
            out[(size_t)(m0 + row) * 256 + col] = acc[nt][r] + bias;
        }
    }
}

// ---------------------------------------------------------------------------
// Kernel 5: edge GEMM + max aggregation. Block = 8 points (64 edges), 4 waves;
// wave w = all 64 edges x cols w*64..+63 (acc 4x4). A = relu(u_p+v_j) split
// hi/lo, staged ONCE per block into double-buffered LDS (stride 36 ->
// conflict-free b64 reads); B direct from L2. One barrier per k-step; the
// stage for s+1 issues before MFMA(s) so its latency hides under other waves.
// Per-col 64-edge max completes in-register + 2 shuffles -> direct part write.
// ---------------------------------------------------------------------------
__global__ __launch_bounds__(256)
void k_edge(const float* __restrict__ u, const float* __restrict__ v,
            const int* __restrict__ nidx,
            const unsigned short* __restrict__ g2h, const unsigned short* __restrict__ g2l,
            const float* __restrict__ hb,
            float* __restrict__ part, const int cell0)
{
    __shared__ unsigned short Abuf[2][2][2304];   // [dbuf][hi/lo][edge*36+k], 18.4 KB

    const int t = threadIdx.x, w = t >> 6, lane = t & 63;
    const int l15 = lane & 15, quad = lane >> 4;

    // XCD swizzle: blockIdx%8 ~ XCD; 2 whole cells per XCD.
    const int b = blockIdx.x;
    const int xcd = b & 7, rest = b >> 3;        // rest 0..127
    const int celll = xcd * 2 + (rest >> 6);     // slab-local cell 0..15
    const int pl0 = celll * NP + (rest & 63) * 8;

    // staging role: edge se = t>>2 (0..63), k-chunk kq = t&3 (8 k's each)
    const int se = t >> 2, kq = t & 3;
    const int surow = pl0 + (se >> 3);
    int svrow = nidx[(size_t)surow * KNN + (se & 7)];
    if ((unsigned)svrow >= (unsigned)SLABPTS) svrow = 0;

    #define STAGE(S, BUF)                                                        \
    {                                                                            \
        const int k0 = (S) * 32 + kq * 8;                                        \
        const float4 ua = *(const float4*)(u + (size_t)surow * 256 + k0);        \
        const float4 ub = *(const float4*)(u + (size_t)surow * 256 + k0 + 4);    \
        const float4 va = *(const float4*)(v + (size_t)svrow * 256 + k0);        \
        const float4 vb = *(const float4*)(v + (size_t)svrow * 256 + k0 + 4);    \
        const float sv[8] = {                                                    \
            fmaxf(ua.x + va.x, 0.f), fmaxf(ua.y + va.y, 0.f),                    \
            fmaxf(ua.z + va.z, 0.f), fmaxf(ua.w + va.w, 0.f),                    \
            fmaxf(ub.x + vb.x, 0.f), fmaxf(ub.y + vb.y, 0.f),                    \
            fmaxf(ub.z + vb.z, 0.f), fmaxf(ub.w + vb.w, 0.f)};                   \
        union { uint2 q[2]; unsigned short us[8]; } th, tl;                      \
        _Pragma("unroll")                                                        \
        for (int j = 0; j < 8; ++j) { split2(sv[j], th.us[j], tl.us[j]); }       \
        *(uint2*)&Abuf[BUF][0][se * 36 + kq * 8]     = th.q[0];                  \
        *(uint2*)&Abuf[BUF][0][se * 36 + kq * 8 + 4] = th.q[1];                  \
        *(uint2*)&Abuf[BUF][1][se * 36 + kq * 8]     = tl.q[0];                  \
        *(uint2*)&Abuf[BUF][1][se * 36 + kq * 8 + 4] = tl.q[1];                  \
    }

    f32x4 acc[4][4];
    #pragma unroll
    for (int mt = 0; mt < 4; ++mt)
        #pragma unroll
        for (int nt = 0; nt < 4; ++nt) acc[mt][nt] = (f32x4){0.f, 0.f, 0.f, 0.f};

    STAGE(0, 0);
    for (int s = 0; s < 8; ++s) {
        __syncthreads();                      // buf[s&1] writes visible; buf[(s+1)&1] free
        if (s < 7) STAGE(s + 1, (s + 1) & 1);

        const int k0 = s * 32 + quad * 8;
        s16x8 ah[4], al[4];
        #pragma unroll
        for (int mt = 0; mt < 4; ++mt) {
            const int ao = (mt * 16 + l15) * 36 + quad * 8;
            union { uint2 q[2]; s16x8 v8; } Th, Tl;
            Th.q[0] = *(const uint2*)&Abuf[s & 1][0][ao];
            Th.q[1] = *(const uint2*)&Abuf[s & 1][0][ao + 4];
            Tl.q[0] = *(const uint2*)&Abuf[s & 1][1][ao];
            Tl.q[1] = *(const uint2*)&Abuf[s & 1][1][ao + 4];
            ah[mt] = Th.v8; al[mt] = Tl.v8;
        }
        #pragma unroll
        for (int nt = 0; nt < 4; ++nt) {
            const int n = w * 64 + nt * 16 + l15;
            const s16x8 bh = *(const s16x8*)(g2h + (size_t)n * 256 + k0);
            const s16x8 bl = *(const s16x8*)(g2l + (size_t)n * 256 + k0);
            #pragma unroll
            for (int mt = 0; mt < 4; ++mt) {
                acc[mt][nt] = __builtin_amdgcn_mfma_f32_16x16x32_bf16(ah[mt], bh, acc[mt][nt], 0, 0, 0);
                acc[mt][nt] = __builtin_amdgcn_mfma_f32_16x16x32_bf16(al[mt], bh, acc[mt][nt], 0, 0, 0);
                acc[mt][nt] = __builtin_amdgcn_mfma_f32_16x16x32_bf16(ah[mt], bl, acc[mt][nt], 0, 0, 0);
            }
        }
    }
    #undef STAGE

    // per-col max over all 64 edges (covers the block's 8 points)
    const int cell = cell0 + celll;
    const int slot = rest & 63;
    #pragma unroll
    for (int nt = 0; nt < 4; ++nt) {
        float rm = -3.4e38f;
        #pragma unroll
        for (int mt = 0; mt < 4; ++mt)
            rm = fmaxf(rm, fmaxf(fmaxf(acc[mt][nt][0], acc[mt][nt][1]),
                                 fmaxf(acc[mt][nt][2], acc[mt][nt][3])));
        rm = fmaxf(rm, __shfl_xor(rm, 16, 64));
        rm = fmaxf(rm, __shfl_xor(rm, 32, 64));
        if (quad == 0) {
            const int col = w * 64 + nt * 16 + l15;
            part[((size_t)cell * 64 + slot) * 256 + col] = rm + hb[col];
        }
    }
}

// ---------------------------------------------------------------------------
// Kernel 6: reduce 64 partial maxes per cell, final MLP (f32), L2 normalize.
// ---------------------------------------------------------------------------
__global__ __launch_bounds__(256)
void k_final(const float* __restrict__ part,
             const float* __restrict__ lW1, const float* __restrict__ lb1,
             const float* __restrict__ lW2, const float* __restrict__ lb2,
             float* __restrict__ out)
{
    __shared__ float pooled[256];
    __shared__ float hid[256];
    __shared__ float red[4];

    const int b = blockIdx.x;
    const int t = threadIdx.x;

    float m = -3.4e38f;
    for (int s = 0; s < 64; ++s)
        m = fmaxf(m, part[((size_t)b * 64 + s) * 256 + t]);
    pooled[t] = m;
    __syncthreads();

    float h = lb1[t];
    for (int k = 0; k < 256; k += 4) {
        #pragma unroll
        for (int kk = 0; kk < 4; ++kk)
            h += pooled[k + kk] * lW1[(k + kk) * 256 + t];
    }
    hid[t] = fmaxf(h, 0.f);
    __syncthreads();

    float o = lb2[t];
    for (int k = 0; k < 256; k += 4) {
        #pragma unroll
        for (int kk = 0; kk < 4; ++kk)
            o += hid[k + kk] * lW2[(k + kk) * 256 + t];
    }

    float ss = o * o;
    #pragma unroll
    for (int s = 32; s > 0; s >>= 1) ss += __shfl_down(ss, s, 64);
    if ((t & 63) == 0) red[t >> 6] = ss;
    __syncthreads();
    const float tot = red[0] + red[1] + red[2] + red[3];
    const float rn = 1.f / fmaxf(sqrtf(tot), 1e-12f);
    out[b * 256 + t] = o * rn;
}

// ---------------------------------------------------------------------------
extern "C" void kernel_launch(void* const* d_in, const int* in_sizes, int n_in,
                              void* d_out, int out_size, void* d_ws, size_t ws_size,
                              hipStream_t stream)
{
    (void)n_in; (void)out_size; (void)ws_size;

    const float* class_table = (const float*)d_in[0];
    const float* cW1 = (const float*)d_in[1];
    const float* cb1 = (const float*)d_in[2];
    const float* cW2 = (const float*)d_in[3];
    const float* cb2 = (const float*)d_in[4];
    const float* pW1 = (const float*)d_in[5];
    const float* pb1 = (const float*)d_in[6];
    const float* pW2 = (const float*)d_in[7];
    const float* pb2 = (const float*)d_in[8];
    const float* mW  = (const float*)d_in[9];
    const float* mb  = (const float*)d_in[10];
    const float* gW1 = (const float*)d_in[11];
    const float* gb1 = (const float*)d_in[12];
    const float* g_gamma = (const float*)d_in[13];
    const float* g_beta  = (const float*)d_in[14];
    const float* gW2 = (const float*)d_in[15];
    const float* gb2 = (const float*)d_in[16];
    const float* lW1 = (const float*)d_in[17];
    const float* lb1 = (const float*)d_in[18];
    const float* lW2 = (const float*)d_in[19];
    const float* lb2 = (const float*)d_in[20];
    const float* positions = (const float*)d_in[21];
    const float* colors    = (const float*)d_in[22];
    const int*  cls        = (const int*)d_in[23];

    const int cstride = (in_sizes[23] == 2 * NTOT) ? 2 : 1;

    // workspace layout (bytes), peak ~39.1 MB (under proven-safe 47.3):
    char* base = (char*)d_ws;
    float*          part   = (float*)(base + 0);               // 4,194,304
    unsigned short* Wdh    = (unsigned short*)(base + 4194304);
    unsigned short* Wdl    = (unsigned short*)(base + 4325376);
    unsigned short* Wbh    = (unsigned short*)(base + 4456448);
    unsigned short* Wbl    = (unsigned short*)(base + 4587520);
    unsigned short* g2h    = (unsigned short*)(base + 4718592);
    unsigned short* g2l    = (unsigned short*)(base + 4849664);
    float*          hb     = (float*)(base + 4980736);
    unsigned short* cW2Th  = (unsigned short*)(base + 4981760);
    unsigned short* cW2Tl  = (unsigned short*)(base + 5014528);
    unsigned short* pW2Th  = (unsigned short*)(base + 5047296);
    unsigned short* pW2Tl  = (unsigned short*)(base + 5080064);
    unsigned short* WcTh   = (unsigned short*)(base + 5112832);
    unsigned short* WcTl   = (unsigned short*)(base + 5145600);
    unsigned short* WpTh   = (unsigned short*)(base + 5178368);
    unsigned short* WpTl   = (unsigned short*)(base + 5211136);
    float*          classMn= (float*)(base + 5243904);         // 31,744
    float*          cbM    = (float*)(base + 5275648);
    float*          pbM    = (float*)(base + 5276672);
    int*            nidx   = (int*)(base + 5277696);           // 262,144
    float*          sqn    = (float*)(base + 5539840);         // 32,768
    unsigned short* ehi    = (unsigned short*)(base + 5572608);// 4,194,304
    unsigned short* elo    = (unsigned short*)(base + 9766912);// 4,194,304
    float*          dist   = (float*)(base + 13961216);        // 16,777,216
    float*          u      = dist;                             // 8,388,608 (aliased)
    float*          v      = (float*)(base + 30738432);        // 8,388,608
    float* out = (float*)d_out;

    k_cvt<<<897, 256, 0, stream>>>(gW1, gW2, g_gamma, g_beta, gb2, cW2, pW2,
                                   Wdh, Wdl, Wbh, Wbl, g2h, g2l, hb,
                                   cW2Th, cW2Tl, pW2Th, pW2Tl);
    k_fold<<<130, 256, 0, stream>>>(cW2, pW2, cb2, pb2, mW,
                                    WcTh, WcTl, WpTh, WpTl, cbM, pbM);
    k_cls<<<31, 256, 0, stream>>>(class_table, mW, classMn);

    for (int s = 0; s < NSLAB; ++s) {
        k_embed<<<SLABPTS / 16, 256, 0, stream>>>(classMn, cW1, cb1, cb2,
                                                  pW1, pb1, pb2, mb,
                                                  cW2Th, cW2Tl, pW2Th, pW2Tl,
                                                  WcTh, WcTl, WpTh, WpTl,
                                                  cbM, pbM,
                                                  positions, colors, cls, cstride,
                                                  ehi, elo, sqn, s * SLABPTS);
        k_gram<<<SLAB * 32, 256, 0, stream>>>(ehi, elo, sqn, dist);
        k_select<<<SLABPTS / 4, 256, 0, stream>>>(dist, nidx);
        k_uv<<<2 * SLABPTS / 32, 256, 0, stream>>>(ehi, elo, Wdh, Wdl, Wbh, Wbl, gb1, u, v);
        k_edge<<<SLABPTS / 8, 256, 0, stream>>>(u, v, nidx, g2h, g2l, hb,
                                                part, s * SLAB);
    }
    k_final<<<NB, 256, 0, stream>>>(part, lW1, lb1, lW2, lb2, out);
}

// Round 12
// 621.872 us; speedup vs baseline: 2.7426x; 1.1592x over previous
//
#include <hip/hip_runtime.h>

#define EDIM 256
#define KNN 8
#define NB 64
#define NP 512
#define NTOT (NB * NP)
#define SLAB 16
#define NSLAB (NB / SLAB)
#define SLABPTS (SLAB * NP)   // 8192

typedef short s16x8 __attribute__((ext_vector_type(8)));
typedef float f32x4 __attribute__((ext_vector_type(4)));

__device__ __forceinline__ unsigned short f2b(float f) {
    unsigned u = __float_as_uint(f);
    u = (u + 0x7fffu + ((u >> 16) & 1u)) >> 16;   // RNE
    return (unsigned short)u;
}
__device__ __forceinline__ float b2f(unsigned short h) {
    return __uint_as_float(((unsigned)h) << 16);
}
__device__ __forceinline__ void split2(float x, unsigned short& h, unsigned short& l) {
    h = f2b(x);
    l = f2b(x - b2f(h));
}

// ---------------------------------------------------------------------------
// Kernel 0a: weight prep -> transposed bf16 hi/lo pairs.
// ---------------------------------------------------------------------------
__global__ __launch_bounds__(256)
void k_cvt(const float* __restrict__ gW1, const float* __restrict__ gW2,
           const float* __restrict__ g_gamma, const float* __restrict__ g_beta,
           const float* __restrict__ gb2,
           const float* __restrict__ cW2, const float* __restrict__ pW2,
           unsigned short* __restrict__ Wdh, unsigned short* __restrict__ Wdl,
           unsigned short* __restrict__ Wbh, unsigned short* __restrict__ Wbl,
           unsigned short* __restrict__ g2h, unsigned short* __restrict__ g2l,
           float* __restrict__ hb,
           unsigned short* __restrict__ cW2Th, unsigned short* __restrict__ cW2Tl,
           unsigned short* __restrict__ pW2Th, unsigned short* __restrict__ pW2Tl)
{
    const int gid = blockIdx.x * 256 + threadIdx.x;
    unsigned short h, l;
    if (gid < 65536) {
        const int n = gid >> 8, k = gid & 255;
        split2(gW1[k * 256 + n] - gW1[(k + 256) * 256 + n], h, l);
        Wdh[gid] = h; Wdl[gid] = l;
    } else if (gid < 131072) {
        const int i = gid - 65536, n = i >> 8, k = i & 255;
        split2(gW1[(k + 256) * 256 + n], h, l);
        Wbh[i] = h; Wbl[i] = l;
    } else if (gid < 196608) {
        const int i = gid - 131072, n = i >> 8, k = i & 255;
        split2(g_gamma[k] * gW2[k * 256 + n], h, l);
        g2h[i] = h; g2l[i] = l;
    } else if (gid < 196864) {
        const int n = gid - 196608;
        float s = gb2[n];
        for (int k = 0; k < 256; ++k) s += g_beta[k] * gW2[k * 256 + n];
        hb[n] = s;
    } else if (gid < 213248) {
        const int i = gid - 196864, n = i >> 6, k = i & 63;
        split2(cW2[k * 256 + n], h, l);
        cW2Th[i] = h; cW2Tl[i] = l;
    } else if (gid < 229632) {
        const int i = gid - 213248, n = i >> 6, k = i & 63;
        split2(pW2[k * 256 + n], h, l);
        pW2Th[i] = h; pW2Tl[i] = l;
    }
}

// ---------------------------------------------------------------------------
// Kernel 0b: fold merge GEMM into the MLP weights (linearity).
// ---------------------------------------------------------------------------
__global__ __launch_bounds__(256)
void k_fold(const float* __restrict__ cW2, const float* __restrict__ pW2,
            const float* __restrict__ cb2, const float* __restrict__ pb2,
            const float* __restrict__ mW,
            unsigned short* __restrict__ WcTh, unsigned short* __restrict__ WcTl,
            unsigned short* __restrict__ WpTh, unsigned short* __restrict__ WpTl,
            float* __restrict__ cbM, float* __restrict__ pbM)
{
    const int gid = blockIdx.x * 256 + threadIdx.x;
    unsigned short h, l;
    if (gid < 16384) {
        const int j = gid >> 8, n = gid & 255;
        float s = 0.f;
        for (int k = 0; k < 256; ++k) s += cW2[j * 256 + k] * mW[(256 + k) * 256 + n];
        split2(s, h, l);
        WcTh[n * 64 + j] = h; WcTl[n * 64 + j] = l;
    } else if (gid < 32768) {
        const int i = gid - 16384, j = i >> 8, n = i & 255;
        float s = 0.f;
        for (int k = 0; k < 256; ++k) s += pW2[j * 256 + k] * mW[(512 + k) * 256 + n];
        split2(s, h, l);
        WpTh[n * 64 + j] = h; WpTl[n * 64 + j] = l;
    } else if (gid < 33024) {
        const int n = gid - 32768;
        float s = 0.f;
        for (int k = 0; k < 256; ++k) s += cb2[k] * mW[(256 + k) * 256 + n];
        cbM[n] = s;
    } else if (gid < 33280) {
        const int n = gid - 33024;
        float s = 0.f;
        for (int k = 0; k < 256; ++k) s += pb2[k] * mW[(512 + k) * 256 + n];
        pbM[n] = s;
    }
}

// ---------------------------------------------------------------------------
// Kernel 0c: classMn[c] = (class_table[c] / ||class_table[c]||) @ M0.
// ---------------------------------------------------------------------------
__global__ __launch_bounds__(256)
void k_cls(const float* __restrict__ ct, const float* __restrict__ mW,
           float* __restrict__ classMn)
{
    __shared__ float ctn[256];
    __shared__ float red[4];
    const int c = blockIdx.x, t = threadIdx.x;
    const float v = ct[c * 256 + t];
    float ss = v * v;
    #pragma unroll
    for (int s = 32; s > 0; s >>= 1) ss += __shfl_down(ss, s, 64);
    if ((t & 63) == 0) red[t >> 6] = ss;
    __syncthreads();
    const float tot = red[0] + red[1] + red[2] + red[3];
    const float r = 1.f / fmaxf(sqrtf(tot), 1e-12f);
    ctn[t] = v * r;
    __syncthreads();
    float s = 0.f;
    for (int k = 0; k < 256; ++k) s += ctn[k] * mW[k * 256 + t];
    classMn[c * 256 + t] = s;
}

// ---------------------------------------------------------------------------
// Kernel 1: embeddings via folded GEMMs. 16 obj/block.
// ---------------------------------------------------------------------------
__global__ __launch_bounds__(256)
void k_embed(const float* __restrict__ classMn,
             const float* __restrict__ cW1, const float* __restrict__ cb1,
             const float* __restrict__ cb2,
             const float* __restrict__ pW1, const float* __restrict__ pb1,
             const float* __restrict__ pb2,
             const float* __restrict__ mb,
             const unsigned short* __restrict__ cW2Th, const unsigned short* __restrict__ cW2Tl,
             const unsigned short* __restrict__ pW2Th, const unsigned short* __restrict__ pW2Tl,
             const unsigned short* __restrict__ WcTh, const unsigned short* __restrict__ WcTl,
             const unsigned short* __restrict__ WpTh, const unsigned short* __restrict__ WpTl,
             const float* __restrict__ cbM, const float* __restrict__ pbM,
             const float* __restrict__ positions, const float* __restrict__ colors,
             const int* __restrict__ cls, const int cstride,
             unsigned short* __restrict__ ehi, unsigned short* __restrict__ elo,
             float* __restrict__ sqn, const int pbase)
{
    __shared__ __align__(16) unsigned short Ahc[16 * 72];
    __shared__ __align__(16) unsigned short Alc[16 * 72];
    __shared__ __align__(16) unsigned short Ahp[16 * 72];
    __shared__ __align__(16) unsigned short Alp[16 * 72];
    __shared__ float sqc[16][4], sqp_[16][4], sqe[16][4];

    const int t = threadIdx.x, w = t >> 6, lane = t & 63;
    const int l15 = lane & 15, quad = lane >> 4;
    const int obase = blockIdx.x * 16;         // slab-local

    {
        const int o = lane >> 4;               // 0..3
        const int objl = w * 4 + o;
        const int gobj = pbase + obase + objl;
        const float c0 = colors[gobj * 3], c1 = colors[gobj * 3 + 1], c2 = colors[gobj * 3 + 2];
        const float q0 = positions[gobj * 3], q1 = positions[gobj * 3 + 1], q2 = positions[gobj * 3 + 2];
        const int u0 = (lane & 15) * 4;
        #pragma unroll
        for (int uu = 0; uu < 4; ++uu) {
            const int u = u0 + uu;
            const float hc = fmaxf(cb1[u] + c0 * cW1[u] + c1 * cW1[64 + u] + c2 * cW1[128 + u], 0.f);
            const float hp = fmaxf(pb1[u] + q0 * pW1[u] + q1 * pW1[64 + u] + q2 * pW1[128 + u], 0.f);
            unsigned short h, l;
            split2(hc, h, l); Ahc[objl * 72 + u] = h; Alc[objl * 72 + u] = l;
            split2(hp, h, l); Ahp[objl * 72 + u] = h; Alp[objl * 72 + u] = l;
        }
    }
    __syncthreads();

    f32x4 aco[4], ape[4];
    #pragma unroll
    for (int nt = 0; nt < 4; ++nt) { aco[nt] = (f32x4){0.f,0.f,0.f,0.f}; ape[nt] = (f32x4){0.f,0.f,0.f,0.f}; }

    #pragma unroll
    for (int kt = 0; kt < 2; ++kt) {
        const int ao = l15 * 72 + kt * 32 + quad * 8;
        const s16x8 ahc = *(const s16x8*)&Ahc[ao];
        const s16x8 alc = *(const s16x8*)&Alc[ao];
        const s16x8 ahp = *(const s16x8*)&Ahp[ao];
        const s16x8 alp = *(const s16x8*)&Alp[ao];
        #pragma unroll
        for (int nt = 0; nt < 4; ++nt) {
            const int n = w * 64 + nt * 16 + l15;
            const size_t bo = (size_t)n * 64 + kt * 32 + quad * 8;
            const s16x8 cbh = *(const s16x8*)(cW2Th + bo);
            const s16x8 cbl = *(const s16x8*)(cW2Tl + bo);
            const s16x8 pbh = *(const s16x8*)(pW2Th + bo);
            const s16x8 pbl = *(const s16x8*)(pW2Tl + bo);
            aco[nt] = __builtin_amdgcn_mfma_f32_16x16x32_bf16(ahc, cbh, aco[nt], 0, 0, 0);
            ape[nt] = __builtin_amdgcn_mfma_f32_16x16x32_bf16(ahp, pbh, ape[nt], 0, 0, 0);
            aco[nt] = __builtin_amdgcn_mfma_f32_16x16x32_bf16(alc, cbh, aco[nt], 0, 0, 0);
            ape[nt] = __builtin_amdgcn_mfma_f32_16x16x32_bf16(alp, pbh, ape[nt], 0, 0, 0);
            aco[nt] = __builtin_amdgcn_mfma_f32_16x16x32_bf16(ahc, cbl, aco[nt], 0, 0, 0);
            ape[nt] = __builtin_amdgcn_mfma_f32_16x16x32_bf16(ahp, pbl, ape[nt], 0, 0, 0);
        }
    }

    float sc[4] = {0.f,0.f,0.f,0.f}, sp[4] = {0.f,0.f,0.f,0.f};
    #pragma unroll
    for (int nt = 0; nt < 4; ++nt) {
        const int col = w * 64 + nt * 16 + l15;
        const float cbv = cb2[col], pbv = pb2[col];
        #pragma unroll
        for (int r = 0; r < 4; ++r) {
            const float co = aco[nt][r] + cbv;
            const float pe = ape[nt][r] + pbv;
            sc[r] += co * co;
            sp[r] += pe * pe;
        }
    }
    #pragma unroll
    for (int s = 8; s > 0; s >>= 1) {
        #pragma unroll
        for (int r = 0; r < 4; ++r) {
            sc[r] += __shfl_xor(sc[r], s, 64);
            sp[r] += __shfl_xor(sp[r], s, 64);
        }
    }
    if (l15 == 0) {
        #pragma unroll
        for (int r = 0; r < 4; ++r) { sqc[quad * 4 + r][w] = sc[r]; sqp_[quad * 4 + r][w] = sp[r]; }
    }
    __syncthreads();

    float rco[4], rpe[4];
    #pragma unroll
    for (int r = 0; r < 4; ++r) {
        const int row = quad * 4 + r;
        rco[r] = 1.f / fmaxf(sqrtf(sqc[row][0] + sqc[row][1] + sqc[row][2] + sqc[row][3]), 1e-12f);
        rpe[r] = 1.f / fmaxf(sqrtf(sqp_[row][0] + sqp_[row][1] + sqp_[row][2] + sqp_[row][3]), 1e-12f);
    }

    f32x4 ac[4], ap[4];
    #pragma unroll
    for (int nt = 0; nt < 4; ++nt) { ac[nt] = (f32x4){0.f,0.f,0.f,0.f}; ap[nt] = (f32x4){0.f,0.f,0.f,0.f}; }

    #pragma unroll
    for (int kt = 0; kt < 2; ++kt) {
        const int ao = l15 * 72 + kt * 32 + quad * 8;
        const s16x8 ahc = *(const s16x8*)&Ahc[ao];
        const s16x8 alc = *(const s16x8*)&Alc[ao];
        const s16x8 ahp = *(const s16x8*)&Ahp[ao];
        const s16x8 alp = *(const s16x8*)&Alp[ao];
        #pragma unroll
        for (int nt = 0; nt < 4; ++nt) {
            const int n = w * 64 + nt * 16 + l15;
            const size_t bo = (size_t)n * 64 + kt * 32 + quad * 8;
            const s16x8 cbh = *(const s16x8*)(WcTh + bo);
            const s16x8 cbl = *(const s16x8*)(WcTl + bo);
            const s16x8 pbh = *(const s16x8*)(WpTh + bo);
            const s16x8 pbl = *(const s16x8*)(WpTl + bo);
            ac[nt] = __builtin_amdgcn_mfma_f32_16x16x32_bf16(ahc, cbh, ac[nt], 0, 0, 0);
            ap[nt] = __builtin_amdgcn_mfma_f32_16x16x32_bf16(ahp, pbh, ap[nt], 0, 0, 0);
            ac[nt] = __builtin_amdgcn_mfma_f32_16x16x32_bf16(alc, cbh, ac[nt], 0, 0, 0);
            ap[nt] = __builtin_amdgcn_mfma_f32_16x16x32_bf16(alp, pbh, ap[nt], 0, 0, 0);
            ac[nt] = __builtin_amdgcn_mfma_f32_16x16x32_bf16(ahc, cbl, ac[nt], 0, 0, 0);
            ap[nt] = __builtin_amdgcn_mfma_f32_16x16x32_bf16(ahp, pbl, ap[nt], 0, 0, 0);
        }
    }

    int ci[4];
    #pragma unroll
    for (int r = 0; r < 4; ++r) {
        const int gobj = pbase + obase + quad * 4 + r;
        int c = cls[(size_t)gobj * cstride];
        if ((unsigned)c > 30u) c = 0;
        ci[r] = c;
    }

    float rp[4] = {0.f,0.f,0.f,0.f};
    #pragma unroll
    for (int nt = 0; nt < 4; ++nt) {
        const int col = w * 64 + nt * 16 + l15;
        const float mbv = mb[col], cbMv = cbM[col], pbMv = pbM[col];
        #pragma unroll
        for (int r = 0; r < 4; ++r) {
            const int row = quad * 4 + r;
            const float e = classMn[ci[r] * 256 + col]
                          + rco[r] * (ac[nt][r] + cbMv)
                          + rpe[r] * (ap[nt][r] + pbMv) + mbv;
            unsigned short h, l;
            split2(e, h, l);
            ehi[(size_t)(obase + row) * 256 + col] = h;
            elo[(size_t)(obase + row) * 256 + col] = l;
            rp[r] += e * e;
        }
    }
    #pragma unroll
    for (int s = 8; s > 0; s >>= 1) {
        #pragma unroll
        for (int r = 0; r < 4; ++r) rp[r] += __shfl_xor(rp[r], s, 64);
    }
    if (l15 == 0) {
        #pragma unroll
        for (int r = 0; r < 4; ++r) sqe[quad * 4 + r][w] = rp[r];
    }
    __syncthreads();
    if (t < 16) sqn[obase + t] = sqe[t][0] + sqe[t][1] + sqe[t][2] + sqe[t][3];
}

// ---------------------------------------------------------------------------
// Kernel 2: Gram/distance via 3-pass split MFMA, 128x64 tile per block.
// (Full 3-pass kept: kNN selection fidelity depends on it.)
// ---------------------------------------------------------------------------
__global__ __launch_bounds__(256)
void k_gram(const unsigned short* __restrict__ ehi, const unsigned short* __restrict__ elo,
            const float* __restrict__ sqn, float* __restrict__ dist)
{
    const int t = threadIdx.x, w = t >> 6, lane = t & 63;
    const int l15 = lane & 15, quad = lane >> 4;
    const int b_local = blockIdx.x >> 5;       // 0..15 (32 blocks/cell)
    const int tile = blockIdx.x & 31;
    const int p0 = (tile >> 3) * 128, q0 = (tile & 7) * 64;
    const size_t cb = (size_t)b_local * NP;

    f32x4 acc[2][4];
    #pragma unroll
    for (int sub = 0; sub < 2; ++sub)
        #pragma unroll
        for (int nt = 0; nt < 4; ++nt) acc[sub][nt] = (f32x4){0.f, 0.f, 0.f, 0.f};

    for (int s = 0; s < 8; ++s) {
        s16x8 ah[2], al[2];
        #pragma unroll
        for (int sub = 0; sub < 2; ++sub) {
            const size_t ao = (cb + p0 + sub * 64 + 16 * w + l15) * 256 + s * 32 + quad * 8;
            ah[sub] = *(const s16x8*)(ehi + ao);
            al[sub] = *(const s16x8*)(elo + ao);
        }
        #pragma unroll
        for (int nt = 0; nt < 4; ++nt) {
            const size_t bo = (cb + q0 + nt * 16 + l15) * 256 + s * 32 + quad * 8;
            const s16x8 bh = *(const s16x8*)(ehi + bo);
            const s16x8 bl = *(const s16x8*)(elo + bo);
            #pragma unroll
            for (int sub = 0; sub < 2; ++sub) {
                acc[sub][nt] = __builtin_amdgcn_mfma_f32_16x16x32_bf16(ah[sub], bh, acc[sub][nt], 0, 0, 0);
                acc[sub][nt] = __builtin_amdgcn_mfma_f32_16x16x32_bf16(al[sub], bh, acc[sub][nt], 0, 0, 0);
                acc[sub][nt] = __builtin_amdgcn_mfma_f32_16x16x32_bf16(ah[sub], bl, acc[sub][nt], 0, 0, 0);
            }
        }
    }

    #pragma unroll
    for (int sub = 0; sub < 2; ++sub) {
        float sqp[4];
        #pragma unroll
        for (int r = 0; r < 4; ++r)
            sqp[r] = sqn[cb + p0 + sub * 64 + 16 * w + quad * 4 + r];
        #pragma unroll
        for (int nt = 0; nt < 4; ++nt) {
            const int colq = q0 + nt * 16 + l15;
            const float sq_q = sqn[cb + colq];
            #pragma unroll
            for (int r = 0; r < 4; ++r) {
                const int rowp = p0 + sub * 64 + 16 * w + quad * 4 + r;
                dist[(cb + rowp) * NP + colq] = (sqp[r] + sq_q) - 2.f * acc[sub][nt][r];
            }
        }
    }
}

// ---------------------------------------------------------------------------
// Kernel 3: top-8 smallest per point (ties -> lowest index). One wave/point.
// ---------------------------------------------------------------------------
__global__ __launch_bounds__(256)
void k_select(const float* __restrict__ dist, int* __restrict__ nidx)
{
    const int wv = threadIdx.x >> 6, lane = threadIdx.x & 63;
    const int p_sl = blockIdx.x * 4 + wv;          // 0..8191
    const float* row = dist + (size_t)p_sl * NP;

    float d[8]; int q[8];
    #pragma unroll
    for (int i = 0; i < 8; ++i) { q[i] = lane + 64 * i; d[i] = row[lane + 64 * i]; }

    for (int r = 0; r < KNN; ++r) {
        float bd = d[0]; int bq = q[0];
        #pragma unroll
        for (int i = 1; i < 8; ++i)
            if (d[i] < bd || (d[i] == bd && q[i] < bq)) { bd = d[i]; bq = q[i]; }
        #pragma unroll
        for (int s = 32; s > 0; s >>= 1) {
            const float od = __shfl_down(bd, s, 64);
            const int oq = __shfl_down(bq, s, 64);
            if (od < bd || (od == bd && oq < bq)) { bd = od; bq = oq; }
        }
        const int win = __shfl(bq, 0, 64);
        if (lane == 0) nidx[(size_t)p_sl * KNN + r] = ((p_sl >> 9) << 9) | win;
        if ((win & 63) == lane) {
            const int wi = win >> 6;
            #pragma unroll
            for (int i = 0; i < 8; ++i) if (wi == i) d[i] = 3.4e38f;
        }
    }
}

// ---------------------------------------------------------------------------
// Kernel 4: u = x@Wd+gb1, v = x@Wb via 2-pass split MFMA (A hi+lo, B hi only).
// 32 points/block.
// ---------------------------------------------------------------------------
__global__ __launch_bounds__(256)
void k_uv(const unsigned short* __restrict__ ehi, const unsigned short* __restrict__ elo,
          const unsigned short* __restrict__ Wdh,
          const unsigned short* __restrict__ Wbh,
          const float* __restrict__ gb1,
          float* __restrict__ u, float* __restrict__ v)
{
    const int t = threadIdx.x, w = t >> 6, lane = t & 63;
    const int l15 = lane & 15, quad = lane >> 4;
    const int isV = blockIdx.x >> 8;
    const int m0 = (blockIdx.x & 255) * 32;    // slab-local
    const unsigned short* Wh = isV ? Wbh : Wdh;
    float* out = isV ? v : u;
    const int mt = w & 1, ch = w >> 1;

    const size_t arow = (size_t)(m0 + mt * 16 + l15) * 256 + quad * 8;

    f32x4 acc[8];
    #pragma unroll
    for (int nt = 0; nt < 8; ++nt) acc[nt] = (f32x4){0.f, 0.f, 0.f, 0.f};

    for (int s = 0; s < 8; ++s) {
        const s16x8 ah = *(const s16x8*)(ehi + arow + s * 32);
        const s16x8 al = *(const s16x8*)(elo + arow + s * 32);
        #pragma unroll
        for (int nt = 0; nt < 8; ++nt) {
            const int n = (ch * 8 + nt) * 16 + l15;
            const size_t bo = (size_t)n * 256 + s * 32 + quad * 8;
            const s16x8 bh = *(const s16x8*)(Wh + bo);
            acc[nt] = __builtin_amdgcn_mfma_f32_16x16x32_bf16(ah, bh, acc[nt], 0, 0, 0);
            acc[nt] = __builtin_amdgcn_mfma_f32_16x16x32_bf16(al, bh, acc[nt], 0, 0, 0);
        }
    }

    #pragma unroll
    for (int nt = 0; nt < 8; ++nt) {
        const int col = (ch * 8 + nt) * 16 + l15;
        const float bias = isV ? 0.f : gb1[col];
        #pragma unroll
        for (int r = 0; r < 4; ++r) {
            const int row = mt * 16 + quad * 4 + r;
            out[(size_t)(m0 + row) * 256 + col] = acc[nt][r] + bias;
        }
    }
}

// ---------------------------------------------------------------------------
// Kernel 5: edge GEMM + max aggregation. Block = 8 points (64 edges), 4 waves;
// wave w = all 64 edges x cols w*64..+63. 2-pass split (A hi+lo, B hi only).
// Software-pipelined A-staging: LOADR (global->regs, 1 k-step ahead) is
// decoupled from SPLITW (regs->split2->LDS, post-barrier) so global-load
// latency never sits on the barrier-to-barrier critical path.
// ---------------------------------------------------------------------------
__global__ __launch_bounds__(256)
void k_edge(const float* __restrict__ u, const float* __restrict__ v,
            const int* __restrict__ nidx,
            const unsigned short* __restrict__ g2h,
            const float* __restrict__ hb,
            float* __restrict__ part, const int cell0)
{
    __shared__ unsigned short Abuf[2][2][2304];   // [dbuf][hi/lo][edge*36+k], 18.4 KB

    const int t = threadIdx.x, w = t >> 6, lane = t & 63;
    const int l15 = lane & 15, quad = lane >> 4;

    // XCD swizzle: blockIdx%8 ~ XCD; 2 whole cells per XCD.
    const int b = blockIdx.x;
    const int xcd = b & 7, rest = b >> 3;        // rest 0..127
    const int celll = xcd * 2 + (rest >> 6);     // slab-local cell 0..15
    const int pl0 = celll * NP + (rest & 63) * 8;

    // staging role: edge se = t>>2 (0..63), k-chunk kq = t&3 (8 k's each)
    const int se = t >> 2, kq = t & 3;
    const int surow = pl0 + (se >> 3);
    int svrow = nidx[(size_t)surow * KNN + (se & 7)];
    if ((unsigned)svrow >= (unsigned)SLABPTS) svrow = 0;

    float4 ua, ub, va, vb;                       // prefetch registers

    #define LOADR(S)                                                             \
    {                                                                            \
        const int k0 = (S) * 32 + kq * 8;                                        \
        ua = *(const float4*)(u + (size_t)surow * 256 + k0);                     \
        ub = *(const float4*)(u + (size_t)surow * 256 + k0 + 4);                 \
        va = *(const float4*)(v + (size_t)svrow * 256 + k0);                     \
        vb = *(const float4*)(v + (size_t)svrow * 256 + k0 + 4);                 \
    }
    #define SPLITW(BUF)                                                          \
    {                                                                            \
        const float sv[8] = {                                                    \
            fmaxf(ua.x + va.x, 0.f), fmaxf(ua.y + va.y, 0.f),                    \
            fmaxf(ua.z + va.z, 0.f), fmaxf(ua.w + va.w, 0.f),                    \
            fmaxf(ub.x + vb.x, 0.f), fmaxf(ub.y + vb.y, 0.f),                    \
            fmaxf(ub.z + vb.z, 0.f), fmaxf(ub.w + vb.w, 0.f)};                   \
        union { uint2 q[2]; unsigned short us[8]; } th, tl;                      \
        _Pragma("unroll")                                                        \
        for (int j = 0; j < 8; ++j) { split2(sv[j], th.us[j], tl.us[j]); }       \
        *(uint2*)&Abuf[BUF][0][se * 36 + kq * 8]     = th.q[0];                  \
        *(uint2*)&Abuf[BUF][0][se * 36 + kq * 8 + 4] = th.q[1];                  \
        *(uint2*)&Abuf[BUF][1][se * 36 + kq * 8]     = tl.q[0];                  \
        *(uint2*)&Abuf[BUF][1][se * 36 + kq * 8 + 4] = tl.q[1];                  \
    }

    f32x4 acc[4][4];
    #pragma unroll
    for (int mt = 0; mt < 4; ++mt)
        #pragma unroll
        for (int nt = 0; nt < 4; ++nt) acc[mt][nt] = (f32x4){0.f, 0.f, 0.f, 0.f};

    LOADR(0);
    SPLITW(0);
    LOADR(1);
    for (int s = 0; s < 8; ++s) {
        __syncthreads();                      // buf[s&1] visible; buf[(s+1)&1] readers done
        if (s < 7) {
            SPLITW((s + 1) & 1);              // regs already resident — pure VALU + ds_write
            if (s < 6) LOADR(s + 2);          // latency hides under this step's MFMAs
        }

        const int k0 = s * 32 + quad * 8;
        s16x8 ah[4], al[4];
        #pragma unroll
        for (int mt = 0; mt < 4; ++mt) {
            const int ao = (mt * 16 + l15) * 36 + quad * 8;
            union { uint2 q[2]; s16x8 v8; } Th, Tl;
            Th.q[0] = *(const uint2*)&Abuf[s & 1][0][ao];
            Th.q[1] = *(const uint2*)&Abuf[s & 1][0][ao + 4];
            Tl.q[0] = *(const uint2*)&Abuf[s & 1][1][ao];
            Tl.q[1] = *(const uint2*)&Abuf[s & 1][1][ao + 4];
            ah[mt] = Th.v8; al[mt] = Tl.v8;
        }
        #pragma unroll
        for (int nt = 0; nt < 4; ++nt) {
            const int n = w * 64 + nt * 16 + l15;
            const s16x8 bh = *(const s16x8*)(g2h + (size_t)n * 256 + k0);
            #pragma unroll
            for (int mt = 0; mt < 4; ++mt) {
                acc[mt][nt] = __builtin_amdgcn_mfma_f32_16x16x32_bf16(ah[mt], bh, acc[mt][nt], 0, 0, 0);
                acc[mt][nt] = __builtin_amdgcn_mfma_f32_16x16x32_bf16(al[mt], bh, acc[mt][nt], 0, 0, 0);
            }
        }
    }
    #undef LOADR
    #undef SPLITW

    // per-col max over all 64 edges (covers the block's 8 points)
    const int cell = cell0 + celll;
    const int slot = rest & 63;
    #pragma unroll
    for (int nt = 0; nt < 4; ++nt) {
        float rm = -3.4e38f;
        #pragma unroll
        for (int mt = 0; mt < 4; ++mt)
            rm = fmaxf(rm, fmaxf(fmaxf(acc[mt][nt][0], acc[mt][nt][1]),
                                 fmaxf(acc[mt][nt][2], acc[mt][nt][3])));
        rm = fmaxf(rm, __shfl_xor(rm, 16, 64));
        rm = fmaxf(rm, __shfl_xor(rm, 32, 64));
        if (quad == 0) {
            const int col = w * 64 + nt * 16 + l15;
            part[((size_t)cell * 64 + slot) * 256 + col] = rm + hb[col];
        }
    }
}

// ---------------------------------------------------------------------------
// Kernel 6: reduce 64 partial maxes per cell, final MLP (f32), L2 normalize.
// ---------------------------------------------------------------------------
__global__ __launch_bounds__(256)
void k_final(const float* __restrict__ part,
             const float* __restrict__ lW1, const float* __restrict__ lb1,
             const float* __restrict__ lW2, const float* __restrict__ lb2,
             float* __restrict__ out)
{
    __shared__ float pooled[256];
    __shared__ float hid[256];
    __shared__ float red[4];

    const int b = blockIdx.x;
    const int t = threadIdx.x;

    float m = -3.4e38f;
    for (int s = 0; s < 64; ++s)
        m = fmaxf(m, part[((size_t)b * 64 + s) * 256 + t]);
    pooled[t] = m;
    __syncthreads();

    float h = lb1[t];
    for (int k = 0; k < 256; k += 4) {
        #pragma unroll
        for (int kk = 0; kk < 4; ++kk)
            h += pooled[k + kk] * lW1[(k + kk) * 256 + t];
    }
    hid[t] = fmaxf(h, 0.f);
    __syncthreads();

    float o = lb2[t];
    for (int k = 0; k < 256; k += 4) {
        #pragma unroll
        for (int kk = 0; kk < 4; ++kk)
            o += hid[k + kk] * lW2[(k + kk) * 256 + t];
    }

    float ss = o * o;
    #pragma unroll
    for (int s = 32; s > 0; s >>= 1) ss += __shfl_down(ss, s, 64);
    if ((t & 63) == 0) red[t >> 6] = ss;
    __syncthreads();
    const float tot = red[0] + red[1] + red[2] + red[3];
    const float rn = 1.f / fmaxf(sqrtf(tot), 1e-12f);
    out[b * 256 + t] = o * rn;
}

// ---------------------------------------------------------------------------
extern "C" void kernel_launch(void* const* d_in, const int* in_sizes, int n_in,
                              void* d_out, int out_size, void* d_ws, size_t ws_size,
                              hipStream_t stream)
{
    (void)n_in; (void)out_size; (void)ws_size;

    const float* class_table = (const float*)d_in[0];
    const float* cW1 = (const float*)d_in[1];
    const float* cb1 = (const float*)d_in[2];
    const float* cW2 = (const float*)d_in[3];
    const float* cb2 = (const float*)d_in[4];
    const float* pW1 = (const float*)d_in[5];
    const float* pb1 = (const float*)d_in[6];
    const float* pW2 = (const float*)d_in[7];
    const float* pb2 = (const float*)d_in[8];
    const float* mW  = (const float*)d_in[9];
    const float* mb  = (const float*)d_in[10];
    const float* gW1 = (const float*)d_in[11];
    const float* gb1 = (const float*)d_in[12];
    const float* g_gamma = (const float*)d_in[13];
    const float* g_beta  = (const float*)d_in[14];
    const float* gW2 = (const float*)d_in[15];
    const float* gb2 = (const float*)d_in[16];
    const float* lW1 = (const float*)d_in[17];
    const float* lb1 = (const float*)d_in[18];
    const float* lW2 = (const float*)d_in[19];
    const float* lb2 = (const float*)d_in[20];
    const float* positions = (const float*)d_in[21];
    const float* colors    = (const float*)d_in[22];
    const int*  cls        = (const int*)d_in[23];

    const int cstride = (in_sizes[23] == 2 * NTOT) ? 2 : 1;

    // workspace layout (bytes), peak ~39.1 MB (under proven-safe 47.3):
    char* base = (char*)d_ws;
    float*          part   = (float*)(base + 0);               // 4,194,304
    unsigned short* Wdh    = (unsigned short*)(base + 4194304);
    unsigned short* Wdl    = (unsigned short*)(base + 4325376);
    unsigned short* Wbh    = (unsigned short*)(base + 4456448);
    unsigned short* Wbl    = (unsigned short*)(base + 4587520);
    unsigned short* g2h    = (unsigned short*)(base + 4718592);
    unsigned short* g2l    = (unsigned short*)(base + 4849664);
    float*          hb     = (float*)(base + 4980736);
    unsigned short* cW2Th  = (unsigned short*)(base + 4981760);
    unsigned short* cW2Tl  = (unsigned short*)(base + 5014528);
    unsigned short* pW2Th  = (unsigned short*)(base + 5047296);
    unsigned short* pW2Tl  = (unsigned short*)(base + 5080064);
    unsigned short* WcTh   = (unsigned short*)(base + 5112832);
    unsigned short* WcTl   = (unsigned short*)(base + 5145600);
    unsigned short* WpTh   = (unsigned short*)(base + 5178368);
    unsigned short* WpTl   = (unsigned short*)(base + 5211136);
    float*          classMn= (float*)(base + 5243904);         // 31,744
    float*          cbM    = (float*)(base + 5275648);
    float*          pbM    = (float*)(base + 5276672);
    int*            nidx   = (int*)(base + 5277696);           // 262,144
    float*          sqn    = (float*)(base + 5539840);         // 32,768
    unsigned short* ehi    = (unsigned short*)(base + 5572608);// 4,194,304
    unsigned short* elo    = (unsigned short*)(base + 9766912);// 4,194,304
    float*          dist   = (float*)(base + 13961216);        // 16,777,216
    float*          u      = dist;                             // 8,388,608 (aliased)
    float*          v      = (float*)(base + 30738432);        // 8,388,608
    float* out = (float*)d_out;

    k_cvt<<<897, 256, 0, stream>>>(gW1, gW2, g_gamma, g_beta, gb2, cW2, pW2,
                                   Wdh, Wdl, Wbh, Wbl, g2h, g2l, hb,
                                   cW2Th, cW2Tl, pW2Th, pW2Tl);
    k_fold<<<130, 256, 0, stream>>>(cW2, pW2, cb2, pb2, mW,
                                    WcTh, WcTl, WpTh, WpTl, cbM, pbM);
    k_cls<<<31, 256, 0, stream>>>(class_table, mW, classMn);

    for (int s = 0; s < NSLAB; ++s) {
        k_embed<<<SLABPTS / 16, 256, 0, stream>>>(classMn, cW1, cb1, cb2,
                                                  pW1, pb1, pb2, mb,
                                                  cW2Th, cW2Tl, pW2Th, pW2Tl,
                                                  WcTh, WcTl, WpTh, WpTl,
                                                  cbM, pbM,
                                                  positions, colors, cls, cstride,
                                                  ehi, elo, sqn, s * SLABPTS);
        k_gram<<<SLAB * 32, 256, 0, stream>>>(ehi, elo, sqn, dist);
        k_select<<<SLABPTS / 4, 256, 0, stream>>>(dist, nidx);
        k_uv<<<2 * SLABPTS / 32, 256, 0, stream>>>(ehi, elo, Wdh, Wbh, gb1, u, v);
        k_edge<<<SLABPTS / 8, 256, 0, stream>>>(u, v, nidx, g2h, hb,
                                                part, s * SLAB);
    }
    k_final<<<NB, 256, 0, stream>>>(part, lW1, lb1, lW2, lb2, out);
}